// Round 1
// 1756.096 us; speedup vs baseline: 1.0148x; 1.0148x over previous
//
#include <hip/hip_runtime.h>
#include <hip/hip_bf16.h>
#include <math.h>

typedef __attribute__((ext_vector_type(8))) short short8;     // 8 bf16 = 4 VGPRs
typedef __attribute__((ext_vector_type(4))) short short4v;    // 4 bf16 = 8B
typedef __attribute__((ext_vector_type(4))) float f32x4;

#define BB 16
#define SS 512
#define EE 512
#define HH 8
#define DH 64
#define LL 3
#define MM (BB*SS)
#define OBSD 128
#define ACTD 17
#define INV_SQRT_D 0.125f

#define ACT_NONE 0
#define ACT_GELU 1

#define NORM_PLAIN 0
#define NORM_ADD 1
#define NORM_SWIGLU 2

__device__ __forceinline__ float gelu_f(float x){
  float x3 = x*x*x;
  return 0.5f*x*(1.f + tanhf(0.7978845608028654f*(x + 0.044715f*x3)));
}
__device__ __forceinline__ float silu_f(float x){ return x/(1.f+expf(-x)); }
__device__ __forceinline__ float lkappa(int h){ return logf(1.f - exp2f(-5.f - (float)h)); }
__device__ __forceinline__ unsigned short f2bs(float f){
  unsigned int u = __float_as_uint(f);
  u += 0x7FFFu + ((u >> 16) & 1u);
  return (unsigned short)(u >> 16);
}
__device__ __forceinline__ float bs2f(unsigned short u){
  return __uint_as_float(((unsigned int)u) << 16);
}

// ---------------- weight transpose: W[K][512] fp32 -> Wt[512][Kpad] bf16 ----------------
__global__ __launch_bounds__(256) void wtpose_kernel(
    const float* __restrict__ src, unsigned short* __restrict__ dst, int K, int Kpad)
{
  __shared__ float t[32][33];
  const int gx = blockIdx.x, gy = blockIdx.y;
  const int tx = threadIdx.x, ty = threadIdx.y;
  #pragma unroll
  for (int i = 0; i < 4; ++i){
    int k = gx*32 + ty + i*8, n = gy*32 + tx;
    t[ty+i*8][tx] = (k < K) ? src[(size_t)k*EE + n] : 0.f;
  }
  __syncthreads();
  #pragma unroll
  for (int i = 0; i < 4; ++i){
    int k = gx*32 + tx, n = gy*32 + ty + i*8;
    dst[(size_t)n*Kpad + k] = f2bs(t[tx][ty+i*8]);
  }
}

struct TP50 { const float* s[50]; unsigned short* d[50]; };
__global__ __launch_bounds__(256) void wtpose_batch_kernel(TP50 tp)
{
  __shared__ float t[32][33];
  const float* src = tp.s[blockIdx.z];
  unsigned short* dst = tp.d[blockIdx.z];
  const int gx = blockIdx.x, gy = blockIdx.y;
  const int tx = threadIdx.x, ty = threadIdx.y;
  #pragma unroll
  for (int i = 0; i < 4; ++i){
    int k = gx*32 + ty + i*8, n = gy*32 + tx;
    t[ty+i*8][tx] = src[(size_t)k*EE + n];
  }
  __syncthreads();
  #pragma unroll
  for (int i = 0; i < 4; ++i){
    int k = gx*32 + tx, n = gy*32 + ty + i*8;
    dst[(size_t)n*EE + k] = f2bs(t[tx][ty+i*8]);
  }
}

// ---------------- MFMA GEMM: act(scale*(A_b@W) + bias) -> fp32 C and/or bf16 Cb and/or per-head CT ----------------
__global__ __launch_bounds__(256) void gemm_b_kernel(
    const unsigned short* __restrict__ A, const unsigned short* __restrict__ Wt,
    const float* __restrict__ bias, float* __restrict__ C,
    unsigned short* __restrict__ Cb, unsigned short* __restrict__ CT,
    int Kpad, float scale, int act)
{
  __shared__ unsigned short As[128*72];
  __shared__ unsigned short Bs[64*72];
  const int bm = blockIdx.y*128, bn = blockIdx.x*64;
  const int tid = threadIdx.x, lane = tid & 63, wv = tid >> 6;
  const int wr = wv >> 1, wc = wv & 1;
  const int l16 = lane & 15, quad = lane >> 4;

  f32x4 acc[4][2];
  #pragma unroll
  for (int i=0;i<4;i++){ acc[i][0]=(f32x4)(0.f); acc[i][1]=(f32x4)(0.f); }

  const int arow = tid >> 1, acol = (tid & 1)*32;
  const int brow = tid >> 2, bcol = (tid & 3)*16;

  for (int k0 = 0; k0 < Kpad; k0 += 64){
    const unsigned short* ag = A + (size_t)(bm+arow)*Kpad + k0 + acol;
    #pragma unroll
    for (int i=0;i<4;i++)
      *(short8*)&As[arow*72 + acol + i*8] = *(const short8*)(ag + i*8);
    const unsigned short* bg = Wt + (size_t)(bn+brow)*Kpad + k0 + bcol;
    #pragma unroll
    for (int i=0;i<2;i++)
      *(short8*)&Bs[brow*72 + bcol + i*8] = *(const short8*)(bg + i*8);
    __syncthreads();
    short8 af[4][2], bf[2][2];
    #pragma unroll
    for (int mt=0; mt<4; ++mt)
      #pragma unroll
      for (int ks=0; ks<2; ++ks)
        af[mt][ks] = *(const short8*)&As[(wr*64 + mt*16 + l16)*72 + ks*32 + quad*8];
    #pragma unroll
    for (int nt=0; nt<2; ++nt)
      #pragma unroll
      for (int ks=0; ks<2; ++ks)
        bf[nt][ks] = *(const short8*)&Bs[(wc*32 + nt*16 + l16)*72 + ks*32 + quad*8];
    #pragma unroll
    for (int ks=0; ks<2; ++ks)
      #pragma unroll
      for (int mt=0; mt<4; ++mt)
        #pragma unroll
        for (int nt=0; nt<2; ++nt)
          acc[mt][nt] = __builtin_amdgcn_mfma_f32_16x16x32_bf16(af[mt][ks], bf[nt][ks], acc[mt][nt], 0, 0, 0);
    __syncthreads();
  }
  #pragma unroll
  for (int mt=0; mt<4; ++mt){
    #pragma unroll
    for (int nt=0; nt<2; ++nt){
      int col = bn + wc*32 + nt*16 + l16;
      float bv = bias ? bias[col] : 0.f;
      int rb = bm + wr*64 + mt*16 + quad*4;
      float vals[4];
      #pragma unroll
      for (int j=0;j<4;j++){
        float v = acc[mt][nt][j]*scale + bv;
        if (act==ACT_GELU) v = gelu_f(v);
        vals[j] = v;
      }
      if (C){
        #pragma unroll
        for (int j=0;j<4;j++) C[(size_t)(rb+j)*EE + col] = vals[j];
      }
      if (Cb){
        #pragma unroll
        for (int j=0;j<4;j++) Cb[(size_t)(rb+j)*EE + col] = f2bs(vals[j]);
      }
      if (CT){
        int bloc = rb >> 9, m0 = rb & 511;
        int hh = col >> 6, ee = col & 63;
        short4v pk;
        #pragma unroll
        for (int j=0;j<4;j++) pk[j] = (short)f2bs(vals[j]);
        *(short4v*)&CT[(((size_t)bloc*HH + hh)*DH + ee)*SS + m0] = pk;
      }
    }
  }
}

// ---------------- rmsnorm: mixed fp32/bf16 input -> bf16 out (+ optional out+pe) ----------------
__global__ __launch_bounds__(256) void norm_b_kernel(
    const float* __restrict__ af, const unsigned short* __restrict__ ab,
    const float* __restrict__ res, const float* __restrict__ g, const float* __restrict__ p,
    const float* __restrict__ w, unsigned short* __restrict__ o1,
    unsigned short* __restrict__ o2, const unsigned short* __restrict__ peb,
    int mode)
{
  __shared__ float red[4];
  const int row = blockIdx.x, tid = threadIdx.x;
  const size_t base = (size_t)row*EE + tid*2;
  float t0, t1;
  if (ab){
    unsigned int av = *(const unsigned int*)&ab[base];
    t0 = bs2f((unsigned short)(av & 0xffffu));
    t1 = bs2f((unsigned short)(av >> 16));
  } else {
    float2 av = *(const float2*)&af[base];
    t0 = av.x; t1 = av.y;
  }
  if (mode == NORM_ADD){
    float2 rv = *(const float2*)&res[base];
    t0 += rv.x; t1 += rv.y;
  } else if (mode == NORM_SWIGLU){
    float2 gv = *(const float2*)&g[base];
    float2 pv = *(const float2*)&p[base];
    t0 += silu_f(gv.x)*pv.x; t1 += silu_f(gv.y)*pv.y;
  }
  float ss = t0*t0 + t1*t1;
  #pragma unroll
  for (int o=32;o;o>>=1) ss += __shfl_down(ss,o);
  if ((tid&63)==0) red[tid>>6]=ss;
  __syncthreads();
  if (tid==0) red[0] = 1.f/sqrtf((red[0]+red[1]+red[2]+red[3])/(float)EE + 1e-6f);
  __syncthreads();
  float r = red[0];
  float2 wv2 = *(const float2*)&w[tid*2];
  float y0 = t0*r*wv2.x, y1 = t1*r*wv2.y;
  unsigned int pk = (unsigned int)f2bs(y0) | ((unsigned int)f2bs(y1) << 16);
  *(unsigned int*)&o1[base] = pk;
  if (o2){
    unsigned int pv = *(const unsigned int*)&peb[base];
    float z0 = y0 + bs2f((unsigned short)(pv & 0xffffu));
    float z1 = y1 + bs2f((unsigned short)(pv >> 16));
    *(unsigned int*)&o2[base] = (unsigned int)f2bs(z0) | ((unsigned int)f2bs(z1) << 16);
  }
}

// obs norm: fp32 [MM][128] -> bf16
__global__ __launch_bounds__(128) void norm_obs_kernel(
    const float* __restrict__ a, const float* __restrict__ w, unsigned short* __restrict__ o)
{
  __shared__ float red[2];
  const int row = blockIdx.x, tid = threadIdx.x;
  float t = a[(size_t)row*OBSD + tid];
  float ss = t*t;
  #pragma unroll
  for (int off=32;off;off>>=1) ss += __shfl_down(ss,off);
  if ((tid&63)==0) red[tid>>6]=ss;
  __syncthreads();
  if (tid==0) red[0] = 1.f/sqrtf((red[0]+red[1])/(float)OBSD + 1e-6f);
  __syncthreads();
  o[(size_t)row*OBSD + tid] = f2bs(t*red[0]*w[tid]);
}

// action embed: fp32 [MM][17] -> bf16 [MM][64] zero-padded
__global__ __launch_bounds__(256) void act_embed_kernel(
    const float* __restrict__ a, unsigned short* __restrict__ o)
{
  int idx = blockIdx.x*256 + threadIdx.x;
  int row = idx >> 6, col = idx & 63;
  o[idx] = (col < ACTD) ? f2bs(a[(size_t)row*ACTD + col]) : 0;
}

// ---------------- MFMA retention: bf16 q,k normal; v transposed per head ----------------
// 64-row n-tile, 4 waves x 16 rows, grid (SS/64, H, B) = 1024 blocks.
// LDS = 4*64*72*2 + 2048 = 38912 B -> 4 blocks/CU -> 16 waves/CU (2x the old 128-row tile).
__global__ __launch_bounds__(256) void retention_kernel(
    const unsigned short* __restrict__ q, const unsigned short* __restrict__ k,
    const unsigned short* __restrict__ vT,
    const float* __restrict__ h0, const int* __restrict__ tsi,
    unsigned short* __restrict__ outp, int masked)
{
  __shared__ unsigned short qsh[64*72];
  __shared__ unsigned short ksh[64*72];
  __shared__ unsigned short vsh[64*72];   // [e][m_local]
  __shared__ unsigned short psh[64*72];
  __shared__ float tsf[SS];
  const int b = blockIdx.z, h = blockIdx.y;
  const int n0 = blockIdx.x * 64;
  const int tid = threadIdx.x, lane = tid & 63, wv = tid >> 6;
  const int quad = lane >> 4, l16 = lane & 15;
  const float lk = lkappa(h);

  for (int i = tid; i < SS; i += 256) tsf[i] = (float)tsi[b*SS + i];
  {
    const int n = tid >> 2, seg = (tid & 3) * 16;
    const unsigned short* qr = q + ((size_t)b*SS + n0 + n)*EE + h*DH + seg;
    #pragma unroll
    for (int i = 0; i < 2; ++i)
      *(short8*)&qsh[n*72 + seg + i*8] = *(const short8*)(qr + i*8);
  }
  {
    const float* h0b = h0 + (size_t)b*(LL*HH*DH*DH) + (size_t)h*(DH*DH);
    const int d = tid >> 2, eb = (tid & 3) * 16;
    #pragma unroll
    for (int i = 0; i < 4; ++i){
      float4 f = *(const float4*)(h0b + d*DH + eb + i*4);
      ksh[(eb+i*4+0)*72 + d] = f2bs(f.x);
      ksh[(eb+i*4+1)*72 + d] = f2bs(f.y);
      ksh[(eb+i*4+2)*72 + d] = f2bs(f.z);
      ksh[(eb+i*4+3)*72 + d] = f2bs(f.w);
    }
  }
  __syncthreads();

  float maxn = tsf[n0 + lane];
  #pragma unroll
  for (int o=32;o;o>>=1) maxn = fmaxf(maxn, __shfl_xor(maxn, o));

  const int rowbase = wv*16;
  short8 qa[2];
  #pragma unroll
  for (int ks=0; ks<2; ++ks)
    qa[ks] = *(const short8*)&qsh[(rowbase + l16)*72 + ks*32 + quad*8];

  f32x4 acc_o[4];
  #pragma unroll
  for (int et=0; et<4; ++et){
    f32x4 a = (f32x4)(0.f);
    #pragma unroll
    for (int ks=0; ks<2; ++ks){
      short8 hb = *(const short8*)&ksh[(et*16 + l16)*72 + ks*32 + quad*8];
      a = __builtin_amdgcn_mfma_f32_16x16x32_bf16(qa[ks], hb, a, 0, 0, 0);
    }
    acc_o[et] = a;
  }
  #pragma unroll
  for (int j=0;j<4;j++){
    float xi = __expf(lk*(tsf[n0 + rowbase + quad*4 + j] + 1.f));
    #pragma unroll
    for (int et=0; et<4; ++et) acc_o[et][j] *= xi;
  }

  for (int mc = 0; mc < SS; mc += 64){
    if (masked){
      float mn = tsf[mc + lane];
      #pragma unroll
      for (int o=32;o;o>>=1) mn = fminf(mn, __shfl_xor(mn, o));
      if (mn > maxn) continue;
    }
    __syncthreads();
    {
      const int m = tid >> 2, cb = (tid & 3) * 16;
      const unsigned short* krow = k + ((size_t)b*SS + mc + m)*EE + h*DH + cb;
      #pragma unroll
      for (int i = 0; i < 2; ++i)
        *(short8*)&ksh[m*72 + cb + i*8] = *(const short8*)(krow + i*8);
      const int e = tid >> 2, mseg = (tid & 3) * 16;
      const unsigned short* vrow = vT + (((size_t)b*HH + h)*DH + e)*SS + mc + mseg;
      #pragma unroll
      for (int i = 0; i < 2; ++i)
        *(short8*)&vsh[e*72 + mseg + i*8] = *(const short8*)(vrow + i*8);
    }
    __syncthreads();
    f32x4 sacc[4];
    #pragma unroll
    for (int mt=0; mt<4; ++mt){
      f32x4 a = (f32x4)(0.f);
      #pragma unroll
      for (int ks=0; ks<2; ++ks){
        short8 kb = *(const short8*)&ksh[(mt*16 + l16)*72 + ks*32 + quad*8];
        a = __builtin_amdgcn_mfma_f32_16x16x32_bf16(qa[ks], kb, a, 0, 0, 0);
      }
      sacc[mt] = a;
    }
    float tsm[4]; int mg[4];
    #pragma unroll
    for (int mt=0; mt<4; ++mt){ mg[mt] = mc + mt*16 + l16; tsm[mt] = tsf[mg[mt]]; }
    #pragma unroll
    for (int j=0;j<4;j++){
      int nloc = rowbase + quad*4 + j;
      int n = n0 + nloc;
      float tsn = tsf[n];
      #pragma unroll
      for (int mt=0; mt<4; ++mt){
        float diff = tsn - tsm[mt];
        float wgt;
        if (masked) wgt = ((diff > 0.f) || (diff == 0.f && n >= mg[mt])) ? __expf(lk*diff) : 0.f;
        else        wgt = __expf(lk*fabsf(diff));
        psh[nloc*72 + mt*16 + l16] = f2bs(sacc[mt][j]*wgt);
      }
    }
    #pragma unroll
    for (int ks=0; ks<2; ++ks){
      short8 pa = *(const short8*)&psh[(rowbase + l16)*72 + ks*32 + quad*8];
      #pragma unroll
      for (int et=0; et<4; ++et){
        short8 vb = *(const short8*)&vsh[(et*16 + l16)*72 + ks*32 + quad*8];
        acc_o[et] = __builtin_amdgcn_mfma_f32_16x16x32_bf16(pa, vb, acc_o[et], 0, 0, 0);
      }
    }
  }
  #pragma unroll
  for (int j=0;j<4;j++){
    size_t rbase = ((size_t)b*SS + n0 + rowbase + quad*4 + j)*EE + h*DH;
    #pragma unroll
    for (int et=0; et<4; ++et)
      outp[rbase + et*16 + l16] = f2bs(acc_o[et][j]);
  }
}

// ---------------- recurrent state (bf16 k,v in; fp32 math) ----------------
__global__ __launch_bounds__(256) void hstate_partial_kernel(
    const unsigned short* __restrict__ k, const unsigned short* __restrict__ v,
    const int* __restrict__ tsi, const float* __restrict__ tmx,
    float* __restrict__ part)
{
  __shared__ float ksh[64*68];
  __shared__ float vsh[64*64];
  __shared__ float wsh[64];
  const int qr = blockIdx.x, h = blockIdx.y, b = blockIdx.z;
  const int tid = threadIdx.x, lane = tid & 63, wv = tid >> 6;
  const float lk = lkappa(h);
  const float tm = tmx[b];
  float acc[16];
  #pragma unroll
  for (int i=0;i<16;i++) acc[i]=0.f;
  for (int mc = qr*256; mc < qr*256 + 256; mc += 64){
    {
      const int m = tid >> 2, seg = (tid & 3) * 16;
      const unsigned short* krow = k + ((size_t)b*SS + mc + m)*EE + h*DH + seg;
      const unsigned short* vrow = v + ((size_t)b*SS + mc + m)*EE + h*DH + seg;
      #pragma unroll
      for (int i = 0; i < 2; ++i){
        short8 kv = *(const short8*)(krow + i*8);
        short8 vv = *(const short8*)(vrow + i*8);
        #pragma unroll
        for (int e = 0; e < 8; ++e){
          ksh[m*68 + seg + i*8 + e] = bs2f((unsigned short)kv[e]);
          vsh[m*64 + seg + i*8 + e] = bs2f((unsigned short)vv[e]);
        }
      }
    }
    if (tid < 64) wsh[tid] = expf(lk*(tm - (float)tsi[b*SS + mc + tid]));
    __syncthreads();
    for (int m = 0; m < 64; ++m){
      float wvv = wsh[m]*vsh[m*64 + lane];
      const float* kr = &ksh[m*68 + wv*16];
      #pragma unroll
      for (int i = 0; i < 16; i += 4){
        float4 k4 = *(const float4*)&kr[i];
        acc[i+0] += k4.x*wvv; acc[i+1] += k4.y*wvv;
        acc[i+2] += k4.z*wvv; acc[i+3] += k4.w*wvv;
      }
    }
    __syncthreads();
  }
  float* pp = part + ((((size_t)b*HH + h)*2 + qr)*DH + wv*16)*DH + lane;
  #pragma unroll
  for (int i=0;i<16;i++) pp[(size_t)i*DH] = acc[i];
}

__global__ __launch_bounds__(256) void hstate_final_kernel(
    const float* __restrict__ part, const float* __restrict__ h0,
    const float* __restrict__ tmx, float* __restrict__ outp)
{
  int idx = blockIdx.x*256 + threadIdx.x;
  int e = idx & 63, d = (idx>>6) & 63, h = (idx>>12) & 7, b = idx >> 15;
  float lk = lkappa(h);
  float dec = expf(lk*(tmx[b] + 1.f));
  const float* pp = part + (((size_t)b*HH + h)*2*DH + d)*DH + e;
  float s = pp[0] + pp[DH*DH];
  size_t off = (size_t)b*(LL*HH*DH*DH) + (size_t)h*DH*DH + d*DH + e;
  outp[off] = dec*h0[off] + s;
}

// ---------------- small helpers ----------------
__global__ void tsmax_kernel(const int* __restrict__ tsi, float* __restrict__ tmx){
  __shared__ int red[4];
  int b = blockIdx.x, tid = threadIdx.x;
  int m = max(tsi[b*SS+tid], tsi[b*SS+256+tid]);
  #pragma unroll
  for (int o=32;o;o>>=1) m = max(m, __shfl_down(m,o));
  if ((tid&63)==0) red[tid>>6]=m;
  __syncthreads();
  if (tid==0) tmx[b] = (float)max(max(red[0],red[1]),max(red[2],red[3]));
}

__global__ void pe_kernel(const int* __restrict__ tsi, unsigned short* __restrict__ peb){
  int idx = blockIdx.x*256 + threadIdx.x;
  int row = idx >> 9, j = idx & 511;
  float ts = (float)tsi[row];
  int jj = j & 255;
  float freq = expf(-9.210340371976184f*(float)jj*(1.f/256.f));
  float ang = ts*freq;
  peb[idx] = f2bs((j < 256) ? sinf(ang) : cosf(ang));
}

__global__ __launch_bounds__(256) void value_head_kernel(
    const unsigned short* __restrict__ x, const float* __restrict__ w,
    const float* __restrict__ bias, float* __restrict__ outp)
{
  const int tid = threadIdx.x, lane = tid & 63, wv = tid >> 6;
  const int r8 = lane >> 3, seg = lane & 7;
  const int row = blockIdx.x*32 + wv*8 + r8;
  const unsigned short* xr = x + (size_t)row*EE + seg*64;
  const float* wr = w + seg*64;
  float s = 0.f;
  #pragma unroll
  for (int i = 0; i < 8; ++i){
    short8 xv = *(const short8*)(xr + i*8);
    #pragma unroll
    for (int e = 0; e < 8; ++e)
      s += bs2f((unsigned short)xv[e]) * wr[i*8 + e];
  }
  s += __shfl_xor(s, 1); s += __shfl_xor(s, 2); s += __shfl_xor(s, 4);
  if (seg == 0) outp[row] = s + bias[0];
}

__global__ __launch_bounds__(256) void logits_head_kernel(
    const unsigned short* __restrict__ x, const float* __restrict__ w,
    const float* __restrict__ bias, float* __restrict__ outp)
{
  __shared__ unsigned short xsh[16*520];
  __shared__ unsigned short wsh[16*520];
  const int tid = threadIdx.x;
  const int row0 = blockIdx.x*16;
  {
    const int r = tid >> 4, kc = (tid & 15)*32;
    const unsigned short* xr = x + (size_t)(row0 + r)*EE + kc;
    #pragma unroll
    for (int i = 0; i < 4; ++i)
      *(short8*)&xsh[r*520 + kc + i*8] = *(const short8*)(xr + i*8);
    const int j = r;
    #pragma unroll
    for (int kk = 0; kk < 32; ++kk)
      wsh[j*520 + kc + kk] = f2bs(w[(size_t)(kc + kk)*16 + j]);
  }
  __syncthreads();
  const int r = tid >> 4, j = tid & 15;
  float s = 0.f;
  for (int k = 0; k < EE; k += 8){
    short8 xv = *(const short8*)&xsh[r*520 + k];
    short8 wv = *(const short8*)&wsh[j*520 + k];
    #pragma unroll
    for (int e = 0; e < 8; ++e)
      s += bs2f((unsigned short)xv[e]) * bs2f((unsigned short)wv[e]);
  }
  outp[(size_t)(row0 + r)*16 + j] = s + bias[j];
}

// ---------------- orchestration ----------------
extern "C" void kernel_launch(void* const* d_in, const int* in_sizes, int n_in,
                              void* d_out, int out_size, void* d_ws, size_t ws_size,
                              hipStream_t stream)
{
  const float* obs     = (const float*)d_in[0];
  const float* action  = (const float*)d_in[1];
  const float* enc_hs  = (const float*)d_in[2];
  const float* dec_hs1 = (const float*)d_in[3];
  const float* dec_hs2 = (const float*)d_in[4];
  const int*   stepc   = (const int*)d_in[5];
  const float* eoln = (const float*)d_in[6];
  const float* eow  = (const float*)d_in[7];
  const float* eln  = (const float*)d_in[8];
  const float* ewq  = (const float*)d_in[9];
  const float* ewk  = (const float*)d_in[10];
  const float* ewv  = (const float*)d_in[11];
  const float* ewo  = (const float*)d_in[12];
  const float* eln1 = (const float*)d_in[13];
  const float* eln2 = (const float*)d_in[14];
  const float* efg  = (const float*)d_in[15];
  const float* efp  = (const float*)d_in[16];
  const float* ehw1 = (const float*)d_in[17];
  const float* ehb1 = (const float*)d_in[18];
  const float* ehln = (const float*)d_in[19];
  const float* ehw2 = (const float*)d_in[20];
  const float* ehb2 = (const float*)d_in[21];
  const float* daw  = (const float*)d_in[22];
  const float* dln  = (const float*)d_in[23];
  const float* dwq1 = (const float*)d_in[24];
  const float* dwk1 = (const float*)d_in[25];
  const float* dwv1 = (const float*)d_in[26];
  const float* dwo1 = (const float*)d_in[27];
  const float* dwq2 = (const float*)d_in[28];
  const float* dwk2 = (const float*)d_in[29];
  const float* dwv2 = (const float*)d_in[30];
  const float* dwo2 = (const float*)d_in[31];
  const float* dln1 = (const float*)d_in[32];
  const float* dln2 = (const float*)d_in[33];
  const float* dln3 = (const float*)d_in[34];
  const float* dfg  = (const float*)d_in[35];
  const float* dfp  = (const float*)d_in[36];
  const float* dhw1 = (const float*)d_in[37];
  const float* dhb1 = (const float*)d_in[38];
  const float* dhln = (const float*)d_in[39];
  const float* dhw2 = (const float*)d_in[40];
  const float* dhb2 = (const float*)d_in[41];

  const size_t BUF = (size_t)MM*EE;
  const size_t PART = (size_t)BB*HH*2*DH*DH;   // 2 m-halves
  // fp32 region
  float* wsf  = (float*)d_ws;
  float* f32a = wsf;              // wo-out / gate / gelu head / obs_rep
  float* f32b = f32a + BUF;       // proj
  float* part = f32b + BUF;
  float* tmx  = part + PART;
  // bf16 region
  unsigned short* ub = (unsigned short*)(tmx + 64);
  unsigned short* xrep_b    = ub;  ub += BUF;
  unsigned short* xrep_pe_b = ub;  ub += BUF;
  unsigned short* x_b       = ub;  ub += BUF;
  unsigned short* x_pe_b    = ub;  ub += BUF;
  unsigned short* t1_b      = ub;  ub += BUF;
  unsigned short* t1_pe_b   = ub;  ub += BUF;
  unsigned short* peb       = ub;  ub += BUF;
  unsigned short* q_b       = ub;  ub += BUF;
  unsigned short* k_b       = ub;  ub += BUF;
  unsigned short* v_b       = ub;  ub += BUF;
  unsigned short* vT_b      = ub;  ub += BUF;   // [B][H][64][512]
  unsigned short* obs_n     = ub;  ub += (size_t)MM*OBSD;
  unsigned short* act_b     = obs_n;            // aliased (obs_n dead by decoder embed)
  // weights
  const size_t W55 = (size_t)EE*EE;
  unsigned short* wts = ub;  ub += 50*W55;
  unsigned short* wt_eow = ub; ub += (size_t)EE*OBSD;
  unsigned short* wt_daw = ub; ub += (size_t)EE*64;
  size_t need = (char*)ub - (char*)d_ws;
  if (ws_size < need) return;

  unsigned short* wt_ewq  = wts + 0*W55;
  unsigned short* wt_ewk  = wts + 3*W55;
  unsigned short* wt_ewv  = wts + 6*W55;
  unsigned short* wt_ewo  = wts + 9*W55;
  unsigned short* wt_efg  = wts + 12*W55;
  unsigned short* wt_efp  = wts + 15*W55;
  unsigned short* wt_ehw1 = wts + 18*W55;
  unsigned short* wt_dwq1 = wts + 19*W55;
  unsigned short* wt_dwk1 = wts + 22*W55;
  unsigned short* wt_dwv1 = wts + 25*W55;
  unsigned short* wt_dwo1 = wts + 28*W55;
  unsigned short* wt_dwq2 = wts + 31*W55;
  unsigned short* wt_dwk2 = wts + 34*W55;
  unsigned short* wt_dwv2 = wts + 37*W55;
  unsigned short* wt_dwo2 = wts + 40*W55;
  unsigned short* wt_dfg  = wts + 43*W55;
  unsigned short* wt_dfp  = wts + 46*W55;
  unsigned short* wt_dhw1 = wts + 49*W55;

  float* out        = (float*)d_out;
  float* value_out  = out;
  float* logits_out = out + 8192;
  float* enc_out    = logits_out + (size_t)MM*16;
  float* d1_out     = enc_out + (size_t)BB*LL*HH*DH*DH;
  float* d2_out     = d1_out  + (size_t)BB*LL*HH*DH*DH;

  const size_t HS_L = (size_t)HH*DH*DH;

  {
    TP50 tp;
    const float* srcs[18] = {ewq, ewk, ewv, ewo, efg, efp, ehw1,
                             dwq1, dwk1, dwv1, dwo1, dwq2, dwk2, dwv2, dwo2, dfg, dfp, dhw1};
    const int cnt[18] = {3,3,3,3,3,3,1, 3,3,3,3,3,3,3,3,3,3,1};
    int z = 0;
    for (int i = 0; i < 18; ++i)
      for (int j = 0; j < cnt[i]; ++j){
        tp.s[z] = srcs[i] + (size_t)j*W55;
        tp.d[z] = wts + (size_t)z*W55;
        ++z;
      }
    wtpose_batch_kernel<<<dim3(16,16,50), dim3(32,8), 0, stream>>>(tp);
  }
  wtpose_kernel<<<dim3(4,16), dim3(32,8), 0, stream>>>(eow, wt_eow, OBSD, OBSD);
  wtpose_kernel<<<dim3(2,16), dim3(32,8), 0, stream>>>(daw, wt_daw, ACTD, 64);

  pe_kernel<<<(MM*EE)/256, 256, 0, stream>>>(stepc, peb);
  tsmax_kernel<<<BB, 256, 0, stream>>>(stepc, tmx);

  auto gemmF = [&](const unsigned short* A, const unsigned short* Wt, const float* bias,
                   float* C, int Kpad, float scale, int act){
    gemm_b_kernel<<<dim3(EE/64, MM/128), 256, 0, stream>>>(A, Wt, bias, C, nullptr, nullptr, Kpad, scale, act);
  };
  auto gemmB = [&](const unsigned short* A, const unsigned short* Wt,
                   unsigned short* Cb, int Kpad, float scale){
    gemm_b_kernel<<<dim3(EE/64, MM/128), 256, 0, stream>>>(A, Wt, nullptr, nullptr, Cb, nullptr, Kpad, scale, ACT_NONE);
  };
  auto gemmBT = [&](const unsigned short* A, const unsigned short* Wt,
                    unsigned short* Cb, unsigned short* CT, int Kpad, float scale){
    gemm_b_kernel<<<dim3(EE/64, MM/128), 256, 0, stream>>>(A, Wt, nullptr, nullptr, Cb, CT, Kpad, scale, ACT_NONE);
  };
  auto norm = [&](const float* af, const unsigned short* ab, const float* res,
                  const float* g, const float* p, const float* w,
                  unsigned short* o1, unsigned short* o2, int mode){
    norm_b_kernel<<<MM, 256, 0, stream>>>(af, ab, res, g, p, w, o1, o2, peb, mode);
  };
  auto retention = [&](const float* h0, unsigned short* o, int masked){
    retention_kernel<<<dim3(8, HH, BB), 256, 0, stream>>>(q_b, k_b, vT_b, h0, stepc, o, masked);
  };
  auto hstate = [&](const float* h0, float* o){
    hstate_partial_kernel<<<dim3(2,HH,BB), 256, 0, stream>>>(k_b, v_b, stepc, tmx, part);
    hstate_final_kernel<<<2048, 256, 0, stream>>>(part, h0, tmx, o);
  };

  // ---- encoder embed ----
  norm_obs_kernel<<<MM, 128, 0, stream>>>(obs, eoln, obs_n);
  gemmF(obs_n, wt_eow, nullptr, f32a, OBSD, 1.f, ACT_GELU);   // f32a = obs_rep

  // ---- encoder layers ----
  for (int i = 0; i < LL; ++i){
    if (i == 0) norm(f32a, nullptr, nullptr, nullptr, nullptr, eln, x_b, x_pe_b, NORM_PLAIN);
    else        norm(nullptr, xrep_b, nullptr, nullptr, nullptr, eln, x_b, x_pe_b, NORM_PLAIN);
    gemmB (x_pe_b, wt_ewq + i*W55, q_b, EE, 1.f);
    gemmB (x_pe_b, wt_ewk + i*W55, k_b, EE, INV_SQRT_D);
    gemmBT(x_pe_b, wt_ewv + i*W55, v_b, vT_b, EE, 1.f);
    retention(enc_hs + i*HS_L, t1_b, 0);
    hstate(enc_hs + i*HS_L, enc_out + i*HS_L);
    gemmF(t1_b, wt_ewo + i*W55, nullptr, f32a, EE, 1.f, ACT_NONE);
    norm(nullptr, x_b, f32a, nullptr, nullptr, eln1 + i*EE, t1_b, nullptr, NORM_ADD);
    gemmF(t1_b, wt_efg + i*W55, nullptr, f32a, EE, 1.f, ACT_NONE);
    gemmF(t1_b, wt_efp + i*W55, nullptr, f32b, EE, 1.f, ACT_NONE);
    norm(nullptr, t1_b, nullptr, f32a, f32b, eln2 + i*EE, xrep_b, xrep_pe_b, NORM_SWIGLU);
  }

  // ---- value head ----
  gemmF(xrep_b, wt_ehw1, ehb1, f32a, EE, 1.f, ACT_GELU);
  norm(f32a, nullptr, nullptr, nullptr, nullptr, ehln, t1_b, nullptr, NORM_PLAIN);
  value_head_kernel<<<MM/32, 256, 0, stream>>>(t1_b, ehw2, ehb2, value_out);

  // ---- decoder embed ----
  act_embed_kernel<<<(MM*64)/256, 256, 0, stream>>>(action, act_b);
  gemmF(act_b, wt_daw, nullptr, f32a, 64, 1.f, ACT_GELU);
  norm(f32a, nullptr, nullptr, nullptr, nullptr, dln, x_b, x_pe_b, NORM_PLAIN);

  // ---- decoder layers ----
  for (int i = 0; i < LL; ++i){
    gemmB (x_pe_b, wt_dwq1 + i*W55, q_b, EE, 1.f);
    gemmB (x_pe_b, wt_dwk1 + i*W55, k_b, EE, INV_SQRT_D);
    gemmBT(x_pe_b, wt_dwv1 + i*W55, v_b, vT_b, EE, 1.f);
    retention(dec_hs1 + i*HS_L, t1_b, 1);
    hstate(dec_hs1 + i*HS_L, d1_out + i*HS_L);
    gemmF(t1_b, wt_dwo1 + i*W55, nullptr, f32a, EE, 1.f, ACT_NONE);
    norm(nullptr, x_b, f32a, nullptr, nullptr, dln1 + i*EE, t1_b, t1_pe_b, NORM_ADD);   // r
    gemmB (xrep_pe_b, wt_dwq2 + i*W55, q_b, EE, 1.f);
    gemmB (t1_pe_b,   wt_dwk2 + i*W55, k_b, EE, INV_SQRT_D);
    gemmBT(t1_pe_b,   wt_dwv2 + i*W55, v_b, vT_b, EE, 1.f);
    retention(dec_hs2 + i*HS_L, t1_b, 1);
    hstate(dec_hs2 + i*HS_L, d2_out + i*HS_L);
    gemmF(t1_b, wt_dwo2 + i*W55, nullptr, f32a, EE, 1.f, ACT_NONE);
    norm(nullptr, xrep_b, f32a, nullptr, nullptr, dln2 + i*EE, x_b, nullptr, NORM_ADD); // y
    gemmF(x_b, wt_dfg + i*W55, nullptr, f32a, EE, 1.f, ACT_NONE);
    gemmF(x_b, wt_dfp + i*W55, nullptr, f32b, EE, 1.f, ACT_NONE);
    norm(nullptr, x_b, nullptr, f32a, f32b, dln3 + i*EE, x_b, x_pe_b, NORM_SWIGLU);
  }

  // ---- logits head ----
  gemmF(x_b, wt_dhw1, dhb1, f32a, EE, 1.f, ACT_GELU);
  norm(f32a, nullptr, nullptr, nullptr, nullptr, dhln, t1_b, nullptr, NORM_PLAIN);
  logits_head_kernel<<<MM/16, 256, 0, stream>>>(t1_b, dhw2, dhb2, logits_out);
}

// Round 2
// 1664.568 us; speedup vs baseline: 1.0706x; 1.0550x over previous
//
#include <hip/hip_runtime.h>
#include <hip/hip_bf16.h>
#include <math.h>

typedef __attribute__((ext_vector_type(8))) short short8;     // 8 bf16 = 4 VGPRs
typedef __attribute__((ext_vector_type(4))) short short4v;    // 4 bf16 = 8B
typedef __attribute__((ext_vector_type(4))) float f32x4;

#define BB 16
#define SS 512
#define EE 512
#define HH 8
#define DH 64
#define LL 3
#define MM (BB*SS)
#define OBSD 128
#define ACTD 17
#define INV_SQRT_D 0.125f

#define ACT_NONE 0
#define ACT_GELU 1

#define NORM_PLAIN 0
#define NORM_ADD 1
#define NORM_SWIGLU 2

__device__ __forceinline__ float gelu_f(float x){
  float x3 = x*x*x;
  return 0.5f*x*(1.f + tanhf(0.7978845608028654f*(x + 0.044715f*x3)));
}
__device__ __forceinline__ float silu_f(float x){ return x/(1.f+expf(-x)); }
__device__ __forceinline__ float lkappa(int h){ return logf(1.f - exp2f(-5.f - (float)h)); }
__device__ __forceinline__ unsigned short f2bs(float f){
  unsigned int u = __float_as_uint(f);
  u += 0x7FFFu + ((u >> 16) & 1u);
  return (unsigned short)(u >> 16);
}
__device__ __forceinline__ float bs2f(unsigned short u){
  return __uint_as_float(((unsigned int)u) << 16);
}

// ---------------- weight transpose: W[K][512] fp32 -> Wt[512][Kpad] bf16 ----------------
__global__ __launch_bounds__(256) void wtpose_kernel(
    const float* __restrict__ src, unsigned short* __restrict__ dst, int K, int Kpad)
{
  __shared__ float t[32][33];
  const int gx = blockIdx.x, gy = blockIdx.y;
  const int tx = threadIdx.x, ty = threadIdx.y;
  #pragma unroll
  for (int i = 0; i < 4; ++i){
    int k = gx*32 + ty + i*8, n = gy*32 + tx;
    t[ty+i*8][tx] = (k < K) ? src[(size_t)k*EE + n] : 0.f;
  }
  __syncthreads();
  #pragma unroll
  for (int i = 0; i < 4; ++i){
    int k = gx*32 + tx, n = gy*32 + ty + i*8;
    dst[(size_t)n*Kpad + k] = f2bs(t[tx][ty+i*8]);
  }
}

struct TP50 { const float* s[50]; unsigned short* d[50]; };
__global__ __launch_bounds__(256) void wtpose_batch_kernel(TP50 tp)
{
  __shared__ float t[32][33];
  const float* src = tp.s[blockIdx.z];
  unsigned short* dst = tp.d[blockIdx.z];
  const int gx = blockIdx.x, gy = blockIdx.y;
  const int tx = threadIdx.x, ty = threadIdx.y;
  #pragma unroll
  for (int i = 0; i < 4; ++i){
    int k = gx*32 + ty + i*8, n = gy*32 + tx;
    t[ty+i*8][tx] = src[(size_t)k*EE + n];
  }
  __syncthreads();
  #pragma unroll
  for (int i = 0; i < 4; ++i){
    int k = gx*32 + tx, n = gy*32 + ty + i*8;
    dst[(size_t)n*EE + k] = f2bs(t[tx][ty+i*8]);
  }
}

// ---------------- MFMA GEMM ----------------
// outputs: fp32 C and/or bf16 Cb and/or per-head transposed CT.
// decay mode (tsi != null): writes lo/hi scaled bf16 outputs (normal and/or per-head
// transposed layouts). lo scale = exp(dsign*lk[h]*ts[row]), hi = reciprocal.
// head is block-uniform (bn is 64-aligned, head width = 64).
__global__ __launch_bounds__(256) void gemm_b_kernel(
    const unsigned short* __restrict__ A, const unsigned short* __restrict__ Wt,
    const float* __restrict__ bias, float* __restrict__ C,
    unsigned short* __restrict__ Cb, unsigned short* __restrict__ CT,
    int Kpad, float scale, int act,
    const int* __restrict__ tsi, float dsign,
    unsigned short* __restrict__ lo_n, unsigned short* __restrict__ lo_t,
    unsigned short* __restrict__ hi_n, unsigned short* __restrict__ hi_t)
{
  __shared__ unsigned short As[128*72];
  __shared__ unsigned short Bs[64*72];
  const int bm = blockIdx.y*128, bn = blockIdx.x*64;
  const int tid = threadIdx.x, lane = tid & 63, wv = tid >> 6;
  const int wr = wv >> 1, wc = wv & 1;
  const int l16 = lane & 15, quad = lane >> 4;

  f32x4 acc[4][2];
  #pragma unroll
  for (int i=0;i<4;i++){ acc[i][0]=(f32x4)(0.f); acc[i][1]=(f32x4)(0.f); }

  const int arow = tid >> 1, acol = (tid & 1)*32;
  const int brow = tid >> 2, bcol = (tid & 3)*16;

  for (int k0 = 0; k0 < Kpad; k0 += 64){
    const unsigned short* ag = A + (size_t)(bm+arow)*Kpad + k0 + acol;
    #pragma unroll
    for (int i=0;i<4;i++)
      *(short8*)&As[arow*72 + acol + i*8] = *(const short8*)(ag + i*8);
    const unsigned short* bg = Wt + (size_t)(bn+brow)*Kpad + k0 + bcol;
    #pragma unroll
    for (int i=0;i<2;i++)
      *(short8*)&Bs[brow*72 + bcol + i*8] = *(const short8*)(bg + i*8);
    __syncthreads();
    short8 af[4][2], bf[2][2];
    #pragma unroll
    for (int mt=0; mt<4; ++mt)
      #pragma unroll
      for (int ks=0; ks<2; ++ks)
        af[mt][ks] = *(const short8*)&As[(wr*64 + mt*16 + l16)*72 + ks*32 + quad*8];
    #pragma unroll
    for (int nt=0; nt<2; ++nt)
      #pragma unroll
      for (int ks=0; ks<2; ++ks)
        bf[nt][ks] = *(const short8*)&Bs[(wc*32 + nt*16 + l16)*72 + ks*32 + quad*8];
    #pragma unroll
    for (int ks=0; ks<2; ++ks)
      #pragma unroll
      for (int mt=0; mt<4; ++mt)
        #pragma unroll
        for (int nt=0; nt<2; ++nt)
          acc[mt][nt] = __builtin_amdgcn_mfma_f32_16x16x32_bf16(af[mt][ks], bf[nt][ks], acc[mt][nt], 0, 0, 0);
    __syncthreads();
  }
  const float lkh = tsi ? lkappa(bn >> 6) : 0.f;
  #pragma unroll
  for (int mt=0; mt<4; ++mt){
    int rb = bm + wr*64 + mt*16 + quad*4;
    float e0[4], e1[4];
    if (tsi){
      #pragma unroll
      for (int j=0;j<4;j++){
        float x = dsign*lkh*(float)tsi[rb+j];
        e0[j] = __expf(x); e1[j] = __expf(-x);
      }
    }
    #pragma unroll
    for (int nt=0; nt<2; ++nt){
      int col = bn + wc*32 + nt*16 + l16;
      float bv = bias ? bias[col] : 0.f;
      float vals[4];
      #pragma unroll
      for (int j=0;j<4;j++){
        float v = acc[mt][nt][j]*scale + bv;
        if (act==ACT_GELU) v = gelu_f(v);
        vals[j] = v;
      }
      int bloc = rb >> 9, m0 = rb & 511;
      int hh = col >> 6, ee = col & 63;
      size_t taddr = (((size_t)bloc*HH + hh)*DH + ee)*SS + m0;
      if (C){
        #pragma unroll
        for (int j=0;j<4;j++) C[(size_t)(rb+j)*EE + col] = vals[j];
      }
      if (Cb){
        #pragma unroll
        for (int j=0;j<4;j++) Cb[(size_t)(rb+j)*EE + col] = f2bs(vals[j]);
      }
      if (CT){
        short4v pk;
        #pragma unroll
        for (int j=0;j<4;j++) pk[j] = (short)f2bs(vals[j]);
        *(short4v*)&CT[taddr] = pk;
      }
      if (tsi){
        if (lo_n){
          #pragma unroll
          for (int j=0;j<4;j++) lo_n[(size_t)(rb+j)*EE + col] = f2bs(vals[j]*e0[j]);
        }
        if (lo_t){
          short4v pk;
          #pragma unroll
          for (int j=0;j<4;j++) pk[j] = (short)f2bs(vals[j]*e0[j]);
          *(short4v*)&lo_t[taddr] = pk;
        }
        if (hi_n){
          #pragma unroll
          for (int j=0;j<4;j++) hi_n[(size_t)(rb+j)*EE + col] = f2bs(vals[j]*e1[j]);
        }
        if (hi_t){
          short4v pk;
          #pragma unroll
          for (int j=0;j<4;j++) pk[j] = (short)f2bs(vals[j]*e1[j]);
          *(short4v*)&hi_t[taddr] = pk;
        }
      }
    }
  }
}

// ---------------- rmsnorm: mixed fp32/bf16 input -> bf16 out (+ optional out+pe) ----------------
__global__ __launch_bounds__(256) void norm_b_kernel(
    const float* __restrict__ af, const unsigned short* __restrict__ ab,
    const float* __restrict__ res, const float* __restrict__ g, const float* __restrict__ p,
    const float* __restrict__ w, unsigned short* __restrict__ o1,
    unsigned short* __restrict__ o2, const unsigned short* __restrict__ peb,
    int mode)
{
  __shared__ float red[4];
  const int row = blockIdx.x, tid = threadIdx.x;
  const size_t base = (size_t)row*EE + tid*2;
  float t0, t1;
  if (ab){
    unsigned int av = *(const unsigned int*)&ab[base];
    t0 = bs2f((unsigned short)(av & 0xffffu));
    t1 = bs2f((unsigned short)(av >> 16));
  } else {
    float2 av = *(const float2*)&af[base];
    t0 = av.x; t1 = av.y;
  }
  if (mode == NORM_ADD){
    float2 rv = *(const float2*)&res[base];
    t0 += rv.x; t1 += rv.y;
  } else if (mode == NORM_SWIGLU){
    float2 gv = *(const float2*)&g[base];
    float2 pv = *(const float2*)&p[base];
    t0 += silu_f(gv.x)*pv.x; t1 += silu_f(gv.y)*pv.y;
  }
  float ss = t0*t0 + t1*t1;
  #pragma unroll
  for (int o=32;o;o>>=1) ss += __shfl_down(ss,o);
  if ((tid&63)==0) red[tid>>6]=ss;
  __syncthreads();
  if (tid==0) red[0] = 1.f/sqrtf((red[0]+red[1]+red[2]+red[3])/(float)EE + 1e-6f);
  __syncthreads();
  float r = red[0];
  float2 wv2 = *(const float2*)&w[tid*2];
  float y0 = t0*r*wv2.x, y1 = t1*r*wv2.y;
  unsigned int pk = (unsigned int)f2bs(y0) | ((unsigned int)f2bs(y1) << 16);
  *(unsigned int*)&o1[base] = pk;
  if (o2){
    unsigned int pv = *(const unsigned int*)&peb[base];
    float z0 = y0 + bs2f((unsigned short)(pv & 0xffffu));
    float z1 = y1 + bs2f((unsigned short)(pv >> 16));
    *(unsigned int*)&o2[base] = (unsigned int)f2bs(z0) | ((unsigned int)f2bs(z1) << 16);
  }
}

// obs norm: fp32 [MM][128] -> bf16
__global__ __launch_bounds__(128) void norm_obs_kernel(
    const float* __restrict__ a, const float* __restrict__ w, unsigned short* __restrict__ o)
{
  __shared__ float red[2];
  const int row = blockIdx.x, tid = threadIdx.x;
  float t = a[(size_t)row*OBSD + tid];
  float ss = t*t;
  #pragma unroll
  for (int off=32;off;off>>=1) ss += __shfl_down(ss,off);
  if ((tid&63)==0) red[tid>>6]=ss;
  __syncthreads();
  if (tid==0) red[0] = 1.f/sqrtf((red[0]+red[1])/(float)OBSD + 1e-6f);
  __syncthreads();
  o[(size_t)row*OBSD + tid] = f2bs(t*red[0]*w[tid]);
}

// action embed: fp32 [MM][17] -> bf16 [MM][64] zero-padded
__global__ __launch_bounds__(256) void act_embed_kernel(
    const float* __restrict__ a, unsigned short* __restrict__ o)
{
  int idx = blockIdx.x*256 + threadIdx.x;
  int row = idx >> 6, col = idx & 63;
  o[idx] = (col < ACTD) ? f2bs(a[(size_t)row*ACTD + col]) : 0;
}

// ---------------- chunk state: Wc_lo[e][d] = sum_m vT[e][m]*kloT[d][m] (fp32),
//                  encoder also Wc_hi with khiT (bf16 out) ----------------
__global__ __launch_bounds__(256) void wchunk_kernel(
    const unsigned short* __restrict__ kloT, const unsigned short* __restrict__ khiT,
    const unsigned short* __restrict__ vT,
    float* __restrict__ wlo, unsigned short* __restrict__ whi, int enc)
{
  __shared__ unsigned short vsh[64*72];
  __shared__ unsigned short ksh[64*72];
  __shared__ unsigned short ksh2[64*72];
  const int c = blockIdx.x, h = blockIdx.y, b = blockIdx.z;
  const int tid = threadIdx.x, lane = tid & 63, wv = tid >> 6;
  const int quad = lane >> 4, l16 = lane & 15;
  const int mc = c*64;
  {
    const int r = tid >> 2, seg = (tid & 3)*16;
    const unsigned short* vrow = vT   + (((size_t)b*HH + h)*DH + r)*SS + mc + seg;
    const unsigned short* krow = kloT + (((size_t)b*HH + h)*DH + r)*SS + mc + seg;
    #pragma unroll
    for (int i = 0; i < 2; ++i){
      *(short8*)&vsh[r*72 + seg + i*8] = *(const short8*)(vrow + i*8);
      *(short8*)&ksh[r*72 + seg + i*8] = *(const short8*)(krow + i*8);
    }
    if (enc){
      const unsigned short* k2row = khiT + (((size_t)b*HH + h)*DH + r)*SS + mc + seg;
      #pragma unroll
      for (int i = 0; i < 2; ++i)
        *(short8*)&ksh2[r*72 + seg + i*8] = *(const short8*)(k2row + i*8);
    }
  }
  __syncthreads();
  short8 av[2];
  #pragma unroll
  for (int ks=0; ks<2; ++ks)
    av[ks] = *(const short8*)&vsh[(wv*16 + l16)*72 + ks*32 + quad*8];
  f32x4 acc[4];
  #pragma unroll
  for (int dt=0; dt<4; ++dt) acc[dt] = (f32x4)(0.f);
  #pragma unroll
  for (int ks=0; ks<2; ++ks)
    #pragma unroll
    for (int dt=0; dt<4; ++dt){
      short8 kb = *(const short8*)&ksh[(dt*16 + l16)*72 + ks*32 + quad*8];
      acc[dt] = __builtin_amdgcn_mfma_f32_16x16x32_bf16(av[ks], kb, acc[dt], 0, 0, 0);
    }
  size_t obase = (((size_t)b*HH + h)*8 + c)*4096;
  #pragma unroll
  for (int dt=0; dt<4; ++dt)
    #pragma unroll
    for (int j=0;j<4;j++)
      wlo[obase + (size_t)(wv*16 + quad*4 + j)*64 + dt*16 + l16] = acc[dt][j];
  if (enc){
    f32x4 acc2[4];
    #pragma unroll
    for (int dt=0; dt<4; ++dt) acc2[dt] = (f32x4)(0.f);
    #pragma unroll
    for (int ks=0; ks<2; ++ks)
      #pragma unroll
      for (int dt=0; dt<4; ++dt){
        short8 kb = *(const short8*)&ksh2[(dt*16 + l16)*72 + ks*32 + quad*8];
        acc2[dt] = __builtin_amdgcn_mfma_f32_16x16x32_bf16(av[ks], kb, acc2[dt], 0, 0, 0);
      }
    #pragma unroll
    for (int dt=0; dt<4; ++dt)
      #pragma unroll
      for (int j=0;j<4;j++)
        whi[obase + (size_t)(wv*16 + quad*4 + j)*64 + dt*16 + l16] = f2bs(acc2[dt][j]);
  }
}

// ---------------- scan: Wcum_lo[t] = elk*h0^T + sum_{c<t} Wc_lo (bf16),
//                  h_new = e^{lk*tm} * (elk*h0^T + sum_all Wc_lo),
//                  encoder: Wcum_hi[t] = sum_{c>t} Wc_hi (in-place) ----------------
__global__ __launch_bounds__(256) void wscan_kernel(
    const float* __restrict__ wc, unsigned short* __restrict__ wcum,
    unsigned short* whi,
    const float* __restrict__ h0, const float* __restrict__ tmx,
    float* __restrict__ hnew, int enc)
{
  const int bh = blockIdx.x, b = bh >> 3, h = bh & 7;
  const float lk = lkappa(h);
  const float elk = __expf(lk);
  const float etm = __expf(lk*tmx[b]);
  const size_t wbase = (size_t)bh*8*4096;
  const size_t hbase = (size_t)b*(LL*HH*DH*DH) + (size_t)h*(DH*DH);
  for (int i = 0; i < 16; ++i){
    int p = i*256 + threadIdx.x;        // p = e*64 + d
    int e = p >> 6, d = p & 63;
    float acc = elk * h0[hbase + d*64 + e];
    #pragma unroll
    for (int c = 0; c < 8; ++c){
      float reg = wc[wbase + c*4096 + p];
      wcum[wbase + c*4096 + p] = f2bs(acc);
      acc += reg;
    }
    hnew[hbase + d*64 + e] = etm * acc;
    if (enc){
      float a2 = 0.f;
      #pragma unroll
      for (int c = 7; c >= 0; --c){
        float reg = bs2f(whi[wbase + c*4096 + p]);
        whi[wbase + c*4096 + p] = f2bs(a2);
        a2 += reg;
      }
    }
  }
}

// ---------------- retention (chunked-recurrent): out = Qlo@Wcum_lo[t]
//                  (+ Qhi@Wcum_hi[t] enc) + boundary diag chunk(s) ----------------
template<int ENC>
__global__ __launch_bounds__(256) void retention2_kernel(
    const unsigned short* __restrict__ qlo, const unsigned short* __restrict__ qhi,
    const unsigned short* __restrict__ klo, const unsigned short* __restrict__ khi,
    const unsigned short* __restrict__ vT,
    const unsigned short* __restrict__ wlo, const unsigned short* __restrict__ whi,
    const int* __restrict__ tsi, unsigned short* __restrict__ outp)
{
  __shared__ unsigned short qsh[64*72];        // reused as psh in boundary
  __shared__ unsigned short wsh[64*72];
  __shared__ unsigned short ksh[64*72];
  __shared__ unsigned short vsh[64*72];
  __shared__ unsigned short qsh2[ENC ? 64*72 : 2];  // reused as ksh2 in boundary
  __shared__ unsigned short wsh2[ENC ? 64*72 : 2];
  __shared__ float tsf[SS];
  const int b = blockIdx.z, h = blockIdx.y, t = blockIdx.x;
  const int n0 = t*64;
  const int tid = threadIdx.x, lane = tid & 63, wv = tid >> 6;
  const int quad = lane >> 4, l16 = lane & 15;

  for (int i = tid; i < SS; i += 256) tsf[i] = (float)tsi[b*SS + i];
  {
    const int n = tid >> 2, seg = (tid & 3)*16;
    const unsigned short* qr = qlo + ((size_t)b*SS + n0 + n)*EE + h*DH + seg;
    #pragma unroll
    for (int i = 0; i < 2; ++i)
      *(short8*)&qsh[n*72 + seg + i*8] = *(const short8*)(qr + i*8);
    const unsigned short* wr = wlo + (((size_t)b*HH + h)*8 + t)*4096 + (size_t)n*64 + seg;
    #pragma unroll
    for (int i = 0; i < 2; ++i)
      *(short8*)&wsh[n*72 + seg + i*8] = *(const short8*)(wr + i*8);
    if (ENC){
      const unsigned short* qr2 = qhi + ((size_t)b*SS + n0 + n)*EE + h*DH + seg;
      #pragma unroll
      for (int i = 0; i < 2; ++i)
        *(short8*)&qsh2[n*72 + seg + i*8] = *(const short8*)(qr2 + i*8);
      const unsigned short* wr2 = whi + (((size_t)b*HH + h)*8 + t)*4096 + (size_t)n*64 + seg;
      #pragma unroll
      for (int i = 0; i < 2; ++i)
        *(short8*)&wsh2[n*72 + seg + i*8] = *(const short8*)(wr2 + i*8);
    }
  }
  __syncthreads();

  const int rowbase = wv*16;
  short8 qa[2], qa2[2];
  #pragma unroll
  for (int ks=0; ks<2; ++ks)
    qa[ks] = *(const short8*)&qsh[(rowbase + l16)*72 + ks*32 + quad*8];
  if (ENC){
    #pragma unroll
    for (int ks=0; ks<2; ++ks)
      qa2[ks] = *(const short8*)&qsh2[(rowbase + l16)*72 + ks*32 + quad*8];
  }

  float tn = tsf[n0 + lane];
  float maxn = tn, minn = tn;
  #pragma unroll
  for (int o=32;o;o>>=1){
    maxn = fmaxf(maxn, __shfl_xor(maxn, o));
    minn = fminf(minn, __shfl_xor(minn, o));
  }

  // cross-chunk + h0 contribution: Qlo @ Wcum_lo (+ Qhi @ Wcum_hi)
  f32x4 acc_o[4];
  #pragma unroll
  for (int et=0; et<4; ++et){
    f32x4 a = (f32x4)(0.f);
    #pragma unroll
    for (int ks=0; ks<2; ++ks){
      short8 wb = *(const short8*)&wsh[(et*16 + l16)*72 + ks*32 + quad*8];
      a = __builtin_amdgcn_mfma_f32_16x16x32_bf16(qa[ks], wb, a, 0, 0, 0);
    }
    if (ENC){
      #pragma unroll
      for (int ks=0; ks<2; ++ks){
        short8 wb2 = *(const short8*)&wsh2[(et*16 + l16)*72 + ks*32 + quad*8];
        a = __builtin_amdgcn_mfma_f32_16x16x32_bf16(qa2[ks], wb2, a, 0, 0, 0);
      }
    }
    acc_o[et] = a;
  }

  // boundary chunk(s)
  for (int c = 0; c < 8; ++c){
    const int mc = c*64;
    float tmv = tsf[mc + lane];
    float maxm = tmv, minm = tmv;
    #pragma unroll
    for (int o=32;o;o>>=1){
      maxm = fmaxf(maxm, __shfl_xor(maxm, o));
      minm = fminf(minm, __shfl_xor(minm, o));
    }
    if (ENC){
      if (maxm <= minn) continue;   // fully lower -> in Wcum_lo
      if (minm >= maxn) continue;   // fully upper -> in Wcum_hi
    } else {
      if ((maxm < minn) || (maxm == minn && (mc + 63) < n0)) continue; // full -> in Wcum_lo
      if (minm > maxn) continue;    // fully masked
    }
    __syncthreads();
    {
      const int m = tid >> 2, cb = (tid & 3)*16;
      const unsigned short* krow = klo + ((size_t)b*SS + mc + m)*EE + h*DH + cb;
      #pragma unroll
      for (int i = 0; i < 2; ++i)
        *(short8*)&ksh[m*72 + cb + i*8] = *(const short8*)(krow + i*8);
      const unsigned short* vrow = vT + (((size_t)b*HH + h)*DH + m)*SS + mc + cb;
      #pragma unroll
      for (int i = 0; i < 2; ++i)
        *(short8*)&vsh[m*72 + cb + i*8] = *(const short8*)(vrow + i*8);
      if (ENC){
        const unsigned short* k2row = khi + ((size_t)b*SS + mc + m)*EE + h*DH + cb;
        #pragma unroll
        for (int i = 0; i < 2; ++i)
          *(short8*)&qsh2[m*72 + cb + i*8] = *(const short8*)(k2row + i*8);
      }
    }
    __syncthreads();
    f32x4 sacc[4], sacc2[4];
    #pragma unroll
    for (int mt=0; mt<4; ++mt){
      f32x4 a = (f32x4)(0.f);
      #pragma unroll
      for (int ks=0; ks<2; ++ks){
        short8 kb = *(const short8*)&ksh[(mt*16 + l16)*72 + ks*32 + quad*8];
        a = __builtin_amdgcn_mfma_f32_16x16x32_bf16(qa[ks], kb, a, 0, 0, 0);
      }
      sacc[mt] = a;
      if (ENC){
        f32x4 a2 = (f32x4)(0.f);
        #pragma unroll
        for (int ks=0; ks<2; ++ks){
          short8 kb2 = *(const short8*)&qsh2[(mt*16 + l16)*72 + ks*32 + quad*8];
          a2 = __builtin_amdgcn_mfma_f32_16x16x32_bf16(qa2[ks], kb2, a2, 0, 0, 0);
        }
        sacc2[mt] = a2;
      }
    }
    float tsm[4]; int mg[4];
    #pragma unroll
    for (int mt=0; mt<4; ++mt){ mg[mt] = mc + mt*16 + l16; tsm[mt] = tsf[mg[mt]]; }
    #pragma unroll
    for (int j=0;j<4;j++){
      int nloc = rowbase + quad*4 + j;
      int n = n0 + nloc;
      float tsn = tsf[n];
      #pragma unroll
      for (int mt=0; mt<4; ++mt){
        float diff = tsn - tsm[mt];
        float p;
        if (ENC) p = (diff >= 0.f) ? sacc[mt][j] : sacc2[mt][j];
        else     p = ((diff > 0.f) || (diff == 0.f && n >= mg[mt])) ? sacc[mt][j] : 0.f;
        qsh[nloc*72 + mt*16 + l16] = f2bs(p);   // qsh reused as psh
      }
    }
    #pragma unroll
    for (int ks=0; ks<2; ++ks){
      short8 pa = *(const short8*)&qsh[(rowbase + l16)*72 + ks*32 + quad*8];
      #pragma unroll
      for (int et=0; et<4; ++et){
        short8 vb = *(const short8*)&vsh[(et*16 + l16)*72 + ks*32 + quad*8];
        acc_o[et] = __builtin_amdgcn_mfma_f32_16x16x32_bf16(pa, vb, acc_o[et], 0, 0, 0);
      }
    }
  }
  #pragma unroll
  for (int j=0;j<4;j++){
    size_t rbase = ((size_t)b*SS + n0 + rowbase + quad*4 + j)*EE + h*DH;
    #pragma unroll
    for (int et=0; et<4; ++et)
      outp[rbase + et*16 + l16] = f2bs(acc_o[et][j]);
  }
}

// ---------------- small helpers ----------------
__global__ void tsmax_kernel(const int* __restrict__ tsi, float* __restrict__ tmx){
  __shared__ int red[4];
  int b = blockIdx.x, tid = threadIdx.x;
  int m = max(tsi[b*SS+tid], tsi[b*SS+256+tid]);
  #pragma unroll
  for (int o=32;o;o>>=1) m = max(m, __shfl_down(m,o));
  if ((tid&63)==0) red[tid>>6]=m;
  __syncthreads();
  if (tid==0) tmx[b] = (float)max(max(red[0],red[1]),max(red[2],red[3]));
}

__global__ void pe_kernel(const int* __restrict__ tsi, unsigned short* __restrict__ peb){
  int idx = blockIdx.x*256 + threadIdx.x;
  int row = idx >> 9, j = idx & 511;
  float ts = (float)tsi[row];
  int jj = j & 255;
  float freq = expf(-9.210340371976184f*(float)jj*(1.f/256.f));
  float ang = ts*freq;
  peb[idx] = f2bs((j < 256) ? sinf(ang) : cosf(ang));
}

__global__ __launch_bounds__(256) void value_head_kernel(
    const unsigned short* __restrict__ x, const float* __restrict__ w,
    const float* __restrict__ bias, float* __restrict__ outp)
{
  const int tid = threadIdx.x, lane = tid & 63, wv = tid >> 6;
  const int r8 = lane >> 3, seg = lane & 7;
  const int row = blockIdx.x*32 + wv*8 + r8;
  const unsigned short* xr = x + (size_t)row*EE + seg*64;
  const float* wr = w + seg*64;
  float s = 0.f;
  #pragma unroll
  for (int i = 0; i < 8; ++i){
    short8 xv = *(const short8*)(xr + i*8);
    #pragma unroll
    for (int e = 0; e < 8; ++e)
      s += bs2f((unsigned short)xv[e]) * wr[i*8 + e];
  }
  s += __shfl_xor(s, 1); s += __shfl_xor(s, 2); s += __shfl_xor(s, 4);
  if (seg == 0) outp[row] = s + bias[0];
}

__global__ __launch_bounds__(256) void logits_head_kernel(
    const unsigned short* __restrict__ x, const float* __restrict__ w,
    const float* __restrict__ bias, float* __restrict__ outp)
{
  __shared__ unsigned short xsh[16*520];
  __shared__ unsigned short wsh[16*520];
  const int tid = threadIdx.x;
  const int row0 = blockIdx.x*16;
  {
    const int r = tid >> 4, kc = (tid & 15)*32;
    const unsigned short* xr = x + (size_t)(row0 + r)*EE + kc;
    #pragma unroll
    for (int i = 0; i < 4; ++i)
      *(short8*)&xsh[r*520 + kc + i*8] = *(const short8*)(xr + i*8);
    const int j = r;
    #pragma unroll
    for (int kk = 0; kk < 32; ++kk)
      wsh[j*520 + kc + kk] = f2bs(w[(size_t)(kc + kk)*16 + j]);
  }
  __syncthreads();
  const int r = tid >> 4, j = tid & 15;
  float s = 0.f;
  for (int k = 0; k < EE; k += 8){
    short8 xv = *(const short8*)&xsh[r*520 + k];
    short8 wv = *(const short8*)&wsh[j*520 + k];
    #pragma unroll
    for (int e = 0; e < 8; ++e)
      s += bs2f((unsigned short)xv[e]) * bs2f((unsigned short)wv[e]);
  }
  outp[(size_t)(row0 + r)*16 + j] = s + bias[j];
}

// ---------------- orchestration ----------------
extern "C" void kernel_launch(void* const* d_in, const int* in_sizes, int n_in,
                              void* d_out, int out_size, void* d_ws, size_t ws_size,
                              hipStream_t stream)
{
  const float* obs     = (const float*)d_in[0];
  const float* action  = (const float*)d_in[1];
  const float* enc_hs  = (const float*)d_in[2];
  const float* dec_hs1 = (const float*)d_in[3];
  const float* dec_hs2 = (const float*)d_in[4];
  const int*   stepc   = (const int*)d_in[5];
  const float* eoln = (const float*)d_in[6];
  const float* eow  = (const float*)d_in[7];
  const float* eln  = (const float*)d_in[8];
  const float* ewq  = (const float*)d_in[9];
  const float* ewk  = (const float*)d_in[10];
  const float* ewv  = (const float*)d_in[11];
  const float* ewo  = (const float*)d_in[12];
  const float* eln1 = (const float*)d_in[13];
  const float* eln2 = (const float*)d_in[14];
  const float* efg  = (const float*)d_in[15];
  const float* efp  = (const float*)d_in[16];
  const float* ehw1 = (const float*)d_in[17];
  const float* ehb1 = (const float*)d_in[18];
  const float* ehln = (const float*)d_in[19];
  const float* ehw2 = (const float*)d_in[20];
  const float* ehb2 = (const float*)d_in[21];
  const float* daw  = (const float*)d_in[22];
  const float* dln  = (const float*)d_in[23];
  const float* dwq1 = (const float*)d_in[24];
  const float* dwk1 = (const float*)d_in[25];
  const float* dwv1 = (const float*)d_in[26];
  const float* dwo1 = (const float*)d_in[27];
  const float* dwq2 = (const float*)d_in[28];
  const float* dwk2 = (const float*)d_in[29];
  const float* dwv2 = (const float*)d_in[30];
  const float* dwo2 = (const float*)d_in[31];
  const float* dln1 = (const float*)d_in[32];
  const float* dln2 = (const float*)d_in[33];
  const float* dln3 = (const float*)d_in[34];
  const float* dfg  = (const float*)d_in[35];
  const float* dfp  = (const float*)d_in[36];
  const float* dhw1 = (const float*)d_in[37];
  const float* dhb1 = (const float*)d_in[38];
  const float* dhln = (const float*)d_in[39];
  const float* dhw2 = (const float*)d_in[40];
  const float* dhb2 = (const float*)d_in[41];

  const size_t BUF = (size_t)MM*EE;
  // fp32 region
  float* wsf  = (float*)d_ws;
  float* f32a = wsf;              // obs_rep / wo-out / gate ; also Wcum_lo+Wcum_hi (bf16)
  float* f32b = f32a + BUF;       // proj ; also Wc_lo (fp32)
  float* tmx  = f32b + BUF;
  // retention scratch aliases
  float* wc_lo = f32b;                                  // [B][H][8][4096] fp32
  unsigned short* wcum_lo = (unsigned short*)f32a;      // [B][H][8][4096] bf16
  unsigned short* wcum_hi = wcum_lo + BUF;              // [B][H][8][4096] bf16 (enc; in-place scan)
  // bf16 region
  unsigned short* ub = (unsigned short*)(tmx + 64);
  unsigned short* xrep_b    = ub;  ub += BUF;
  unsigned short* xrep_pe_b = ub;  ub += BUF;
  unsigned short* x_b       = ub;  ub += BUF;
  unsigned short* x_pe_b    = ub;  ub += BUF;
  unsigned short* t1_b      = ub;  ub += BUF;
  unsigned short* t1_pe_b   = ub;  ub += BUF;   // decoder-only; aliased as qhi_b (encoder-only)
  unsigned short* peb       = ub;  ub += BUF;
  unsigned short* qlo_b     = ub;  ub += BUF;
  unsigned short* klo_b     = ub;  ub += BUF;
  unsigned short* kloT_b    = ub;  ub += BUF;
  unsigned short* khi_b     = ub;  ub += BUF;
  unsigned short* khiT_b    = ub;  ub += BUF;
  unsigned short* vT_b      = ub;  ub += BUF;   // [B][H][64][512]
  unsigned short* obs_n     = ub;  ub += (size_t)MM*OBSD;
  unsigned short* act_b     = obs_n;            // aliased (obs_n dead by decoder embed)
  unsigned short* qhi_b     = t1_pe_b;          // alias
  // weights
  const size_t W55 = (size_t)EE*EE;
  unsigned short* wts = ub;  ub += 50*W55;
  unsigned short* wt_eow = ub; ub += (size_t)EE*OBSD;
  unsigned short* wt_daw = ub; ub += (size_t)EE*64;
  size_t need = (char*)ub - (char*)d_ws;
  if (ws_size < need) return;

  unsigned short* wt_ewq  = wts + 0*W55;
  unsigned short* wt_ewk  = wts + 3*W55;
  unsigned short* wt_ewv  = wts + 6*W55;
  unsigned short* wt_ewo  = wts + 9*W55;
  unsigned short* wt_efg  = wts + 12*W55;
  unsigned short* wt_efp  = wts + 15*W55;
  unsigned short* wt_ehw1 = wts + 18*W55;
  unsigned short* wt_dwq1 = wts + 19*W55;
  unsigned short* wt_dwk1 = wts + 22*W55;
  unsigned short* wt_dwv1 = wts + 25*W55;
  unsigned short* wt_dwo1 = wts + 28*W55;
  unsigned short* wt_dwq2 = wts + 31*W55;
  unsigned short* wt_dwk2 = wts + 34*W55;
  unsigned short* wt_dwv2 = wts + 37*W55;
  unsigned short* wt_dwo2 = wts + 40*W55;
  unsigned short* wt_dfg  = wts + 43*W55;
  unsigned short* wt_dfp  = wts + 46*W55;
  unsigned short* wt_dhw1 = wts + 49*W55;

  float* out        = (float*)d_out;
  float* value_out  = out;
  float* logits_out = out + 8192;
  float* enc_out    = logits_out + (size_t)MM*16;
  float* d1_out     = enc_out + (size_t)BB*LL*HH*DH*DH;
  float* d2_out     = d1_out  + (size_t)BB*LL*HH*DH*DH;

  const size_t HS_L = (size_t)HH*DH*DH;

  {
    TP50 tp;
    const float* srcs[18] = {ewq, ewk, ewv, ewo, efg, efp, ehw1,
                             dwq1, dwk1, dwv1, dwo1, dwq2, dwk2, dwv2, dwo2, dfg, dfp, dhw1};
    const int cnt[18] = {3,3,3,3,3,3,1, 3,3,3,3,3,3,3,3,3,3,1};
    int z = 0;
    for (int i = 0; i < 18; ++i)
      for (int j = 0; j < cnt[i]; ++j){
        tp.s[z] = srcs[i] + (size_t)j*W55;
        tp.d[z] = wts + (size_t)z*W55;
        ++z;
      }
    wtpose_batch_kernel<<<dim3(16,16,50), dim3(32,8), 0, stream>>>(tp);
  }
  wtpose_kernel<<<dim3(4,16), dim3(32,8), 0, stream>>>(eow, wt_eow, OBSD, OBSD);
  wtpose_kernel<<<dim3(2,16), dim3(32,8), 0, stream>>>(daw, wt_daw, ACTD, 64);

  pe_kernel<<<(MM*EE)/256, 256, 0, stream>>>(stepc, peb);
  tsmax_kernel<<<BB, 256, 0, stream>>>(stepc, tmx);

  auto gemmF = [&](const unsigned short* A, const unsigned short* Wt, const float* bias,
                   float* C, int Kpad, float scale, int act){
    gemm_b_kernel<<<dim3(EE/64, MM/128), 256, 0, stream>>>(A, Wt, bias, C, nullptr, nullptr,
        Kpad, scale, act, nullptr, 0.f, nullptr, nullptr, nullptr, nullptr);
  };
  auto gemmQ = [&](const unsigned short* A, const unsigned short* Wt, int enc){
    gemm_b_kernel<<<dim3(EE/64, MM/128), 256, 0, stream>>>(A, Wt, nullptr, nullptr, nullptr, nullptr,
        EE, 1.f, ACT_NONE, stepc, 1.f, qlo_b, nullptr, enc ? qhi_b : nullptr, nullptr);
  };
  auto gemmK = [&](const unsigned short* A, const unsigned short* Wt, int enc){
    gemm_b_kernel<<<dim3(EE/64, MM/128), 256, 0, stream>>>(A, Wt, nullptr, nullptr, nullptr, nullptr,
        EE, INV_SQRT_D, ACT_NONE, stepc, -1.f, klo_b, kloT_b,
        enc ? khi_b : nullptr, enc ? khiT_b : nullptr);
  };
  auto gemmV = [&](const unsigned short* A, const unsigned short* Wt){
    gemm_b_kernel<<<dim3(EE/64, MM/128), 256, 0, stream>>>(A, Wt, nullptr, nullptr, nullptr, vT_b,
        EE, 1.f, ACT_NONE, nullptr, 0.f, nullptr, nullptr, nullptr, nullptr);
  };
  auto norm = [&](const float* af, const unsigned short* ab, const float* res,
                  const float* g, const float* p, const float* w,
                  unsigned short* o1, unsigned short* o2, int mode){
    norm_b_kernel<<<MM, 256, 0, stream>>>(af, ab, res, g, p, w, o1, o2, peb, mode);
  };
  auto retention = [&](const float* h0, float* hnew, unsigned short* o, int enc){
    wchunk_kernel<<<dim3(8, HH, BB), 256, 0, stream>>>(kloT_b, khiT_b, vT_b, wc_lo,
        enc ? wcum_hi : nullptr, enc);
    wscan_kernel<<<BB*HH, 256, 0, stream>>>(wc_lo, wcum_lo, enc ? wcum_hi : nullptr,
        h0, tmx, hnew, enc);
    if (enc)
      retention2_kernel<1><<<dim3(8, HH, BB), 256, 0, stream>>>(
          qlo_b, qhi_b, klo_b, khi_b, vT_b, wcum_lo, wcum_hi, stepc, o);
    else
      retention2_kernel<0><<<dim3(8, HH, BB), 256, 0, stream>>>(
          qlo_b, nullptr, klo_b, nullptr, vT_b, wcum_lo, nullptr, stepc, o);
  };

  // ---- encoder embed ----
  norm_obs_kernel<<<MM, 128, 0, stream>>>(obs, eoln, obs_n);
  gemmF(obs_n, wt_eow, nullptr, f32a, OBSD, 1.f, ACT_GELU);   // f32a = obs_rep

  // ---- encoder layers ----
  for (int i = 0; i < LL; ++i){
    if (i == 0) norm(f32a, nullptr, nullptr, nullptr, nullptr, eln, x_b, x_pe_b, NORM_PLAIN);
    else        norm(nullptr, xrep_b, nullptr, nullptr, nullptr, eln, x_b, x_pe_b, NORM_PLAIN);
    gemmQ(x_pe_b, wt_ewq + i*W55, 1);
    gemmK(x_pe_b, wt_ewk + i*W55, 1);
    gemmV(x_pe_b, wt_ewv + i*W55);
    retention(enc_hs + i*HS_L, enc_out + i*HS_L, t1_b, 1);
    gemmF(t1_b, wt_ewo + i*W55, nullptr, f32a, EE, 1.f, ACT_NONE);
    norm(nullptr, x_b, f32a, nullptr, nullptr, eln1 + i*EE, t1_b, nullptr, NORM_ADD);
    gemmF(t1_b, wt_efg + i*W55, nullptr, f32a, EE, 1.f, ACT_NONE);
    gemmF(t1_b, wt_efp + i*W55, nullptr, f32b, EE, 1.f, ACT_NONE);
    norm(nullptr, t1_b, nullptr, f32a, f32b, eln2 + i*EE, xrep_b, xrep_pe_b, NORM_SWIGLU);
  }

  // ---- value head ----
  gemmF(xrep_b, wt_ehw1, ehb1, f32a, EE, 1.f, ACT_GELU);
  norm(f32a, nullptr, nullptr, nullptr, nullptr, ehln, t1_b, nullptr, NORM_PLAIN);
  value_head_kernel<<<MM/32, 256, 0, stream>>>(t1_b, ehw2, ehb2, value_out);

  // ---- decoder embed ----
  act_embed_kernel<<<(MM*64)/256, 256, 0, stream>>>(action, act_b);
  gemmF(act_b, wt_daw, nullptr, f32a, 64, 1.f, ACT_GELU);
  norm(f32a, nullptr, nullptr, nullptr, nullptr, dln, x_b, x_pe_b, NORM_PLAIN);

  // ---- decoder layers ----
  for (int i = 0; i < LL; ++i){
    gemmQ(x_pe_b, wt_dwq1 + i*W55, 0);
    gemmK(x_pe_b, wt_dwk1 + i*W55, 0);
    gemmV(x_pe_b, wt_dwv1 + i*W55);
    retention(dec_hs1 + i*HS_L, d1_out + i*HS_L, t1_b, 0);
    gemmF(t1_b, wt_dwo1 + i*W55, nullptr, f32a, EE, 1.f, ACT_NONE);
    norm(nullptr, x_b, f32a, nullptr, nullptr, dln1 + i*EE, t1_b, t1_pe_b, NORM_ADD);   // r
    gemmQ(xrep_pe_b, wt_dwq2 + i*W55, 0);
    gemmK(t1_pe_b,   wt_dwk2 + i*W55, 0);
    gemmV(t1_pe_b,   wt_dwv2 + i*W55);
    retention(dec_hs2 + i*HS_L, d2_out + i*HS_L, t1_b, 0);
    gemmF(t1_b, wt_dwo2 + i*W55, nullptr, f32a, EE, 1.f, ACT_NONE);
    norm(nullptr, xrep_b, f32a, nullptr, nullptr, dln2 + i*EE, x_b, nullptr, NORM_ADD); // y
    gemmF(x_b, wt_dfg + i*W55, nullptr, f32a, EE, 1.f, ACT_NONE);
    gemmF(x_b, wt_dfp + i*W55, nullptr, f32b, EE, 1.f, ACT_NONE);
    norm(nullptr, x_b, nullptr, f32a, f32b, dln3 + i*EE, x_b, x_pe_b, NORM_SWIGLU);
  }

  // ---- logits head ----
  gemmF(x_b, wt_dhw1, dhb1, f32a, EE, 1.f, ACT_GELU);
  norm(f32a, nullptr, nullptr, nullptr, nullptr, dhln, t1_b, nullptr, NORM_PLAIN);
  logits_head_kernel<<<MM/16, 256, 0, stream>>>(t1_b, dhw2, dhb2, logits_out);
}

// Round 3
// 1564.992 us; speedup vs baseline: 1.1387x; 1.0636x over previous
//
#include <hip/hip_runtime.h>
#include <hip/hip_bf16.h>
#include <math.h>

typedef __attribute__((ext_vector_type(8))) short short8;     // 8 bf16 = 4 VGPRs
typedef __attribute__((ext_vector_type(4))) short short4v;    // 4 bf16 = 8B
typedef __attribute__((ext_vector_type(4))) float f32x4;

#define BB 16
#define SS 512
#define EE 512
#define HH 8
#define DH 64
#define LL 3
#define MM (BB*SS)
#define OBSD 128
#define ACTD 17
#define INV_SQRT_D 0.125f

#define ACT_NONE 0
#define ACT_GELU 1

#define NORM_PLAIN 0
#define NORM_ADD 1

__device__ __forceinline__ float gelu_f(float x){
  float x3 = x*x*x;
  return 0.5f*x*(1.f + tanhf(0.7978845608028654f*(x + 0.044715f*x3)));
}
__device__ __forceinline__ float silu_f(float x){ return x/(1.f+expf(-x)); }
__device__ __forceinline__ float lkappa(int h){ return logf(1.f - exp2f(-5.f - (float)h)); }
__device__ __forceinline__ unsigned short f2bs(float f){
  unsigned int u = __float_as_uint(f);
  u += 0x7FFFu + ((u >> 16) & 1u);
  return (unsigned short)(u >> 16);
}
__device__ __forceinline__ float bs2f(unsigned short u){
  return __uint_as_float(((unsigned int)u) << 16);
}

// async global->LDS, 16B per lane. LDS dest = wave-uniform base + lane*16 (linear).
typedef const __attribute__((address_space(1))) unsigned int* gas1_t;
typedef __attribute__((address_space(3))) unsigned int* las3_t;
__device__ __forceinline__ void gl16(const void* g, void* l){
  __builtin_amdgcn_global_load_lds((gas1_t)g, (las3_t)l, 16, 0, 0);
}

// ---------------- weight transpose: W[K][512] fp32 -> Wt[512][Kpad] bf16 ----------------
__global__ __launch_bounds__(256) void wtpose_kernel(
    const float* __restrict__ src, unsigned short* __restrict__ dst, int K, int Kpad)
{
  __shared__ float t[32][33];
  const int gx = blockIdx.x, gy = blockIdx.y;
  const int tx = threadIdx.x, ty = threadIdx.y;
  #pragma unroll
  for (int i = 0; i < 4; ++i){
    int k = gx*32 + ty + i*8, n = gy*32 + tx;
    t[ty+i*8][tx] = (k < K) ? src[(size_t)k*EE + n] : 0.f;
  }
  __syncthreads();
  #pragma unroll
  for (int i = 0; i < 4; ++i){
    int k = gx*32 + tx, n = gy*32 + ty + i*8;
    dst[(size_t)n*Kpad + k] = f2bs(t[tx][ty+i*8]);
  }
}

struct TP50 { const float* s[50]; unsigned short* d[50]; };
__global__ __launch_bounds__(256) void wtpose_batch_kernel(TP50 tp)
{
  __shared__ float t[32][33];
  const float* src = tp.s[blockIdx.z];
  unsigned short* dst = tp.d[blockIdx.z];
  const int gx = blockIdx.x, gy = blockIdx.y;
  const int tx = threadIdx.x, ty = threadIdx.y;
  #pragma unroll
  for (int i = 0; i < 4; ++i){
    int k = gx*32 + ty + i*8, n = gy*32 + tx;
    t[ty+i*8][tx] = src[(size_t)k*EE + n];
  }
  __syncthreads();
  #pragma unroll
  for (int i = 0; i < 4; ++i){
    int k = gx*32 + tx, n = gy*32 + ty + i*8;
    dst[(size_t)n*EE + k] = f2bs(t[tx][ty+i*8]);
  }
}

// ---------------- MFMA GEMM (global_load_lds staged, XOR-swizzled LDS) ----------------
// SW=0: outputs fp32 C and/or bf16 Cb and/or per-head transposed CT; decay mode
//       (tsi != null) writes lo/hi scaled bf16 outputs. head block-uniform (bn 64-aligned).
// SW=1: second weight Wt2; writes swo = bf16 silu(A@Wt)*(A@Wt2) only.
template<int SW>
__global__ __launch_bounds__(256) void gemm_b_kernel(
    const unsigned short* __restrict__ A, const unsigned short* __restrict__ Wt,
    const unsigned short* __restrict__ Wt2,
    const float* __restrict__ bias, float* __restrict__ C,
    unsigned short* __restrict__ Cb, unsigned short* __restrict__ CT,
    int Kpad, float scale, int act,
    const int* __restrict__ tsi, float dsign,
    unsigned short* __restrict__ lo_n, unsigned short* __restrict__ lo_t,
    unsigned short* __restrict__ hi_n, unsigned short* __restrict__ hi_t,
    unsigned short* __restrict__ swo)
{
  // linear LDS, swizzle: physical elem = row*64 + (col ^ ((row&7)<<3))
  __shared__ unsigned short As[128*64];
  __shared__ unsigned short Bs[64*64];
  __shared__ unsigned short Bs2[SW ? 64*64 : 8];
  const int bm = blockIdx.y*128, bn = blockIdx.x*64;
  const int tid = threadIdx.x, lane = tid & 63, wv = tid >> 6;
  const int wr = wv >> 1, wc = wv & 1;
  const int l16 = lane & 15, quad = lane >> 4;

  f32x4 acc[4][2], acc2[SW ? 4 : 1][SW ? 2 : 1];
  #pragma unroll
  for (int i=0;i<4;i++){ acc[i][0]=(f32x4)(0.f); acc[i][1]=(f32x4)(0.f); }
  if (SW){
    #pragma unroll
    for (int i=0;i<4;i++){ acc2[i][0]=(f32x4)(0.f); acc2[i][1]=(f32x4)(0.f); }
  }

  // staging source offsets: lane covers physical granule (issue_base + lane);
  // row = granule>>3, physical slot = granule&7, logical slot = slot ^ (row&7)
  const int sg = lane >> 3;                  // row-within-issue
  const int lg = (lane & 7) ^ sg;            // logical 16B-granule (inverse swizzle)
  size_t aoff[4], boff[2];
  #pragma unroll
  for (int i=0;i<4;i++)
    aoff[i] = (size_t)(bm + (wv*4+i)*8 + sg)*Kpad + lg*8;
  #pragma unroll
  for (int i=0;i<2;i++)
    boff[i] = (size_t)(bn + (wv*2+i)*8 + sg)*Kpad + lg*8;

  const int swz = (l16 & 7) << 3;            // read-side XOR (elements)

  for (int k0 = 0; k0 < Kpad; k0 += 64){
    #pragma unroll
    for (int i=0;i<4;i++)
      gl16(A + aoff[i] + k0, (char*)As + ((wv*4+i) << 10));
    #pragma unroll
    for (int i=0;i<2;i++)
      gl16(Wt + boff[i] + k0, (char*)Bs + ((wv*2+i) << 10));
    if (SW){
      #pragma unroll
      for (int i=0;i<2;i++)
        gl16(Wt2 + boff[i] + k0, (char*)Bs2 + ((wv*2+i) << 10));
    }
    __syncthreads();
    short8 af[4][2], bf[2][2];
    #pragma unroll
    for (int mt=0; mt<4; ++mt)
      #pragma unroll
      for (int ks=0; ks<2; ++ks)
        af[mt][ks] = *(const short8*)&As[(wr*64 + mt*16 + l16)*64 + ((ks*32 + quad*8) ^ swz)];
    #pragma unroll
    for (int nt=0; nt<2; ++nt)
      #pragma unroll
      for (int ks=0; ks<2; ++ks)
        bf[nt][ks] = *(const short8*)&Bs[(wc*32 + nt*16 + l16)*64 + ((ks*32 + quad*8) ^ swz)];
    #pragma unroll
    for (int ks=0; ks<2; ++ks)
      #pragma unroll
      for (int mt=0; mt<4; ++mt)
        #pragma unroll
        for (int nt=0; nt<2; ++nt)
          acc[mt][nt] = __builtin_amdgcn_mfma_f32_16x16x32_bf16(af[mt][ks], bf[nt][ks], acc[mt][nt], 0, 0, 0);
    if (SW){
      short8 bf2[2][2];
      #pragma unroll
      for (int nt=0; nt<2; ++nt)
        #pragma unroll
        for (int ks=0; ks<2; ++ks)
          bf2[nt][ks] = *(const short8*)&Bs2[(wc*32 + nt*16 + l16)*64 + ((ks*32 + quad*8) ^ swz)];
      #pragma unroll
      for (int ks=0; ks<2; ++ks)
        #pragma unroll
        for (int mt=0; mt<4; ++mt)
          #pragma unroll
          for (int nt=0; nt<2; ++nt)
            acc2[mt][nt] = __builtin_amdgcn_mfma_f32_16x16x32_bf16(af[mt][ks], bf2[nt][ks], acc2[mt][nt], 0, 0, 0);
    }
    __syncthreads();
  }
  const float lkh = (!SW && tsi) ? lkappa(bn >> 6) : 0.f;
  #pragma unroll
  for (int mt=0; mt<4; ++mt){
    int rb = bm + wr*64 + mt*16 + quad*4;
    if (SW){
      #pragma unroll
      for (int nt=0; nt<2; ++nt){
        int col = bn + wc*32 + nt*16 + l16;
        #pragma unroll
        for (int j=0;j<4;j++)
          swo[(size_t)(rb+j)*EE + col] = f2bs(silu_f(acc[mt][nt][j])*acc2[mt][nt][j]);
      }
      continue;
    }
    float e0[4], e1[4];
    if (tsi){
      #pragma unroll
      for (int j=0;j<4;j++){
        float x = dsign*lkh*(float)tsi[rb+j];
        e0[j] = __expf(x); e1[j] = __expf(-x);
      }
    }
    #pragma unroll
    for (int nt=0; nt<2; ++nt){
      int col = bn + wc*32 + nt*16 + l16;
      float bv = bias ? bias[col] : 0.f;
      float vals[4];
      #pragma unroll
      for (int j=0;j<4;j++){
        float v = acc[mt][nt][j]*scale + bv;
        if (act==ACT_GELU) v = gelu_f(v);
        vals[j] = v;
      }
      int bloc = rb >> 9, m0 = rb & 511;
      int hh = col >> 6, ee = col & 63;
      size_t taddr = (((size_t)bloc*HH + hh)*DH + ee)*SS + m0;
      if (C){
        #pragma unroll
        for (int j=0;j<4;j++) C[(size_t)(rb+j)*EE + col] = vals[j];
      }
      if (Cb){
        #pragma unroll
        for (int j=0;j<4;j++) Cb[(size_t)(rb+j)*EE + col] = f2bs(vals[j]);
      }
      if (CT){
        short4v pk;
        #pragma unroll
        for (int j=0;j<4;j++) pk[j] = (short)f2bs(vals[j]);
        *(short4v*)&CT[taddr] = pk;
      }
      if (tsi){
        if (lo_n){
          #pragma unroll
          for (int j=0;j<4;j++) lo_n[(size_t)(rb+j)*EE + col] = f2bs(vals[j]*e0[j]);
        }
        if (lo_t){
          short4v pk;
          #pragma unroll
          for (int j=0;j<4;j++) pk[j] = (short)f2bs(vals[j]*e0[j]);
          *(short4v*)&lo_t[taddr] = pk;
        }
        if (hi_n){
          #pragma unroll
          for (int j=0;j<4;j++) hi_n[(size_t)(rb+j)*EE + col] = f2bs(vals[j]*e1[j]);
        }
        if (hi_t){
          short4v pk;
          #pragma unroll
          for (int j=0;j<4;j++) pk[j] = (short)f2bs(vals[j]*e1[j]);
          *(short4v*)&hi_t[taddr] = pk;
        }
      }
    }
  }
}

// ---------------- rmsnorm: mixed fp32/bf16 input (+fp32 or bf16 residual) -> bf16 ----------------
__global__ __launch_bounds__(256) void norm_b_kernel(
    const float* __restrict__ af, const unsigned short* __restrict__ ab,
    const float* __restrict__ res, const unsigned short* __restrict__ resb,
    const float* __restrict__ w, unsigned short* __restrict__ o1,
    unsigned short* __restrict__ o2, const unsigned short* __restrict__ peb,
    int mode)
{
  __shared__ float red[4];
  const int row = blockIdx.x, tid = threadIdx.x;
  const size_t base = (size_t)row*EE + tid*2;
  float t0, t1;
  if (ab){
    unsigned int av = *(const unsigned int*)&ab[base];
    t0 = bs2f((unsigned short)(av & 0xffffu));
    t1 = bs2f((unsigned short)(av >> 16));
  } else {
    float2 av = *(const float2*)&af[base];
    t0 = av.x; t1 = av.y;
  }
  if (mode == NORM_ADD){
    if (resb){
      unsigned int rv = *(const unsigned int*)&resb[base];
      t0 += bs2f((unsigned short)(rv & 0xffffu));
      t1 += bs2f((unsigned short)(rv >> 16));
    } else {
      float2 rv = *(const float2*)&res[base];
      t0 += rv.x; t1 += rv.y;
    }
  }
  float ss = t0*t0 + t1*t1;
  #pragma unroll
  for (int o=32;o;o>>=1) ss += __shfl_down(ss,o);
  if ((tid&63)==0) red[tid>>6]=ss;
  __syncthreads();
  if (tid==0) red[0] = 1.f/sqrtf((red[0]+red[1]+red[2]+red[3])/(float)EE + 1e-6f);
  __syncthreads();
  float r = red[0];
  float2 wv2 = *(const float2*)&w[tid*2];
  float y0 = t0*r*wv2.x, y1 = t1*r*wv2.y;
  unsigned int pk = (unsigned int)f2bs(y0) | ((unsigned int)f2bs(y1) << 16);
  *(unsigned int*)&o1[base] = pk;
  if (o2){
    unsigned int pv = *(const unsigned int*)&peb[base];
    float z0 = y0 + bs2f((unsigned short)(pv & 0xffffu));
    float z1 = y1 + bs2f((unsigned short)(pv >> 16));
    *(unsigned int*)&o2[base] = (unsigned int)f2bs(z0) | ((unsigned int)f2bs(z1) << 16);
  }
}

// obs norm: fp32 [MM][128] -> bf16
__global__ __launch_bounds__(128) void norm_obs_kernel(
    const float* __restrict__ a, const float* __restrict__ w, unsigned short* __restrict__ o)
{
  __shared__ float red[2];
  const int row = blockIdx.x, tid = threadIdx.x;
  float t = a[(size_t)row*OBSD + tid];
  float ss = t*t;
  #pragma unroll
  for (int off=32;off;off>>=1) ss += __shfl_down(ss,off);
  if ((tid&63)==0) red[tid>>6]=ss;
  __syncthreads();
  if (tid==0) red[0] = 1.f/sqrtf((red[0]+red[1])/(float)OBSD + 1e-6f);
  __syncthreads();
  o[(size_t)row*OBSD + tid] = f2bs(t*red[0]*w[tid]);
}

// action embed: fp32 [MM][17] -> bf16 [MM][64] zero-padded
__global__ __launch_bounds__(256) void act_embed_kernel(
    const float* __restrict__ a, unsigned short* __restrict__ o)
{
  int idx = blockIdx.x*256 + threadIdx.x;
  int row = idx >> 6, col = idx & 63;
  o[idx] = (col < ACTD) ? f2bs(a[(size_t)row*ACTD + col]) : 0;
}

// ---------------- chunk state: Wc_lo[e][d] = sum_m vT[e][m]*kloT[d][m] (fp32),
//                  encoder also Wc_hi with khiT (bf16 out) ----------------
__global__ __launch_bounds__(256) void wchunk_kernel(
    const unsigned short* __restrict__ kloT, const unsigned short* __restrict__ khiT,
    const unsigned short* __restrict__ vT,
    float* __restrict__ wlo, unsigned short* __restrict__ whi, int enc)
{
  __shared__ unsigned short vsh[64*72];
  __shared__ unsigned short ksh[64*72];
  __shared__ unsigned short ksh2[64*72];
  const int c = blockIdx.x, h = blockIdx.y, b = blockIdx.z;
  const int tid = threadIdx.x, lane = tid & 63, wv = tid >> 6;
  const int quad = lane >> 4, l16 = lane & 15;
  const int mc = c*64;
  {
    const int r = tid >> 2, seg = (tid & 3)*16;
    const unsigned short* vrow = vT   + (((size_t)b*HH + h)*DH + r)*SS + mc + seg;
    const unsigned short* krow = kloT + (((size_t)b*HH + h)*DH + r)*SS + mc + seg;
    #pragma unroll
    for (int i = 0; i < 2; ++i){
      *(short8*)&vsh[r*72 + seg + i*8] = *(const short8*)(vrow + i*8);
      *(short8*)&ksh[r*72 + seg + i*8] = *(const short8*)(krow + i*8);
    }
    if (enc){
      const unsigned short* k2row = khiT + (((size_t)b*HH + h)*DH + r)*SS + mc + seg;
      #pragma unroll
      for (int i = 0; i < 2; ++i)
        *(short8*)&ksh2[r*72 + seg + i*8] = *(const short8*)(k2row + i*8);
    }
  }
  __syncthreads();
  short8 av[2];
  #pragma unroll
  for (int ks=0; ks<2; ++ks)
    av[ks] = *(const short8*)&vsh[(wv*16 + l16)*72 + ks*32 + quad*8];
  f32x4 acc[4];
  #pragma unroll
  for (int dt=0; dt<4; ++dt) acc[dt] = (f32x4)(0.f);
  #pragma unroll
  for (int ks=0; ks<2; ++ks)
    #pragma unroll
    for (int dt=0; dt<4; ++dt){
      short8 kb = *(const short8*)&ksh[(dt*16 + l16)*72 + ks*32 + quad*8];
      acc[dt] = __builtin_amdgcn_mfma_f32_16x16x32_bf16(av[ks], kb, acc[dt], 0, 0, 0);
    }
  size_t obase = (((size_t)b*HH + h)*8 + c)*4096;
  #pragma unroll
  for (int dt=0; dt<4; ++dt)
    #pragma unroll
    for (int j=0;j<4;j++)
      wlo[obase + (size_t)(wv*16 + quad*4 + j)*64 + dt*16 + l16] = acc[dt][j];
  if (enc){
    f32x4 acc2[4];
    #pragma unroll
    for (int dt=0; dt<4; ++dt) acc2[dt] = (f32x4)(0.f);
    #pragma unroll
    for (int ks=0; ks<2; ++ks)
      #pragma unroll
      for (int dt=0; dt<4; ++dt){
        short8 kb = *(const short8*)&ksh2[(dt*16 + l16)*72 + ks*32 + quad*8];
        acc2[dt] = __builtin_amdgcn_mfma_f32_16x16x32_bf16(av[ks], kb, acc2[dt], 0, 0, 0);
      }
    #pragma unroll
    for (int dt=0; dt<4; ++dt)
      #pragma unroll
      for (int j=0;j<4;j++)
        whi[obase + (size_t)(wv*16 + quad*4 + j)*64 + dt*16 + l16] = f2bs(acc2[dt][j]);
  }
}

// ---------------- scan: Wcum_lo[t] = elk*h0^T + sum_{c<t} Wc_lo (bf16),
//                  h_new = e^{lk*tm} * (elk*h0^T + sum_all Wc_lo),
//                  encoder: Wcum_hi[t] = sum_{c>t} Wc_hi (in-place) ----------------
__global__ __launch_bounds__(256) void wscan_kernel(
    const float* __restrict__ wc, unsigned short* __restrict__ wcum,
    unsigned short* whi,
    const float* __restrict__ h0, const float* __restrict__ tmx,
    float* __restrict__ hnew, int enc)
{
  const int bh = blockIdx.x, b = bh >> 3, h = bh & 7;
  const float lk = lkappa(h);
  const float elk = __expf(lk);
  const float etm = __expf(lk*tmx[b]);
  const size_t wbase = (size_t)bh*8*4096;
  const size_t hbase = (size_t)b*(LL*HH*DH*DH) + (size_t)h*(DH*DH);
  for (int i = 0; i < 16; ++i){
    int p = i*256 + threadIdx.x;        // p = e*64 + d
    int e = p >> 6, d = p & 63;
    float acc = elk * h0[hbase + d*64 + e];
    #pragma unroll
    for (int c = 0; c < 8; ++c){
      float reg = wc[wbase + c*4096 + p];
      wcum[wbase + c*4096 + p] = f2bs(acc);
      acc += reg;
    }
    hnew[hbase + d*64 + e] = etm * acc;
    if (enc){
      float a2 = 0.f;
      #pragma unroll
      for (int c = 7; c >= 0; --c){
        float reg = bs2f(whi[wbase + c*4096 + p]);
        whi[wbase + c*4096 + p] = f2bs(a2);
        a2 += reg;
      }
    }
  }
}

// ---------------- retention (chunked-recurrent): out = Qlo@Wcum_lo[t]
//                  (+ Qhi@Wcum_hi[t] enc) + boundary diag chunk(s) ----------------
template<int ENC>
__global__ __launch_bounds__(256) void retention2_kernel(
    const unsigned short* __restrict__ qlo, const unsigned short* __restrict__ qhi,
    const unsigned short* __restrict__ klo, const unsigned short* __restrict__ khi,
    const unsigned short* __restrict__ vT,
    const unsigned short* __restrict__ wlo, const unsigned short* __restrict__ whi,
    const int* __restrict__ tsi, unsigned short* __restrict__ outp)
{
  __shared__ unsigned short qsh[64*72];        // reused as psh in boundary
  __shared__ unsigned short wsh[64*72];
  __shared__ unsigned short ksh[64*72];
  __shared__ unsigned short vsh[64*72];
  __shared__ unsigned short qsh2[ENC ? 64*72 : 2];  // reused as ksh2 in boundary
  __shared__ unsigned short wsh2[ENC ? 64*72 : 2];
  __shared__ float tsf[SS];
  const int b = blockIdx.z, h = blockIdx.y, t = blockIdx.x;
  const int n0 = t*64;
  const int tid = threadIdx.x, lane = tid & 63, wv = tid >> 6;
  const int quad = lane >> 4, l16 = lane & 15;

  for (int i = tid; i < SS; i += 256) tsf[i] = (float)tsi[b*SS + i];
  {
    const int n = tid >> 2, seg = (tid & 3)*16;
    const unsigned short* qr = qlo + ((size_t)b*SS + n0 + n)*EE + h*DH + seg;
    #pragma unroll
    for (int i = 0; i < 2; ++i)
      *(short8*)&qsh[n*72 + seg + i*8] = *(const short8*)(qr + i*8);
    const unsigned short* wr = wlo + (((size_t)b*HH + h)*8 + t)*4096 + (size_t)n*64 + seg;
    #pragma unroll
    for (int i = 0; i < 2; ++i)
      *(short8*)&wsh[n*72 + seg + i*8] = *(const short8*)(wr + i*8);
    if (ENC){
      const unsigned short* qr2 = qhi + ((size_t)b*SS + n0 + n)*EE + h*DH + seg;
      #pragma unroll
      for (int i = 0; i < 2; ++i)
        *(short8*)&qsh2[n*72 + seg + i*8] = *(const short8*)(qr2 + i*8);
      const unsigned short* wr2 = whi + (((size_t)b*HH + h)*8 + t)*4096 + (size_t)n*64 + seg;
      #pragma unroll
      for (int i = 0; i < 2; ++i)
        *(short8*)&wsh2[n*72 + seg + i*8] = *(const short8*)(wr2 + i*8);
    }
  }
  __syncthreads();

  const int rowbase = wv*16;
  short8 qa[2], qa2[2];
  #pragma unroll
  for (int ks=0; ks<2; ++ks)
    qa[ks] = *(const short8*)&qsh[(rowbase + l16)*72 + ks*32 + quad*8];
  if (ENC){
    #pragma unroll
    for (int ks=0; ks<2; ++ks)
      qa2[ks] = *(const short8*)&qsh2[(rowbase + l16)*72 + ks*32 + quad*8];
  }

  float tn = tsf[n0 + lane];
  float maxn = tn, minn = tn;
  #pragma unroll
  for (int o=32;o;o>>=1){
    maxn = fmaxf(maxn, __shfl_xor(maxn, o));
    minn = fminf(minn, __shfl_xor(minn, o));
  }

  // cross-chunk + h0 contribution: Qlo @ Wcum_lo (+ Qhi @ Wcum_hi)
  f32x4 acc_o[4];
  #pragma unroll
  for (int et=0; et<4; ++et){
    f32x4 a = (f32x4)(0.f);
    #pragma unroll
    for (int ks=0; ks<2; ++ks){
      short8 wb = *(const short8*)&wsh[(et*16 + l16)*72 + ks*32 + quad*8];
      a = __builtin_amdgcn_mfma_f32_16x16x32_bf16(qa[ks], wb, a, 0, 0, 0);
    }
    if (ENC){
      #pragma unroll
      for (int ks=0; ks<2; ++ks){
        short8 wb2 = *(const short8*)&wsh2[(et*16 + l16)*72 + ks*32 + quad*8];
        a = __builtin_amdgcn_mfma_f32_16x16x32_bf16(qa2[ks], wb2, a, 0, 0, 0);
      }
    }
    acc_o[et] = a;
  }

  // boundary chunk(s)
  for (int c = 0; c < 8; ++c){
    const int mc = c*64;
    float tmv = tsf[mc + lane];
    float maxm = tmv, minm = tmv;
    #pragma unroll
    for (int o=32;o;o>>=1){
      maxm = fmaxf(maxm, __shfl_xor(maxm, o));
      minm = fminf(minm, __shfl_xor(minm, o));
    }
    if (ENC){
      if (maxm <= minn) continue;   // fully lower -> in Wcum_lo
      if (minm >= maxn) continue;   // fully upper -> in Wcum_hi
    } else {
      if ((maxm < minn) || (maxm == minn && (mc + 63) < n0)) continue; // full -> in Wcum_lo
      if (minm > maxn) continue;    // fully masked
    }
    __syncthreads();
    {
      const int m = tid >> 2, cb = (tid & 3)*16;
      const unsigned short* krow = klo + ((size_t)b*SS + mc + m)*EE + h*DH + cb;
      #pragma unroll
      for (int i = 0; i < 2; ++i)
        *(short8*)&ksh[m*72 + cb + i*8] = *(const short8*)(krow + i*8);
      const unsigned short* vrow = vT + (((size_t)b*HH + h)*DH + m)*SS + mc + cb;
      #pragma unroll
      for (int i = 0; i < 2; ++i)
        *(short8*)&vsh[m*72 + cb + i*8] = *(const short8*)(vrow + i*8);
      if (ENC){
        const unsigned short* k2row = khi + ((size_t)b*SS + mc + m)*EE + h*DH + cb;
        #pragma unroll
        for (int i = 0; i < 2; ++i)
          *(short8*)&qsh2[m*72 + cb + i*8] = *(const short8*)(k2row + i*8);
      }
    }
    __syncthreads();
    f32x4 sacc[4], sacc2[4];
    #pragma unroll
    for (int mt=0; mt<4; ++mt){
      f32x4 a = (f32x4)(0.f);
      #pragma unroll
      for (int ks=0; ks<2; ++ks){
        short8 kb = *(const short8*)&ksh[(mt*16 + l16)*72 + ks*32 + quad*8];
        a = __builtin_amdgcn_mfma_f32_16x16x32_bf16(qa[ks], kb, a, 0, 0, 0);
      }
      sacc[mt] = a;
      if (ENC){
        f32x4 a2 = (f32x4)(0.f);
        #pragma unroll
        for (int ks=0; ks<2; ++ks){
          short8 kb2 = *(const short8*)&qsh2[(mt*16 + l16)*72 + ks*32 + quad*8];
          a2 = __builtin_amdgcn_mfma_f32_16x16x32_bf16(qa2[ks], kb2, a2, 0, 0, 0);
        }
        sacc2[mt] = a2;
      }
    }
    float tsm[4]; int mg[4];
    #pragma unroll
    for (int mt=0; mt<4; ++mt){ mg[mt] = mc + mt*16 + l16; tsm[mt] = tsf[mg[mt]]; }
    #pragma unroll
    for (int j=0;j<4;j++){
      int nloc = rowbase + quad*4 + j;
      int n = n0 + nloc;
      float tsn = tsf[n];
      #pragma unroll
      for (int mt=0; mt<4; ++mt){
        float diff = tsn - tsm[mt];
        float p;
        if (ENC) p = (diff >= 0.f) ? sacc[mt][j] : sacc2[mt][j];
        else     p = ((diff > 0.f) || (diff == 0.f && n >= mg[mt])) ? sacc[mt][j] : 0.f;
        qsh[nloc*72 + mt*16 + l16] = f2bs(p);   // qsh reused as psh
      }
    }
    #pragma unroll
    for (int ks=0; ks<2; ++ks){
      short8 pa = *(const short8*)&qsh[(rowbase + l16)*72 + ks*32 + quad*8];
      #pragma unroll
      for (int et=0; et<4; ++et){
        short8 vb = *(const short8*)&vsh[(et*16 + l16)*72 + ks*32 + quad*8];
        acc_o[et] = __builtin_amdgcn_mfma_f32_16x16x32_bf16(pa, vb, acc_o[et], 0, 0, 0);
      }
    }
  }
  #pragma unroll
  for (int j=0;j<4;j++){
    size_t rbase = ((size_t)b*SS + n0 + rowbase + quad*4 + j)*EE + h*DH;
    #pragma unroll
    for (int et=0; et<4; ++et)
      outp[rbase + et*16 + l16] = f2bs(acc_o[et][j]);
  }
}

// ---------------- small helpers ----------------
__global__ void tsmax_kernel(const int* __restrict__ tsi, float* __restrict__ tmx){
  __shared__ int red[4];
  int b = blockIdx.x, tid = threadIdx.x;
  int m = max(tsi[b*SS+tid], tsi[b*SS+256+tid]);
  #pragma unroll
  for (int o=32;o;o>>=1) m = max(m, __shfl_down(m,o));
  if ((tid&63)==0) red[tid>>6]=m;
  __syncthreads();
  if (tid==0) tmx[b] = (float)max(max(red[0],red[1]),max(red[2],red[3]));
}

__global__ void pe_kernel(const int* __restrict__ tsi, unsigned short* __restrict__ peb){
  int idx = blockIdx.x*256 + threadIdx.x;
  int row = idx >> 9, j = idx & 511;
  float ts = (float)tsi[row];
  int jj = j & 255;
  float freq = expf(-9.210340371976184f*(float)jj*(1.f/256.f));
  float ang = ts*freq;
  peb[idx] = f2bs((j < 256) ? sinf(ang) : cosf(ang));
}

__global__ __launch_bounds__(256) void value_head_kernel(
    const unsigned short* __restrict__ x, const float* __restrict__ w,
    const float* __restrict__ bias, float* __restrict__ outp)
{
  const int tid = threadIdx.x, lane = tid & 63, wv = tid >> 6;
  const int r8 = lane >> 3, seg = lane & 7;
  const int row = blockIdx.x*32 + wv*8 + r8;
  const unsigned short* xr = x + (size_t)row*EE + seg*64;
  const float* wr = w + seg*64;
  float s = 0.f;
  #pragma unroll
  for (int i = 0; i < 8; ++i){
    short8 xv = *(const short8*)(xr + i*8);
    #pragma unroll
    for (int e = 0; e < 8; ++e)
      s += bs2f((unsigned short)xv[e]) * wr[i*8 + e];
  }
  s += __shfl_xor(s, 1); s += __shfl_xor(s, 2); s += __shfl_xor(s, 4);
  if (seg == 0) outp[row] = s + bias[0];
}

__global__ __launch_bounds__(256) void logits_head_kernel(
    const unsigned short* __restrict__ x, const float* __restrict__ w,
    const float* __restrict__ bias, float* __restrict__ outp)
{
  __shared__ unsigned short xsh[16*520];
  __shared__ unsigned short wsh[16*520];
  const int tid = threadIdx.x;
  const int row0 = blockIdx.x*16;
  {
    const int r = tid >> 4, kc = (tid & 15)*32;
    const unsigned short* xr = x + (size_t)(row0 + r)*EE + kc;
    #pragma unroll
    for (int i = 0; i < 4; ++i)
      *(short8*)&xsh[r*520 + kc + i*8] = *(const short8*)(xr + i*8);
    const int j = r;
    #pragma unroll
    for (int kk = 0; kk < 32; ++kk)
      wsh[j*520 + kc + kk] = f2bs(w[(size_t)(kc + kk)*16 + j]);
  }
  __syncthreads();
  const int r = tid >> 4, j = tid & 15;
  float s = 0.f;
  for (int k = 0; k < EE; k += 8){
    short8 xv = *(const short8*)&xsh[r*520 + k];
    short8 wv = *(const short8*)&wsh[j*520 + k];
    #pragma unroll
    for (int e = 0; e < 8; ++e)
      s += bs2f((unsigned short)xv[e]) * bs2f((unsigned short)wv[e]);
  }
  outp[(size_t)(row0 + r)*16 + j] = s + bias[j];
}

// ---------------- orchestration ----------------
extern "C" void kernel_launch(void* const* d_in, const int* in_sizes, int n_in,
                              void* d_out, int out_size, void* d_ws, size_t ws_size,
                              hipStream_t stream)
{
  const float* obs     = (const float*)d_in[0];
  const float* action  = (const float*)d_in[1];
  const float* enc_hs  = (const float*)d_in[2];
  const float* dec_hs1 = (const float*)d_in[3];
  const float* dec_hs2 = (const float*)d_in[4];
  const int*   stepc   = (const int*)d_in[5];
  const float* eoln = (const float*)d_in[6];
  const float* eow  = (const float*)d_in[7];
  const float* eln  = (const float*)d_in[8];
  const float* ewq  = (const float*)d_in[9];
  const float* ewk  = (const float*)d_in[10];
  const float* ewv  = (const float*)d_in[11];
  const float* ewo  = (const float*)d_in[12];
  const float* eln1 = (const float*)d_in[13];
  const float* eln2 = (const float*)d_in[14];
  const float* efg  = (const float*)d_in[15];
  const float* efp  = (const float*)d_in[16];
  const float* ehw1 = (const float*)d_in[17];
  const float* ehb1 = (const float*)d_in[18];
  const float* ehln = (const float*)d_in[19];
  const float* ehw2 = (const float*)d_in[20];
  const float* ehb2 = (const float*)d_in[21];
  const float* daw  = (const float*)d_in[22];
  const float* dln  = (const float*)d_in[23];
  const float* dwq1 = (const float*)d_in[24];
  const float* dwk1 = (const float*)d_in[25];
  const float* dwv1 = (const float*)d_in[26];
  const float* dwo1 = (const float*)d_in[27];
  const float* dwq2 = (const float*)d_in[28];
  const float* dwk2 = (const float*)d_in[29];
  const float* dwv2 = (const float*)d_in[30];
  const float* dwo2 = (const float*)d_in[31];
  const float* dln1 = (const float*)d_in[32];
  const float* dln2 = (const float*)d_in[33];
  const float* dln3 = (const float*)d_in[34];
  const float* dfg  = (const float*)d_in[35];
  const float* dfp  = (const float*)d_in[36];
  const float* dhw1 = (const float*)d_in[37];
  const float* dhb1 = (const float*)d_in[38];
  const float* dhln = (const float*)d_in[39];
  const float* dhw2 = (const float*)d_in[40];
  const float* dhb2 = (const float*)d_in[41];

  const size_t BUF = (size_t)MM*EE;
  // fp32 region
  float* wsf  = (float*)d_ws;
  float* f32a = wsf;              // obs_rep / wo-out / gelu heads ; also Wcum_lo+Wcum_hi (bf16)
  float* f32b = f32a + BUF;       // Wc_lo (fp32) ; also sw_b (bf16)
  float* tmx  = f32b + BUF;
  // retention / FFN scratch aliases
  float* wc_lo = f32b;                                  // [B][H][8][4096] fp32
  unsigned short* wcum_lo = (unsigned short*)f32a;      // [B][H][8][4096] bf16
  unsigned short* wcum_hi = wcum_lo + BUF;              // [B][H][8][4096] bf16 (enc; in-place scan)
  unsigned short* sw_b    = (unsigned short*)f32b;      // silu(g)*p bf16 (after retention)
  // bf16 region
  unsigned short* ub = (unsigned short*)(tmx + 64);
  unsigned short* xrep_b    = ub;  ub += BUF;
  unsigned short* xrep_pe_b = ub;  ub += BUF;
  unsigned short* x_b       = ub;  ub += BUF;
  unsigned short* x_pe_b    = ub;  ub += BUF;
  unsigned short* t1_b      = ub;  ub += BUF;
  unsigned short* t1_pe_b   = ub;  ub += BUF;   // decoder-only; aliased as qhi_b (encoder-only)
  unsigned short* peb       = ub;  ub += BUF;
  unsigned short* qlo_b     = ub;  ub += BUF;
  unsigned short* klo_b     = ub;  ub += BUF;
  unsigned short* kloT_b    = ub;  ub += BUF;
  unsigned short* khi_b     = ub;  ub += BUF;
  unsigned short* khiT_b    = ub;  ub += BUF;
  unsigned short* vT_b      = ub;  ub += BUF;   // [B][H][64][512]
  unsigned short* obs_n     = ub;  ub += (size_t)MM*OBSD;
  unsigned short* act_b     = obs_n;            // aliased (obs_n dead by decoder embed)
  unsigned short* qhi_b     = t1_pe_b;          // alias
  // weights
  const size_t W55 = (size_t)EE*EE;
  unsigned short* wts = ub;  ub += 50*W55;
  unsigned short* wt_eow = ub; ub += (size_t)EE*OBSD;
  unsigned short* wt_daw = ub; ub += (size_t)EE*64;
  size_t need = (char*)ub - (char*)d_ws;
  if (ws_size < need) return;

  unsigned short* wt_ewq  = wts + 0*W55;
  unsigned short* wt_ewk  = wts + 3*W55;
  unsigned short* wt_ewv  = wts + 6*W55;
  unsigned short* wt_ewo  = wts + 9*W55;
  unsigned short* wt_efg  = wts + 12*W55;
  unsigned short* wt_efp  = wts + 15*W55;
  unsigned short* wt_ehw1 = wts + 18*W55;
  unsigned short* wt_dwq1 = wts + 19*W55;
  unsigned short* wt_dwk1 = wts + 22*W55;
  unsigned short* wt_dwv1 = wts + 25*W55;
  unsigned short* wt_dwo1 = wts + 28*W55;
  unsigned short* wt_dwq2 = wts + 31*W55;
  unsigned short* wt_dwk2 = wts + 34*W55;
  unsigned short* wt_dwv2 = wts + 37*W55;
  unsigned short* wt_dwo2 = wts + 40*W55;
  unsigned short* wt_dfg  = wts + 43*W55;
  unsigned short* wt_dfp  = wts + 46*W55;
  unsigned short* wt_dhw1 = wts + 49*W55;

  float* out        = (float*)d_out;
  float* value_out  = out;
  float* logits_out = out + 8192;
  float* enc_out    = logits_out + (size_t)MM*16;
  float* d1_out     = enc_out + (size_t)BB*LL*HH*DH*DH;
  float* d2_out     = d1_out  + (size_t)BB*LL*HH*DH*DH;

  const size_t HS_L = (size_t)HH*DH*DH;

  {
    TP50 tp;
    const float* srcs[18] = {ewq, ewk, ewv, ewo, efg, efp, ehw1,
                             dwq1, dwk1, dwv1, dwo1, dwq2, dwk2, dwv2, dwo2, dfg, dfp, dhw1};
    const int cnt[18] = {3,3,3,3,3,3,1, 3,3,3,3,3,3,3,3,3,3,1};
    int z = 0;
    for (int i = 0; i < 18; ++i)
      for (int j = 0; j < cnt[i]; ++j){
        tp.s[z] = srcs[i] + (size_t)j*W55;
        tp.d[z] = wts + (size_t)z*W55;
        ++z;
      }
    wtpose_batch_kernel<<<dim3(16,16,50), dim3(32,8), 0, stream>>>(tp);
  }
  wtpose_kernel<<<dim3(4,16), dim3(32,8), 0, stream>>>(eow, wt_eow, OBSD, OBSD);
  wtpose_kernel<<<dim3(2,16), dim3(32,8), 0, stream>>>(daw, wt_daw, ACTD, 64);

  pe_kernel<<<(MM*EE)/256, 256, 0, stream>>>(stepc, peb);
  tsmax_kernel<<<BB, 256, 0, stream>>>(stepc, tmx);

  auto gemmF = [&](const unsigned short* A, const unsigned short* Wt, const float* bias,
                   float* C, int Kpad, float scale, int act){
    gemm_b_kernel<0><<<dim3(EE/64, MM/128), 256, 0, stream>>>(A, Wt, nullptr, bias, C, nullptr, nullptr,
        Kpad, scale, act, nullptr, 0.f, nullptr, nullptr, nullptr, nullptr, nullptr);
  };
  auto gemmQ = [&](const unsigned short* A, const unsigned short* Wt, int enc){
    gemm_b_kernel<0><<<dim3(EE/64, MM/128), 256, 0, stream>>>(A, Wt, nullptr, nullptr, nullptr, nullptr, nullptr,
        EE, 1.f, ACT_NONE, stepc, 1.f, qlo_b, nullptr, enc ? qhi_b : nullptr, nullptr, nullptr);
  };
  auto gemmK = [&](const unsigned short* A, const unsigned short* Wt, int enc){
    gemm_b_kernel<0><<<dim3(EE/64, MM/128), 256, 0, stream>>>(A, Wt, nullptr, nullptr, nullptr, nullptr, nullptr,
        EE, INV_SQRT_D, ACT_NONE, stepc, -1.f, klo_b, kloT_b,
        enc ? khi_b : nullptr, enc ? khiT_b : nullptr, nullptr);
  };
  auto gemmV = [&](const unsigned short* A, const unsigned short* Wt){
    gemm_b_kernel<0><<<dim3(EE/64, MM/128), 256, 0, stream>>>(A, Wt, nullptr, nullptr, nullptr, nullptr, vT_b,
        EE, 1.f, ACT_NONE, nullptr, 0.f, nullptr, nullptr, nullptr, nullptr, nullptr);
  };
  auto gemmSW = [&](const unsigned short* A, const unsigned short* Wg, const unsigned short* Wp){
    gemm_b_kernel<1><<<dim3(EE/64, MM/128), 256, 0, stream>>>(A, Wg, Wp, nullptr, nullptr, nullptr, nullptr,
        EE, 1.f, ACT_NONE, nullptr, 0.f, nullptr, nullptr, nullptr, nullptr, sw_b);
  };
  auto norm = [&](const float* af, const unsigned short* ab, const float* res,
                  const unsigned short* resb, const float* w,
                  unsigned short* o1, unsigned short* o2, int mode){
    norm_b_kernel<<<MM, 256, 0, stream>>>(af, ab, res, resb, w, o1, o2, peb, mode);
  };
  auto retention = [&](const float* h0, float* hnew, unsigned short* o, int enc){
    wchunk_kernel<<<dim3(8, HH, BB), 256, 0, stream>>>(kloT_b, khiT_b, vT_b, wc_lo,
        enc ? wcum_hi : nullptr, enc);
    wscan_kernel<<<BB*HH, 256, 0, stream>>>(wc_lo, wcum_lo, enc ? wcum_hi : nullptr,
        h0, tmx, hnew, enc);
    if (enc)
      retention2_kernel<1><<<dim3(8, HH, BB), 256, 0, stream>>>(
          qlo_b, qhi_b, klo_b, khi_b, vT_b, wcum_lo, wcum_hi, stepc, o);
    else
      retention2_kernel<0><<<dim3(8, HH, BB), 256, 0, stream>>>(
          qlo_b, nullptr, klo_b, nullptr, vT_b, wcum_lo, nullptr, stepc, o);
  };

  // ---- encoder embed ----
  norm_obs_kernel<<<MM, 128, 0, stream>>>(obs, eoln, obs_n);
  gemmF(obs_n, wt_eow, nullptr, f32a, OBSD, 1.f, ACT_GELU);   // f32a = obs_rep

  // ---- encoder layers ----
  for (int i = 0; i < LL; ++i){
    if (i == 0) norm(f32a, nullptr, nullptr, nullptr, eln, x_b, x_pe_b, NORM_PLAIN);
    else        norm(nullptr, xrep_b, nullptr, nullptr, eln, x_b, x_pe_b, NORM_PLAIN);
    gemmQ(x_pe_b, wt_ewq + i*W55, 1);
    gemmK(x_pe_b, wt_ewk + i*W55, 1);
    gemmV(x_pe_b, wt_ewv + i*W55);
    retention(enc_hs + i*HS_L, enc_out + i*HS_L, t1_b, 1);
    gemmF(t1_b, wt_ewo + i*W55, nullptr, f32a, EE, 1.f, ACT_NONE);
    norm(nullptr, x_b, f32a, nullptr, eln1 + i*EE, t1_b, nullptr, NORM_ADD);
    gemmSW(t1_b, wt_efg + i*W55, wt_efp + i*W55);
    norm(nullptr, t1_b, nullptr, sw_b, eln2 + i*EE, xrep_b, xrep_pe_b, NORM_ADD);
  }

  // ---- value head ----
  gemmF(xrep_b, wt_ehw1, ehb1, f32a, EE, 1.f, ACT_GELU);
  norm(f32a, nullptr, nullptr, nullptr, ehln, t1_b, nullptr, NORM_PLAIN);
  value_head_kernel<<<MM/32, 256, 0, stream>>>(t1_b, ehw2, ehb2, value_out);

  // ---- decoder embed ----
  act_embed_kernel<<<(MM*64)/256, 256, 0, stream>>>(action, act_b);
  gemmF(act_b, wt_daw, nullptr, f32a, 64, 1.f, ACT_GELU);
  norm(f32a, nullptr, nullptr, nullptr, dln, x_b, x_pe_b, NORM_PLAIN);

  // ---- decoder layers ----
  for (int i = 0; i < LL; ++i){
    gemmQ(x_pe_b, wt_dwq1 + i*W55, 0);
    gemmK(x_pe_b, wt_dwk1 + i*W55, 0);
    gemmV(x_pe_b, wt_dwv1 + i*W55);
    retention(dec_hs1 + i*HS_L, d1_out + i*HS_L, t1_b, 0);
    gemmF(t1_b, wt_dwo1 + i*W55, nullptr, f32a, EE, 1.f, ACT_NONE);
    norm(nullptr, x_b, f32a, nullptr, dln1 + i*EE, t1_b, t1_pe_b, NORM_ADD);   // r
    gemmQ(xrep_pe_b, wt_dwq2 + i*W55, 0);
    gemmK(t1_pe_b,   wt_dwk2 + i*W55, 0);
    gemmV(t1_pe_b,   wt_dwv2 + i*W55);
    retention(dec_hs2 + i*HS_L, d2_out + i*HS_L, t1_b, 0);
    gemmF(t1_b, wt_dwo2 + i*W55, nullptr, f32a, EE, 1.f, ACT_NONE);
    norm(nullptr, xrep_b, f32a, nullptr, dln2 + i*EE, x_b, nullptr, NORM_ADD); // y
    gemmSW(x_b, wt_dfg + i*W55, wt_dfp + i*W55);
    norm(nullptr, x_b, nullptr, sw_b, dln3 + i*EE, x_b, x_pe_b, NORM_ADD);
  }

  // ---- logits head ----
  gemmF(x_b, wt_dhw1, dhb1, f32a, EE, 1.f, ACT_GELU);
  norm(f32a, nullptr, nullptr, nullptr, dhln, t1_b, nullptr, NORM_PLAIN);
  logits_head_kernel<<<MM/16, 256, 0, stream>>>(t1_b, dhw2, dhb2, logits_out);
}

// Round 4
// 1356.552 us; speedup vs baseline: 1.3137x; 1.1537x over previous
//
#include <hip/hip_runtime.h>
#include <hip/hip_bf16.h>
#include <math.h>

typedef __attribute__((ext_vector_type(8))) short short8;     // 8 bf16 = 4 VGPRs
typedef __attribute__((ext_vector_type(4))) short short4v;    // 4 bf16 = 8B
typedef __attribute__((ext_vector_type(4))) float f32x4;

#define BB 16
#define SS 512
#define EE 512
#define HH 8
#define DH 64
#define LL 3
#define MM (BB*SS)
#define OBSD 128
#define ACTD 17
#define INV_SQRT_D 0.125f

#define ACT_NONE 0
#define ACT_GELU 1

#define NORM_PLAIN 0
#define NORM_ADD 1

__device__ __forceinline__ float gelu_f(float x){
  float x3 = x*x*x;
  return 0.5f*x*(1.f + tanhf(0.7978845608028654f*(x + 0.044715f*x3)));
}
__device__ __forceinline__ float silu_f(float x){ return x/(1.f+expf(-x)); }
__device__ __forceinline__ float lkappa(int h){ return logf(1.f - exp2f(-5.f - (float)h)); }
__device__ __forceinline__ unsigned short f2bs(float f){
  unsigned int u = __float_as_uint(f);
  u += 0x7FFFu + ((u >> 16) & 1u);
  return (unsigned short)(u >> 16);
}
__device__ __forceinline__ float bs2f(unsigned short u){
  return __uint_as_float(((unsigned int)u) << 16);
}

// async global->LDS, 16B per lane. LDS dest = wave-uniform base + lane*16 (linear).
typedef const __attribute__((address_space(1))) unsigned int* gas1_t;
typedef __attribute__((address_space(3))) unsigned int* las3_t;
__device__ __forceinline__ void gl16(const void* g, void* l){
  __builtin_amdgcn_global_load_lds((gas1_t)g, (las3_t)l, 16, 0, 0);
}

// raw pipeline sync: wait own async loads, block barrier, pin scheduler.
#define PIPE_SYNC do{ asm volatile("s_waitcnt vmcnt(0)" ::: "memory"); \
                      __builtin_amdgcn_s_barrier(); \
                      __builtin_amdgcn_sched_barrier(0); }while(0)

// ---------------- weight transpose: W[K][512] fp32 -> Wt[512][Kpad] bf16 ----------------
__global__ __launch_bounds__(256) void wtpose_kernel(
    const float* __restrict__ src, unsigned short* __restrict__ dst, int K, int Kpad)
{
  __shared__ float t[32][33];
  const int gx = blockIdx.x, gy = blockIdx.y;
  const int tx = threadIdx.x, ty = threadIdx.y;
  #pragma unroll
  for (int i = 0; i < 4; ++i){
    int k = gx*32 + ty + i*8, n = gy*32 + tx;
    t[ty+i*8][tx] = (k < K) ? src[(size_t)k*EE + n] : 0.f;
  }
  __syncthreads();
  #pragma unroll
  for (int i = 0; i < 4; ++i){
    int k = gx*32 + tx, n = gy*32 + ty + i*8;
    dst[(size_t)n*Kpad + k] = f2bs(t[tx][ty+i*8]);
  }
}

struct TP50 { const float* s[50]; unsigned short* d[50]; };
__global__ __launch_bounds__(256) void wtpose_batch_kernel(TP50 tp)
{
  __shared__ float t[32][33];
  const float* src = tp.s[blockIdx.z];
  unsigned short* dst = tp.d[blockIdx.z];
  const int gx = blockIdx.x, gy = blockIdx.y;
  const int tx = threadIdx.x, ty = threadIdx.y;
  #pragma unroll
  for (int i = 0; i < 4; ++i){
    int k = gx*32 + ty + i*8, n = gy*32 + tx;
    t[ty+i*8][tx] = src[(size_t)k*EE + n];
  }
  __syncthreads();
  #pragma unroll
  for (int i = 0; i < 4; ++i){
    int k = gx*32 + tx, n = gy*32 + ty + i*8;
    dst[(size_t)n*EE + k] = f2bs(t[tx][ty+i*8]);
  }
}

// ---------------- MFMA GEMM (double-buffered global_load_lds, XOR-swizzled LDS) ----------------
// SW=0: outputs fp32 C and/or bf16 Cb; decay mode (tsi != null) writes lo_n (Q path).
// SW=1: second weight Wt2; writes swo = bf16 silu(A@Wt)*(A@Wt2) only.
template<int SW>
__global__ __launch_bounds__(256) void gemm_b_kernel(
    const unsigned short* __restrict__ A, const unsigned short* __restrict__ Wt,
    const unsigned short* __restrict__ Wt2,
    const float* __restrict__ bias, float* __restrict__ C,
    unsigned short* __restrict__ Cb,
    int Kpad, float scale, int act,
    const int* __restrict__ tsi, float dsign,
    unsigned short* __restrict__ lo_n,
    unsigned short* __restrict__ swo)
{
  __shared__ unsigned short As[2][128*64];
  __shared__ unsigned short Bs[2][64*64];
  __shared__ unsigned short Bs2[SW ? 2 : 1][SW ? 64*64 : 8];
  const int bm = blockIdx.y*128, bn = blockIdx.x*64;
  const int tid = threadIdx.x, lane = tid & 63, wv = tid >> 6;
  const int wr = wv >> 1, wc = wv & 1;
  const int l16 = lane & 15, quad = lane >> 4;

  f32x4 acc[4][2], acc2[SW ? 4 : 1][SW ? 2 : 1];
  #pragma unroll
  for (int i=0;i<4;i++){ acc[i][0]=(f32x4)(0.f); acc[i][1]=(f32x4)(0.f); }
  if (SW){
    #pragma unroll
    for (int i=0;i<4;i++){ acc2[i][0]=(f32x4)(0.f); acc2[i][1]=(f32x4)(0.f); }
  }

  // staging: lane covers physical granule; row = granule>>3, logical slot = (g&7)^(row&7)
  const int sg = lane >> 3;
  const int lg = (lane & 7) ^ sg;
  size_t aoff[4], boff[2];
  #pragma unroll
  for (int i=0;i<4;i++)
    aoff[i] = (size_t)(bm + (wv*4+i)*8 + sg)*Kpad + lg*8;
  #pragma unroll
  for (int i=0;i<2;i++)
    boff[i] = (size_t)(bn + (wv*2+i)*8 + sg)*Kpad + lg*8;

  const int swz = (l16 & 7) << 3;            // read-side XOR (elements)

  auto STAGE = [&](int buf, int t){
    const int k0 = t*64;
    #pragma unroll
    for (int i=0;i<4;i++)
      gl16(A + aoff[i] + k0, (char*)&As[buf][0] + ((wv*4+i) << 10));
    #pragma unroll
    for (int i=0;i<2;i++)
      gl16(Wt + boff[i] + k0, (char*)&Bs[buf][0] + ((wv*2+i) << 10));
    if (SW){
      #pragma unroll
      for (int i=0;i<2;i++)
        gl16(Wt2 + boff[i] + k0, (char*)&Bs2[buf][0] + ((wv*2+i) << 10));
    }
  };
  auto COMPUTE = [&](int buf){
    short8 af[4][2], bf[2][2];
    #pragma unroll
    for (int mt=0; mt<4; ++mt)
      #pragma unroll
      for (int ks=0; ks<2; ++ks)
        af[mt][ks] = *(const short8*)&As[buf][(wr*64 + mt*16 + l16)*64 + ((ks*32 + quad*8) ^ swz)];
    #pragma unroll
    for (int nt=0; nt<2; ++nt)
      #pragma unroll
      for (int ks=0; ks<2; ++ks)
        bf[nt][ks] = *(const short8*)&Bs[buf][(wc*32 + nt*16 + l16)*64 + ((ks*32 + quad*8) ^ swz)];
    #pragma unroll
    for (int ks=0; ks<2; ++ks)
      #pragma unroll
      for (int mt=0; mt<4; ++mt)
        #pragma unroll
        for (int nt=0; nt<2; ++nt)
          acc[mt][nt] = __builtin_amdgcn_mfma_f32_16x16x32_bf16(af[mt][ks], bf[nt][ks], acc[mt][nt], 0, 0, 0);
    if (SW){
      short8 bf2[2][2];
      #pragma unroll
      for (int nt=0; nt<2; ++nt)
        #pragma unroll
        for (int ks=0; ks<2; ++ks)
          bf2[nt][ks] = *(const short8*)&Bs2[buf][(wc*32 + nt*16 + l16)*64 + ((ks*32 + quad*8) ^ swz)];
      #pragma unroll
      for (int ks=0; ks<2; ++ks)
        #pragma unroll
        for (int mt=0; mt<4; ++mt)
          #pragma unroll
          for (int nt=0; nt<2; ++nt)
            acc2[mt][nt] = __builtin_amdgcn_mfma_f32_16x16x32_bf16(af[mt][ks], bf2[nt][ks], acc2[mt][nt], 0, 0, 0);
    }
  };

  const int NT = Kpad >> 6;
  STAGE(0, 0);
  PIPE_SYNC;
  int cur = 0;
  for (int t = 0; t < NT; ++t){
    if (t+1 < NT) STAGE(cur^1, t+1);
    COMPUTE(cur);
    if (t+1 < NT) PIPE_SYNC;
    cur ^= 1;
  }

  const float lkh = (!SW && tsi) ? lkappa(bn >> 6) : 0.f;
  #pragma unroll
  for (int mt=0; mt<4; ++mt){
    int rb = bm + wr*64 + mt*16 + quad*4;
    if (SW){
      #pragma unroll
      for (int nt=0; nt<2; ++nt){
        int col = bn + wc*32 + nt*16 + l16;
        #pragma unroll
        for (int j=0;j<4;j++)
          swo[(size_t)(rb+j)*EE + col] = f2bs(silu_f(acc[mt][nt][j])*acc2[mt][nt][j]);
      }
      continue;
    }
    float e0[4];
    if (tsi){
      #pragma unroll
      for (int j=0;j<4;j++) e0[j] = __expf(dsign*lkh*(float)tsi[rb+j]);
    }
    #pragma unroll
    for (int nt=0; nt<2; ++nt){
      int col = bn + wc*32 + nt*16 + l16;
      float bv = bias ? bias[col] : 0.f;
      float vals[4];
      #pragma unroll
      for (int j=0;j<4;j++){
        float v = acc[mt][nt][j]*scale + bv;
        if (act==ACT_GELU) v = gelu_f(v);
        vals[j] = v;
      }
      if (C){
        #pragma unroll
        for (int j=0;j<4;j++) C[(size_t)(rb+j)*EE + col] = vals[j];
      }
      if (Cb){
        #pragma unroll
        for (int j=0;j<4;j++) Cb[(size_t)(rb+j)*EE + col] = f2bs(vals[j]);
      }
      if (tsi){
        #pragma unroll
        for (int j=0;j<4;j++) lo_n[(size_t)(rb+j)*EE + col] = f2bs(vals[j]*e0[j]);
      }
    }
  }
}

// ---------------- fused QKV / KV projection GEMM (same pipeline) ----------------
// Wt is a fused [ngroups*512][512] block. group = gstart + (bn>>9):
//   0: Q -> qlo (+qhi enc) ; 1: K (scale 1/8) -> klo,kloT (+khi,khiT enc) ; 2: V -> vT
template<int ENC>
__global__ __launch_bounds__(256) void gemm_qkv_kernel(
    const unsigned short* __restrict__ A, const unsigned short* __restrict__ Wt,
    int gstart, const int* __restrict__ tsi,
    unsigned short* __restrict__ qlo, unsigned short* __restrict__ qhi,
    unsigned short* __restrict__ klo, unsigned short* __restrict__ kloT,
    unsigned short* __restrict__ khi, unsigned short* __restrict__ khiT,
    unsigned short* __restrict__ vT)
{
  __shared__ unsigned short As[2][128*64];
  __shared__ unsigned short Bs[2][64*64];
  const int bm = blockIdx.y*128, bn = blockIdx.x*64;
  const int tid = threadIdx.x, lane = tid & 63, wv = tid >> 6;
  const int wr = wv >> 1, wc = wv & 1;
  const int l16 = lane & 15, quad = lane >> 4;

  f32x4 acc[4][2];
  #pragma unroll
  for (int i=0;i<4;i++){ acc[i][0]=(f32x4)(0.f); acc[i][1]=(f32x4)(0.f); }

  const int sg = lane >> 3;
  const int lg = (lane & 7) ^ sg;
  size_t aoff[4], boff[2];
  #pragma unroll
  for (int i=0;i<4;i++)
    aoff[i] = (size_t)(bm + (wv*4+i)*8 + sg)*EE + lg*8;
  #pragma unroll
  for (int i=0;i<2;i++)
    boff[i] = (size_t)(bn + (wv*2+i)*8 + sg)*EE + lg*8;

  const int swz = (l16 & 7) << 3;

  auto STAGE = [&](int buf, int t){
    const int k0 = t*64;
    #pragma unroll
    for (int i=0;i<4;i++)
      gl16(A + aoff[i] + k0, (char*)&As[buf][0] + ((wv*4+i) << 10));
    #pragma unroll
    for (int i=0;i<2;i++)
      gl16(Wt + boff[i] + k0, (char*)&Bs[buf][0] + ((wv*2+i) << 10));
  };
  auto COMPUTE = [&](int buf){
    short8 af[4][2], bf[2][2];
    #pragma unroll
    for (int mt=0; mt<4; ++mt)
      #pragma unroll
      for (int ks=0; ks<2; ++ks)
        af[mt][ks] = *(const short8*)&As[buf][(wr*64 + mt*16 + l16)*64 + ((ks*32 + quad*8) ^ swz)];
    #pragma unroll
    for (int nt=0; nt<2; ++nt)
      #pragma unroll
      for (int ks=0; ks<2; ++ks)
        bf[nt][ks] = *(const short8*)&Bs[buf][(wc*32 + nt*16 + l16)*64 + ((ks*32 + quad*8) ^ swz)];
    #pragma unroll
    for (int ks=0; ks<2; ++ks)
      #pragma unroll
      for (int mt=0; mt<4; ++mt)
        #pragma unroll
        for (int nt=0; nt<2; ++nt)
          acc[mt][nt] = __builtin_amdgcn_mfma_f32_16x16x32_bf16(af[mt][ks], bf[nt][ks], acc[mt][nt], 0, 0, 0);
  };

  STAGE(0, 0);
  PIPE_SYNC;
  int cur = 0;
  for (int t = 0; t < 8; ++t){
    if (t+1 < 8) STAGE(cur^1, t+1);
    COMPUTE(cur);
    if (t+1 < 8) PIPE_SYNC;
    cur ^= 1;
  }

  const int group = gstart + (bn >> 9);
  const int coll = bn & 511;               // column within logical 512-wide output
  const int hh = coll >> 6;                // block-uniform head
  const float lkh = lkappa(hh);
  const float scl = (group == 1) ? INV_SQRT_D : 1.f;
  const float dsg = (group == 1) ? -1.f : 1.f;

  #pragma unroll
  for (int mt=0; mt<4; ++mt){
    int rb = bm + wr*64 + mt*16 + quad*4;
    float e0[4], e1[4];
    if (group < 2){
      #pragma unroll
      for (int j=0;j<4;j++){
        float x = dsg*lkh*(float)tsi[rb+j];
        e0[j] = __expf(x); e1[j] = __expf(-x);
      }
    }
    int bloc = rb >> 9, m0 = rb & 511;
    #pragma unroll
    for (int nt=0; nt<2; ++nt){
      int col = coll + wc*32 + nt*16 + l16;
      int ee = col & 63;
      size_t taddr = (((size_t)bloc*HH + hh)*DH + ee)*SS + m0;
      float vals[4];
      #pragma unroll
      for (int j=0;j<4;j++) vals[j] = acc[mt][nt][j]*scl;
      if (group == 0){
        #pragma unroll
        for (int j=0;j<4;j++) qlo[(size_t)(rb+j)*EE + col] = f2bs(vals[j]*e0[j]);
        if (ENC){
          #pragma unroll
          for (int j=0;j<4;j++) qhi[(size_t)(rb+j)*EE + col] = f2bs(vals[j]*e1[j]);
        }
      } else if (group == 1){
        short4v pk;
        #pragma unroll
        for (int j=0;j<4;j++){
          unsigned short v = f2bs(vals[j]*e0[j]);
          klo[(size_t)(rb+j)*EE + col] = v;
          pk[j] = (short)v;
        }
        *(short4v*)&kloT[taddr] = pk;
        if (ENC){
          short4v pk2;
          #pragma unroll
          for (int j=0;j<4;j++){
            unsigned short v = f2bs(vals[j]*e1[j]);
            khi[(size_t)(rb+j)*EE + col] = v;
            pk2[j] = (short)v;
          }
          *(short4v*)&khiT[taddr] = pk2;
        }
      } else {
        short4v pk;
        #pragma unroll
        for (int j=0;j<4;j++) pk[j] = (short)f2bs(vals[j]);
        *(short4v*)&vT[taddr] = pk;
      }
    }
  }
}

// ---------------- rmsnorm: wave-per-row, no LDS / barriers ----------------
__global__ __launch_bounds__(256) void norm_b_kernel(
    const float* __restrict__ af, const unsigned short* __restrict__ ab,
    const float* __restrict__ res, const unsigned short* __restrict__ resb,
    const float* __restrict__ w, unsigned short* __restrict__ o1,
    unsigned short* __restrict__ o2, const unsigned short* __restrict__ peb,
    int mode)
{
  const int row = blockIdx.x*4 + (threadIdx.x >> 6);
  const int lane = threadIdx.x & 63;
  const size_t base = (size_t)row*EE + lane*8;
  float t[8];
  if (ab){
    short8 av = *(const short8*)&ab[base];
    #pragma unroll
    for (int e=0;e<8;++e) t[e] = bs2f((unsigned short)av[e]);
  } else {
    float4 a0 = *(const float4*)&af[base];
    float4 a1 = *(const float4*)&af[base+4];
    t[0]=a0.x;t[1]=a0.y;t[2]=a0.z;t[3]=a0.w;t[4]=a1.x;t[5]=a1.y;t[6]=a1.z;t[7]=a1.w;
  }
  if (mode == NORM_ADD){
    if (resb){
      short8 rv = *(const short8*)&resb[base];
      #pragma unroll
      for (int e=0;e<8;++e) t[e] += bs2f((unsigned short)rv[e]);
    } else {
      float4 r0 = *(const float4*)&res[base];
      float4 r1 = *(const float4*)&res[base+4];
      t[0]+=r0.x;t[1]+=r0.y;t[2]+=r0.z;t[3]+=r0.w;t[4]+=r1.x;t[5]+=r1.y;t[6]+=r1.z;t[7]+=r1.w;
    }
  }
  float ss = 0.f;
  #pragma unroll
  for (int e=0;e<8;++e) ss += t[e]*t[e];
  #pragma unroll
  for (int o=32;o;o>>=1) ss += __shfl_xor(ss, o);
  float r = 1.f/sqrtf(ss/(float)EE + 1e-6f);
  float4 w0 = *(const float4*)&w[lane*8];
  float4 w1 = *(const float4*)&w[lane*8+4];
  float y[8];
  y[0]=t[0]*r*w0.x; y[1]=t[1]*r*w0.y; y[2]=t[2]*r*w0.z; y[3]=t[3]*r*w0.w;
  y[4]=t[4]*r*w1.x; y[5]=t[5]*r*w1.y; y[6]=t[6]*r*w1.z; y[7]=t[7]*r*w1.w;
  short8 pk;
  #pragma unroll
  for (int e=0;e<8;++e) pk[e] = (short)f2bs(y[e]);
  *(short8*)&o1[base] = pk;
  if (o2){
    short8 pv = *(const short8*)&peb[base];
    short8 pz;
    #pragma unroll
    for (int e=0;e<8;++e) pz[e] = (short)f2bs(y[e] + bs2f((unsigned short)pv[e]));
    *(short8*)&o2[base] = pz;
  }
}

// obs norm: wave-per-row, fp32 [MM][128] -> bf16
__global__ __launch_bounds__(256) void norm_obs_kernel(
    const float* __restrict__ a, const float* __restrict__ w, unsigned short* __restrict__ o)
{
  const int row = blockIdx.x*4 + (threadIdx.x >> 6);
  const int lane = threadIdx.x & 63;
  const size_t base = (size_t)row*OBSD + lane*2;
  float2 av = *(const float2*)&a[base];
  float ss = av.x*av.x + av.y*av.y;
  #pragma unroll
  for (int off=32;off;off>>=1) ss += __shfl_xor(ss, off);
  float r = 1.f/sqrtf(ss/(float)OBSD + 1e-6f);
  float2 wv2 = *(const float2*)&w[lane*2];
  unsigned int pk = (unsigned int)f2bs(av.x*r*wv2.x) | ((unsigned int)f2bs(av.y*r*wv2.y) << 16);
  *(unsigned int*)&o[base] = pk;
}

// action embed: fp32 [MM][17] -> bf16 [MM][64] zero-padded
__global__ __launch_bounds__(256) void act_embed_kernel(
    const float* __restrict__ a, unsigned short* __restrict__ o)
{
  int idx = blockIdx.x*256 + threadIdx.x;
  int row = idx >> 6, col = idx & 63;
  o[idx] = (col < ACTD) ? f2bs(a[(size_t)row*ACTD + col]) : 0;
}

// ---------------- chunk state: Wc_lo[e][d] = sum_m vT[e][m]*kloT[d][m] (fp32),
//                  encoder also Wc_hi with khiT (bf16 out) ----------------
__global__ __launch_bounds__(256) void wchunk_kernel(
    const unsigned short* __restrict__ kloT, const unsigned short* __restrict__ khiT,
    const unsigned short* __restrict__ vT,
    float* __restrict__ wlo, unsigned short* __restrict__ whi, int enc)
{
  __shared__ unsigned short vsh[64*72];
  __shared__ unsigned short ksh[64*72];
  __shared__ unsigned short ksh2[64*72];
  const int c = blockIdx.x, h = blockIdx.y, b = blockIdx.z;
  const int tid = threadIdx.x, lane = tid & 63, wv = tid >> 6;
  const int quad = lane >> 4, l16 = lane & 15;
  const int mc = c*64;
  {
    const int r = tid >> 2, seg = (tid & 3)*16;
    const unsigned short* vrow = vT   + (((size_t)b*HH + h)*DH + r)*SS + mc + seg;
    const unsigned short* krow = kloT + (((size_t)b*HH + h)*DH + r)*SS + mc + seg;
    #pragma unroll
    for (int i = 0; i < 2; ++i){
      *(short8*)&vsh[r*72 + seg + i*8] = *(const short8*)(vrow + i*8);
      *(short8*)&ksh[r*72 + seg + i*8] = *(const short8*)(krow + i*8);
    }
    if (enc){
      const unsigned short* k2row = khiT + (((size_t)b*HH + h)*DH + r)*SS + mc + seg;
      #pragma unroll
      for (int i = 0; i < 2; ++i)
        *(short8*)&ksh2[r*72 + seg + i*8] = *(const short8*)(k2row + i*8);
    }
  }
  __syncthreads();
  short8 av[2];
  #pragma unroll
  for (int ks=0; ks<2; ++ks)
    av[ks] = *(const short8*)&vsh[(wv*16 + l16)*72 + ks*32 + quad*8];
  f32x4 acc[4];
  #pragma unroll
  for (int dt=0; dt<4; ++dt) acc[dt] = (f32x4)(0.f);
  #pragma unroll
  for (int ks=0; ks<2; ++ks)
    #pragma unroll
    for (int dt=0; dt<4; ++dt){
      short8 kb = *(const short8*)&ksh[(dt*16 + l16)*72 + ks*32 + quad*8];
      acc[dt] = __builtin_amdgcn_mfma_f32_16x16x32_bf16(av[ks], kb, acc[dt], 0, 0, 0);
    }
  size_t obase = (((size_t)b*HH + h)*8 + c)*4096;
  #pragma unroll
  for (int dt=0; dt<4; ++dt)
    #pragma unroll
    for (int j=0;j<4;j++)
      wlo[obase + (size_t)(wv*16 + quad*4 + j)*64 + dt*16 + l16] = acc[dt][j];
  if (enc){
    f32x4 acc2[4];
    #pragma unroll
    for (int dt=0; dt<4; ++dt) acc2[dt] = (f32x4)(0.f);
    #pragma unroll
    for (int ks=0; ks<2; ++ks)
      #pragma unroll
      for (int dt=0; dt<4; ++dt){
        short8 kb = *(const short8*)&ksh2[(dt*16 + l16)*72 + ks*32 + quad*8];
        acc2[dt] = __builtin_amdgcn_mfma_f32_16x16x32_bf16(av[ks], kb, acc2[dt], 0, 0, 0);
      }
    #pragma unroll
    for (int dt=0; dt<4; ++dt)
      #pragma unroll
      for (int j=0;j<4;j++)
        whi[obase + (size_t)(wv*16 + quad*4 + j)*64 + dt*16 + l16] = f2bs(acc2[dt][j]);
  }
}

// ---------------- scan ----------------
__global__ __launch_bounds__(256) void wscan_kernel(
    const float* __restrict__ wc, unsigned short* __restrict__ wcum,
    unsigned short* whi,
    const float* __restrict__ h0, const float* __restrict__ tmx,
    float* __restrict__ hnew, int enc)
{
  const int bh = blockIdx.x, b = bh >> 3, h = bh & 7;
  const float lk = lkappa(h);
  const float elk = __expf(lk);
  const float etm = __expf(lk*tmx[b]);
  const size_t wbase = (size_t)bh*8*4096;
  const size_t hbase = (size_t)b*(LL*HH*DH*DH) + (size_t)h*(DH*DH);
  for (int i = 0; i < 16; ++i){
    int p = i*256 + threadIdx.x;        // p = e*64 + d
    int e = p >> 6, d = p & 63;
    float acc = elk * h0[hbase + d*64 + e];
    #pragma unroll
    for (int c = 0; c < 8; ++c){
      float reg = wc[wbase + c*4096 + p];
      wcum[wbase + c*4096 + p] = f2bs(acc);
      acc += reg;
    }
    hnew[hbase + d*64 + e] = etm * acc;
    if (enc){
      float a2 = 0.f;
      #pragma unroll
      for (int c = 7; c >= 0; --c){
        float reg = bs2f(whi[wbase + c*4096 + p]);
        whi[wbase + c*4096 + p] = f2bs(a2);
        a2 += reg;
      }
    }
  }
}

// ---------------- retention (chunked-recurrent) ----------------
template<int ENC>
__global__ __launch_bounds__(256) void retention2_kernel(
    const unsigned short* __restrict__ qlo, const unsigned short* __restrict__ qhi,
    const unsigned short* __restrict__ klo, const unsigned short* __restrict__ khi,
    const unsigned short* __restrict__ vT,
    const unsigned short* __restrict__ wlo, const unsigned short* __restrict__ whi,
    const int* __restrict__ tsi, unsigned short* __restrict__ outp)
{
  __shared__ unsigned short qsh[64*72];        // reused as psh in boundary
  __shared__ unsigned short wsh[64*72];
  __shared__ unsigned short ksh[64*72];
  __shared__ unsigned short vsh[64*72];
  __shared__ unsigned short qsh2[ENC ? 64*72 : 2];  // reused as ksh2 in boundary
  __shared__ unsigned short wsh2[ENC ? 64*72 : 2];
  __shared__ float tsf[SS];
  const int b = blockIdx.z, h = blockIdx.y, t = blockIdx.x;
  const int n0 = t*64;
  const int tid = threadIdx.x, lane = tid & 63, wv = tid >> 6;
  const int quad = lane >> 4, l16 = lane & 15;

  for (int i = tid; i < SS; i += 256) tsf[i] = (float)tsi[b*SS + i];
  {
    const int n = tid >> 2, seg = (tid & 3)*16;
    const unsigned short* qr = qlo + ((size_t)b*SS + n0 + n)*EE + h*DH + seg;
    #pragma unroll
    for (int i = 0; i < 2; ++i)
      *(short8*)&qsh[n*72 + seg + i*8] = *(const short8*)(qr + i*8);
    const unsigned short* wr = wlo + (((size_t)b*HH + h)*8 + t)*4096 + (size_t)n*64 + seg;
    #pragma unroll
    for (int i = 0; i < 2; ++i)
      *(short8*)&wsh[n*72 + seg + i*8] = *(const short8*)(wr + i*8);
    if (ENC){
      const unsigned short* qr2 = qhi + ((size_t)b*SS + n0 + n)*EE + h*DH + seg;
      #pragma unroll
      for (int i = 0; i < 2; ++i)
        *(short8*)&qsh2[n*72 + seg + i*8] = *(const short8*)(qr2 + i*8);
      const unsigned short* wr2 = whi + (((size_t)b*HH + h)*8 + t)*4096 + (size_t)n*64 + seg;
      #pragma unroll
      for (int i = 0; i < 2; ++i)
        *(short8*)&wsh2[n*72 + seg + i*8] = *(const short8*)(wr2 + i*8);
    }
  }
  __syncthreads();

  const int rowbase = wv*16;
  short8 qa[2], qa2[2];
  #pragma unroll
  for (int ks=0; ks<2; ++ks)
    qa[ks] = *(const short8*)&qsh[(rowbase + l16)*72 + ks*32 + quad*8];
  if (ENC){
    #pragma unroll
    for (int ks=0; ks<2; ++ks)
      qa2[ks] = *(const short8*)&qsh2[(rowbase + l16)*72 + ks*32 + quad*8];
  }

  float tn = tsf[n0 + lane];
  float maxn = tn, minn = tn;
  #pragma unroll
  for (int o=32;o;o>>=1){
    maxn = fmaxf(maxn, __shfl_xor(maxn, o));
    minn = fminf(minn, __shfl_xor(minn, o));
  }

  // cross-chunk + h0 contribution
  f32x4 acc_o[4];
  #pragma unroll
  for (int et=0; et<4; ++et){
    f32x4 a = (f32x4)(0.f);
    #pragma unroll
    for (int ks=0; ks<2; ++ks){
      short8 wb = *(const short8*)&wsh[(et*16 + l16)*72 + ks*32 + quad*8];
      a = __builtin_amdgcn_mfma_f32_16x16x32_bf16(qa[ks], wb, a, 0, 0, 0);
    }
    if (ENC){
      #pragma unroll
      for (int ks=0; ks<2; ++ks){
        short8 wb2 = *(const short8*)&wsh2[(et*16 + l16)*72 + ks*32 + quad*8];
        a = __builtin_amdgcn_mfma_f32_16x16x32_bf16(qa2[ks], wb2, a, 0, 0, 0);
      }
    }
    acc_o[et] = a;
  }

  // boundary chunk(s)
  for (int c = 0; c < 8; ++c){
    const int mc = c*64;
    float tmv = tsf[mc + lane];
    float maxm = tmv, minm = tmv;
    #pragma unroll
    for (int o=32;o;o>>=1){
      maxm = fmaxf(maxm, __shfl_xor(maxm, o));
      minm = fminf(minm, __shfl_xor(minm, o));
    }
    if (ENC){
      if (maxm <= minn) continue;
      if (minm >= maxn) continue;
    } else {
      if ((maxm < minn) || (maxm == minn && (mc + 63) < n0)) continue;
      if (minm > maxn) continue;
    }
    __syncthreads();
    {
      const int m = tid >> 2, cb = (tid & 3)*16;
      const unsigned short* krow = klo + ((size_t)b*SS + mc + m)*EE + h*DH + cb;
      #pragma unroll
      for (int i = 0; i < 2; ++i)
        *(short8*)&ksh[m*72 + cb + i*8] = *(const short8*)(krow + i*8);
      const unsigned short* vrow = vT + (((size_t)b*HH + h)*DH + m)*SS + mc + cb;
      #pragma unroll
      for (int i = 0; i < 2; ++i)
        *(short8*)&vsh[m*72 + cb + i*8] = *(const short8*)(vrow + i*8);
      if (ENC){
        const unsigned short* k2row = khi + ((size_t)b*SS + mc + m)*EE + h*DH + cb;
        #pragma unroll
        for (int i = 0; i < 2; ++i)
          *(short8*)&qsh2[m*72 + cb + i*8] = *(const short8*)(k2row + i*8);
      }
    }
    __syncthreads();
    f32x4 sacc[4], sacc2[4];
    #pragma unroll
    for (int mt=0; mt<4; ++mt){
      f32x4 a = (f32x4)(0.f);
      #pragma unroll
      for (int ks=0; ks<2; ++ks){
        short8 kb = *(const short8*)&ksh[(mt*16 + l16)*72 + ks*32 + quad*8];
        a = __builtin_amdgcn_mfma_f32_16x16x32_bf16(qa[ks], kb, a, 0, 0, 0);
      }
      sacc[mt] = a;
      if (ENC){
        f32x4 a2 = (f32x4)(0.f);
        #pragma unroll
        for (int ks=0; ks<2; ++ks){
          short8 kb2 = *(const short8*)&qsh2[(mt*16 + l16)*72 + ks*32 + quad*8];
          a2 = __builtin_amdgcn_mfma_f32_16x16x32_bf16(qa2[ks], kb2, a2, 0, 0, 0);
        }
        sacc2[mt] = a2;
      }
    }
    float tsm[4]; int mg[4];
    #pragma unroll
    for (int mt=0; mt<4; ++mt){ mg[mt] = mc + mt*16 + l16; tsm[mt] = tsf[mg[mt]]; }
    #pragma unroll
    for (int j=0;j<4;j++){
      int nloc = rowbase + quad*4 + j;
      int n = n0 + nloc;
      float tsn = tsf[n];
      #pragma unroll
      for (int mt=0; mt<4; ++mt){
        float diff = tsn - tsm[mt];
        float p;
        if (ENC) p = (diff >= 0.f) ? sacc[mt][j] : sacc2[mt][j];
        else     p = ((diff > 0.f) || (diff == 0.f && n >= mg[mt])) ? sacc[mt][j] : 0.f;
        qsh[nloc*72 + mt*16 + l16] = f2bs(p);   // qsh reused as psh
      }
    }
    #pragma unroll
    for (int ks=0; ks<2; ++ks){
      short8 pa = *(const short8*)&qsh[(rowbase + l16)*72 + ks*32 + quad*8];
      #pragma unroll
      for (int et=0; et<4; ++et){
        short8 vb = *(const short8*)&vsh[(et*16 + l16)*72 + ks*32 + quad*8];
        acc_o[et] = __builtin_amdgcn_mfma_f32_16x16x32_bf16(pa, vb, acc_o[et], 0, 0, 0);
      }
    }
  }
  #pragma unroll
  for (int j=0;j<4;j++){
    size_t rbase = ((size_t)b*SS + n0 + rowbase + quad*4 + j)*EE + h*DH;
    #pragma unroll
    for (int et=0; et<4; ++et)
      outp[rbase + et*16 + l16] = f2bs(acc_o[et][j]);
  }
}

// ---------------- small helpers ----------------
__global__ void tsmax_kernel(const int* __restrict__ tsi, float* __restrict__ tmx){
  __shared__ int red[4];
  int b = blockIdx.x, tid = threadIdx.x;
  int m = max(tsi[b*SS+tid], tsi[b*SS+256+tid]);
  #pragma unroll
  for (int o=32;o;o>>=1) m = max(m, __shfl_down(m,o));
  if ((tid&63)==0) red[tid>>6]=m;
  __syncthreads();
  if (tid==0) tmx[b] = (float)max(max(red[0],red[1]),max(red[2],red[3]));
}

__global__ void pe_kernel(const int* __restrict__ tsi, unsigned short* __restrict__ peb){
  int idx = blockIdx.x*256 + threadIdx.x;
  int row = idx >> 9, j = idx & 511;
  float ts = (float)tsi[row];
  int jj = j & 255;
  float freq = expf(-9.210340371976184f*(float)jj*(1.f/256.f));
  float ang = ts*freq;
  peb[idx] = f2bs((j < 256) ? sinf(ang) : cosf(ang));
}

__global__ __launch_bounds__(256) void value_head_kernel(
    const unsigned short* __restrict__ x, const float* __restrict__ w,
    const float* __restrict__ bias, float* __restrict__ outp)
{
  const int tid = threadIdx.x, lane = tid & 63, wv = tid >> 6;
  const int r8 = lane >> 3, seg = lane & 7;
  const int row = blockIdx.x*32 + wv*8 + r8;
  const unsigned short* xr = x + (size_t)row*EE + seg*64;
  const float* wr = w + seg*64;
  float s = 0.f;
  #pragma unroll
  for (int i = 0; i < 8; ++i){
    short8 xv = *(const short8*)(xr + i*8);
    #pragma unroll
    for (int e = 0; e < 8; ++e)
      s += bs2f((unsigned short)xv[e]) * wr[i*8 + e];
  }
  s += __shfl_xor(s, 1); s += __shfl_xor(s, 2); s += __shfl_xor(s, 4);
  if (seg == 0) outp[row] = s + bias[0];
}

__global__ __launch_bounds__(256) void logits_head_kernel(
    const unsigned short* __restrict__ x, const float* __restrict__ w,
    const float* __restrict__ bias, float* __restrict__ outp)
{
  __shared__ unsigned short xsh[16*520];
  __shared__ unsigned short wsh[16*520];
  const int tid = threadIdx.x;
  const int row0 = blockIdx.x*16;
  {
    const int r = tid >> 4, kc = (tid & 15)*32;
    const unsigned short* xr = x + (size_t)(row0 + r)*EE + kc;
    #pragma unroll
    for (int i = 0; i < 4; ++i)
      *(short8*)&xsh[r*520 + kc + i*8] = *(const short8*)(xr + i*8);
    const int j = r;
    #pragma unroll
    for (int kk = 0; kk < 32; ++kk)
      wsh[j*520 + kc + kk] = f2bs(w[(size_t)(kc + kk)*16 + j]);
  }
  __syncthreads();
  const int r = tid >> 4, j = tid & 15;
  float s = 0.f;
  for (int k = 0; k < EE; k += 8){
    short8 xv = *(const short8*)&xsh[r*520 + k];
    short8 wv = *(const short8*)&wsh[j*520 + k];
    #pragma unroll
    for (int e = 0; e < 8; ++e)
      s += bs2f((unsigned short)xv[e]) * bs2f((unsigned short)wv[e]);
  }
  outp[(size_t)(row0 + r)*16 + j] = s + bias[j];
}

// ---------------- orchestration ----------------
extern "C" void kernel_launch(void* const* d_in, const int* in_sizes, int n_in,
                              void* d_out, int out_size, void* d_ws, size_t ws_size,
                              hipStream_t stream)
{
  const float* obs     = (const float*)d_in[0];
  const float* action  = (const float*)d_in[1];
  const float* enc_hs  = (const float*)d_in[2];
  const float* dec_hs1 = (const float*)d_in[3];
  const float* dec_hs2 = (const float*)d_in[4];
  const int*   stepc   = (const int*)d_in[5];
  const float* eoln = (const float*)d_in[6];
  const float* eow  = (const float*)d_in[7];
  const float* eln  = (const float*)d_in[8];
  const float* ewq  = (const float*)d_in[9];
  const float* ewk  = (const float*)d_in[10];
  const float* ewv  = (const float*)d_in[11];
  const float* ewo  = (const float*)d_in[12];
  const float* eln1 = (const float*)d_in[13];
  const float* eln2 = (const float*)d_in[14];
  const float* efg  = (const float*)d_in[15];
  const float* efp  = (const float*)d_in[16];
  const float* ehw1 = (const float*)d_in[17];
  const float* ehb1 = (const float*)d_in[18];
  const float* ehln = (const float*)d_in[19];
  const float* ehw2 = (const float*)d_in[20];
  const float* ehb2 = (const float*)d_in[21];
  const float* daw  = (const float*)d_in[22];
  const float* dln  = (const float*)d_in[23];
  const float* dwq1 = (const float*)d_in[24];
  const float* dwk1 = (const float*)d_in[25];
  const float* dwv1 = (const float*)d_in[26];
  const float* dwo1 = (const float*)d_in[27];
  const float* dwq2 = (const float*)d_in[28];
  const float* dwk2 = (const float*)d_in[29];
  const float* dwv2 = (const float*)d_in[30];
  const float* dwo2 = (const float*)d_in[31];
  const float* dln1 = (const float*)d_in[32];
  const float* dln2 = (const float*)d_in[33];
  const float* dln3 = (const float*)d_in[34];
  const float* dfg  = (const float*)d_in[35];
  const float* dfp  = (const float*)d_in[36];
  const float* dhw1 = (const float*)d_in[37];
  const float* dhb1 = (const float*)d_in[38];
  const float* dhln = (const float*)d_in[39];
  const float* dhw2 = (const float*)d_in[40];
  const float* dhb2 = (const float*)d_in[41];

  const size_t BUF = (size_t)MM*EE;
  // fp32 region
  float* wsf  = (float*)d_ws;
  float* f32a = wsf;              // obs_rep / wo-out / gelu heads ; also Wcum_lo+Wcum_hi (bf16)
  float* f32b = f32a + BUF;       // Wc_lo (fp32) ; also sw_b (bf16)
  float* tmx  = f32b + BUF;
  // retention / FFN scratch aliases
  float* wc_lo = f32b;                                  // [B][H][8][4096] fp32
  unsigned short* wcum_lo = (unsigned short*)f32a;      // [B][H][8][4096] bf16
  unsigned short* wcum_hi = wcum_lo + BUF;              // [B][H][8][4096] bf16 (enc; in-place scan)
  unsigned short* sw_b    = (unsigned short*)f32b;      // silu(g)*p bf16 (after retention)
  // bf16 region
  unsigned short* ub = (unsigned short*)(tmx + 64);
  unsigned short* xrep_b    = ub;  ub += BUF;
  unsigned short* xrep_pe_b = ub;  ub += BUF;
  unsigned short* x_b       = ub;  ub += BUF;
  unsigned short* x_pe_b    = ub;  ub += BUF;
  unsigned short* t1_b      = ub;  ub += BUF;
  unsigned short* t1_pe_b   = ub;  ub += BUF;   // decoder-only; aliased as qhi_b (encoder-only)
  unsigned short* peb       = ub;  ub += BUF;
  unsigned short* qlo_b     = ub;  ub += BUF;
  unsigned short* klo_b     = ub;  ub += BUF;
  unsigned short* kloT_b    = ub;  ub += BUF;
  unsigned short* khi_b     = ub;  ub += BUF;
  unsigned short* khiT_b    = ub;  ub += BUF;
  unsigned short* vT_b      = ub;  ub += BUF;   // [B][H][64][512]
  unsigned short* obs_n     = ub;  ub += (size_t)MM*OBSD;
  unsigned short* act_b     = obs_n;            // aliased (obs_n dead by decoder embed)
  unsigned short* qhi_b     = t1_pe_b;          // alias
  // weights
  const size_t W55 = (size_t)EE*EE;
  unsigned short* wts = ub;  ub += 50*W55;
  unsigned short* wt_eow = ub; ub += (size_t)EE*OBSD;
  unsigned short* wt_daw = ub; ub += (size_t)EE*64;
  size_t need = (char*)ub - (char*)d_ws;
  if (ws_size < need) return;

  // fused-weight layout (z index into wts):
  // 0..8  : enc [q,k,v] x3 layers     9..11 : ewo
  // 12..14: efg   15..17: efp   18: ehw1
  // 19..27: dec1 [q,k,v] x3           28..30: dwo1
  // 31..36: dec2 [k,v] x3             37..39: dwq2
  // 40..42: dwo2  43..45: dfg  46..48: dfp   49: dhw1
  unsigned short* wt_eqkv  = wts + 0*W55;   // +3*i per layer
  unsigned short* wt_ewo   = wts + 9*W55;
  unsigned short* wt_efg   = wts + 12*W55;
  unsigned short* wt_efp   = wts + 15*W55;
  unsigned short* wt_ehw1  = wts + 18*W55;
  unsigned short* wt_dqkv1 = wts + 19*W55;  // +3*i
  unsigned short* wt_dwo1  = wts + 28*W55;
  unsigned short* wt_dkv2  = wts + 31*W55;  // +2*i
  unsigned short* wt_dwq2  = wts + 37*W55;
  unsigned short* wt_dwo2  = wts + 40*W55;
  unsigned short* wt_dfg   = wts + 43*W55;
  unsigned short* wt_dfp   = wts + 46*W55;
  unsigned short* wt_dhw1  = wts + 49*W55;

  float* out        = (float*)d_out;
  float* value_out  = out;
  float* logits_out = out + 8192;
  float* enc_out    = logits_out + (size_t)MM*16;
  float* d1_out     = enc_out + (size_t)BB*LL*HH*DH*DH;
  float* d2_out     = d1_out  + (size_t)BB*LL*HH*DH*DH;

  const size_t HS_L = (size_t)HH*DH*DH;

  {
    TP50 tp;
    int z = 0;
    auto add = [&](const float* p){ tp.s[z] = p; tp.d[z] = wts + (size_t)z*W55; ++z; };
    for (int i=0;i<3;++i){ add(ewq+i*W55); add(ewk+i*W55); add(ewv+i*W55); }
    for (int i=0;i<3;++i) add(ewo+i*W55);
    for (int i=0;i<3;++i) add(efg+i*W55);
    for (int i=0;i<3;++i) add(efp+i*W55);
    add(ehw1);
    for (int i=0;i<3;++i){ add(dwq1+i*W55); add(dwk1+i*W55); add(dwv1+i*W55); }
    for (int i=0;i<3;++i) add(dwo1+i*W55);
    for (int i=0;i<3;++i){ add(dwk2+i*W55); add(dwv2+i*W55); }
    for (int i=0;i<3;++i) add(dwq2+i*W55);
    for (int i=0;i<3;++i) add(dwo2+i*W55);
    for (int i=0;i<3;++i) add(dfg+i*W55);
    for (int i=0;i<3;++i) add(dfp+i*W55);
    add(dhw1);
    wtpose_batch_kernel<<<dim3(16,16,50), dim3(32,8), 0, stream>>>(tp);
  }
  wtpose_kernel<<<dim3(4,16), dim3(32,8), 0, stream>>>(eow, wt_eow, OBSD, OBSD);
  wtpose_kernel<<<dim3(2,16), dim3(32,8), 0, stream>>>(daw, wt_daw, ACTD, 64);

  pe_kernel<<<(MM*EE)/256, 256, 0, stream>>>(stepc, peb);
  tsmax_kernel<<<BB, 256, 0, stream>>>(stepc, tmx);

  auto gemmF = [&](const unsigned short* A, const unsigned short* Wt, const float* bias,
                   float* C, int Kpad, float scale, int act){
    gemm_b_kernel<0><<<dim3(EE/64, MM/128), 256, 0, stream>>>(A, Wt, nullptr, bias, C, nullptr,
        Kpad, scale, act, nullptr, 0.f, nullptr, nullptr);
  };
  auto gemmQ2 = [&](const unsigned short* A, const unsigned short* Wt){
    gemm_b_kernel<0><<<dim3(EE/64, MM/128), 256, 0, stream>>>(A, Wt, nullptr, nullptr, nullptr, nullptr,
        EE, 1.f, ACT_NONE, stepc, 1.f, qlo_b, nullptr);
  };
  auto gemmSW = [&](const unsigned short* A, const unsigned short* Wg, const unsigned short* Wp){
    gemm_b_kernel<1><<<dim3(EE/64, MM/128), 256, 0, stream>>>(A, Wg, Wp, nullptr, nullptr, nullptr,
        EE, 1.f, ACT_NONE, nullptr, 0.f, nullptr, sw_b);
  };
  auto gemmQKV = [&](const unsigned short* A, const unsigned short* Wt, int enc){
    if (enc)
      gemm_qkv_kernel<1><<<dim3(24, MM/128), 256, 0, stream>>>(A, Wt, 0, stepc,
          qlo_b, qhi_b, klo_b, kloT_b, khi_b, khiT_b, vT_b);
    else
      gemm_qkv_kernel<0><<<dim3(24, MM/128), 256, 0, stream>>>(A, Wt, 0, stepc,
          qlo_b, nullptr, klo_b, kloT_b, nullptr, nullptr, vT_b);
  };
  auto gemmKV = [&](const unsigned short* A, const unsigned short* Wt){
    gemm_qkv_kernel<0><<<dim3(16, MM/128), 256, 0, stream>>>(A, Wt, 1, stepc,
        nullptr, nullptr, klo_b, kloT_b, nullptr, nullptr, vT_b);
  };
  auto norm = [&](const float* af, const unsigned short* ab, const float* res,
                  const unsigned short* resb, const float* w,
                  unsigned short* o1, unsigned short* o2, int mode){
    norm_b_kernel<<<MM/4, 256, 0, stream>>>(af, ab, res, resb, w, o1, o2, peb, mode);
  };
  auto retention = [&](const float* h0, float* hnew, unsigned short* o, int enc){
    wchunk_kernel<<<dim3(8, HH, BB), 256, 0, stream>>>(kloT_b, khiT_b, vT_b, wc_lo,
        enc ? wcum_hi : nullptr, enc);
    wscan_kernel<<<BB*HH, 256, 0, stream>>>(wc_lo, wcum_lo, enc ? wcum_hi : nullptr,
        h0, tmx, hnew, enc);
    if (enc)
      retention2_kernel<1><<<dim3(8, HH, BB), 256, 0, stream>>>(
          qlo_b, qhi_b, klo_b, khi_b, vT_b, wcum_lo, wcum_hi, stepc, o);
    else
      retention2_kernel<0><<<dim3(8, HH, BB), 256, 0, stream>>>(
          qlo_b, nullptr, klo_b, nullptr, vT_b, wcum_lo, nullptr, stepc, o);
  };

  // ---- encoder embed ----
  norm_obs_kernel<<<MM/4, 256, 0, stream>>>(obs, eoln, obs_n);
  gemmF(obs_n, wt_eow, nullptr, f32a, OBSD, 1.f, ACT_GELU);   // f32a = obs_rep

  // ---- encoder layers ----
  for (int i = 0; i < LL; ++i){
    if (i == 0) norm(f32a, nullptr, nullptr, nullptr, eln, x_b, x_pe_b, NORM_PLAIN);
    else        norm(nullptr, xrep_b, nullptr, nullptr, eln, x_b, x_pe_b, NORM_PLAIN);
    gemmQKV(x_pe_b, wt_eqkv + (size_t)3*i*W55, 1);
    retention(enc_hs + i*HS_L, enc_out + i*HS_L, t1_b, 1);
    gemmF(t1_b, wt_ewo + i*W55, nullptr, f32a, EE, 1.f, ACT_NONE);
    norm(nullptr, x_b, f32a, nullptr, eln1 + i*EE, t1_b, nullptr, NORM_ADD);
    gemmSW(t1_b, wt_efg + i*W55, wt_efp + i*W55);
    norm(nullptr, t1_b, nullptr, sw_b, eln2 + i*EE, xrep_b, xrep_pe_b, NORM_ADD);
  }

  // ---- value head ----
  gemmF(xrep_b, wt_ehw1, ehb1, f32a, EE, 1.f, ACT_GELU);
  norm(f32a, nullptr, nullptr, nullptr, ehln, t1_b, nullptr, NORM_PLAIN);
  value_head_kernel<<<MM/32, 256, 0, stream>>>(t1_b, ehw2, ehb2, value_out);

  // ---- decoder embed ----
  act_embed_kernel<<<(MM*64)/256, 256, 0, stream>>>(action, act_b);
  gemmF(act_b, wt_daw, nullptr, f32a, 64, 1.f, ACT_GELU);
  norm(f32a, nullptr, nullptr, nullptr, dln, x_b, x_pe_b, NORM_PLAIN);

  // ---- decoder layers ----
  for (int i = 0; i < LL; ++i){
    gemmQKV(x_pe_b, wt_dqkv1 + (size_t)3*i*W55, 0);
    retention(dec_hs1 + i*HS_L, d1_out + i*HS_L, t1_b, 0);
    gemmF(t1_b, wt_dwo1 + i*W55, nullptr, f32a, EE, 1.f, ACT_NONE);
    norm(nullptr, x_b, f32a, nullptr, dln1 + i*EE, t1_b, t1_pe_b, NORM_ADD);   // r
    gemmQ2(xrep_pe_b, wt_dwq2 + i*W55);
    gemmKV(t1_pe_b, wt_dkv2 + (size_t)2*i*W55);
    retention(dec_hs2 + i*HS_L, d2_out + i*HS_L, t1_b, 0);
    gemmF(t1_b, wt_dwo2 + i*W55, nullptr, f32a, EE, 1.f, ACT_NONE);
    norm(nullptr, xrep_b, f32a, nullptr, dln2 + i*EE, x_b, nullptr, NORM_ADD); // y
    gemmSW(x_b, wt_dfg + i*W55, wt_dfp + i*W55);
    norm(nullptr, x_b, nullptr, sw_b, dln3 + i*EE, x_b, x_pe_b, NORM_ADD);
  }

  // ---- logits head ----
  gemmF(x_b, wt_dhw1, dhb1, f32a, EE, 1.f, ACT_GELU);
  norm(f32a, nullptr, nullptr, nullptr, dhln, t1_b, nullptr, NORM_PLAIN);
  logits_head_kernel<<<MM/16, 256, 0, stream>>>(t1_b, dhw2, dhb2, logits_out);
}

// Round 5
// 1247.264 us; speedup vs baseline: 1.4288x; 1.0876x over previous
//
#include <hip/hip_runtime.h>
#include <hip/hip_bf16.h>
#include <math.h>

typedef __attribute__((ext_vector_type(8))) short short8;     // 8 bf16 = 4 VGPRs
typedef __attribute__((ext_vector_type(4))) short short4v;    // 4 bf16 = 8B
typedef __attribute__((ext_vector_type(4))) float f32x4;

#define BB 16
#define SS 512
#define EE 512
#define HH 8
#define DH 64
#define LL 3
#define MM (BB*SS)
#define OBSD 128
#define ACTD 17
#define INV_SQRT_D 0.125f

#define ACT_NONE 0
#define ACT_GELU 1

#define NORM_PLAIN 0
#define NORM_ADD 1

__device__ __forceinline__ float gelu_f(float x){
  float x3 = x*x*x;
  return 0.5f*x*(1.f + tanhf(0.7978845608028654f*(x + 0.044715f*x3)));
}
__device__ __forceinline__ float silu_f(float x){ return x/(1.f+expf(-x)); }
__device__ __forceinline__ float lkappa(int h){ return logf(1.f - exp2f(-5.f - (float)h)); }
__device__ __forceinline__ unsigned short f2bs(float f){
  unsigned int u = __float_as_uint(f);
  u += 0x7FFFu + ((u >> 16) & 1u);
  return (unsigned short)(u >> 16);
}
__device__ __forceinline__ float bs2f(unsigned short u){
  return __uint_as_float(((unsigned int)u) << 16);
}

// async global->LDS, 16B per lane. LDS dest = wave-uniform base + lane*16 (linear).
typedef const __attribute__((address_space(1))) unsigned int* gas1_t;
typedef __attribute__((address_space(3))) unsigned int* las3_t;
__device__ __forceinline__ void gl16(const void* g, void* l){
  __builtin_amdgcn_global_load_lds((gas1_t)g, (las3_t)l, 16, 0, 0);
}

// raw pipeline sync: wait own async loads, block barrier, pin scheduler.
#define PIPE_SYNC do{ asm volatile("s_waitcnt vmcnt(0)" ::: "memory"); \
                      __builtin_amdgcn_s_barrier(); \
                      __builtin_amdgcn_sched_barrier(0); }while(0)

// ---------------- weight transpose: W[K][512] fp32 -> Wt[512][Kpad] bf16 ----------------
__global__ __launch_bounds__(256) void wtpose_kernel(
    const float* __restrict__ src, unsigned short* __restrict__ dst, int K, int Kpad)
{
  __shared__ float t[32][33];
  const int gx = blockIdx.x, gy = blockIdx.y;
  const int tx = threadIdx.x, ty = threadIdx.y;
  #pragma unroll
  for (int i = 0; i < 4; ++i){
    int k = gx*32 + ty + i*8, n = gy*32 + tx;
    t[ty+i*8][tx] = (k < K) ? src[(size_t)k*EE + n] : 0.f;
  }
  __syncthreads();
  #pragma unroll
  for (int i = 0; i < 4; ++i){
    int k = gx*32 + tx, n = gy*32 + ty + i*8;
    dst[(size_t)n*Kpad + k] = f2bs(t[tx][ty+i*8]);
  }
}

struct TP50 { const float* s[50]; unsigned short* d[50]; };
__global__ __launch_bounds__(256) void wtpose_batch_kernel(TP50 tp)
{
  __shared__ float t[32][33];
  const float* src = tp.s[blockIdx.z];
  unsigned short* dst = tp.d[blockIdx.z];
  const int gx = blockIdx.x, gy = blockIdx.y;
  const int tx = threadIdx.x, ty = threadIdx.y;
  #pragma unroll
  for (int i = 0; i < 4; ++i){
    int k = gx*32 + ty + i*8, n = gy*32 + tx;
    t[ty+i*8][tx] = src[(size_t)k*EE + n];
  }
  __syncthreads();
  #pragma unroll
  for (int i = 0; i < 4; ++i){
    int k = gx*32 + tx, n = gy*32 + ty + i*8;
    dst[(size_t)n*EE + k] = f2bs(t[tx][ty+i*8]);
  }
}

// ---------------- 128x128 MFMA GEMM (double-buffered global_load_lds, XOR-swizzled LDS) ----------------
// MODE 0: C = act(scale*(A@W) + bias) fp32.
// MODE 1: QKV epilogue. group = gstart + (bn>>9):
//   0: Q -> qlo (+qhi ENC) ; 1: K (scale 1/8) -> klo,kloT (+khi,khiT ENC) ; 2: V -> vT
template<int MODE, int ENC>
__global__ __launch_bounds__(256) void gemm128_kernel(
    const unsigned short* __restrict__ A, const unsigned short* __restrict__ Wt,
    const float* __restrict__ bias, float* __restrict__ C,
    int Kpad, float scale, int act,
    int gstart, const int* __restrict__ tsi,
    unsigned short* __restrict__ qlo, unsigned short* __restrict__ qhi,
    unsigned short* __restrict__ klo, unsigned short* __restrict__ kloT,
    unsigned short* __restrict__ khi, unsigned short* __restrict__ khiT,
    unsigned short* __restrict__ vT)
{
  __shared__ unsigned short As[2][128*64];
  __shared__ unsigned short Bs[2][128*64];
  const int bm = blockIdx.y*128, bn = blockIdx.x*128;
  const int tid = threadIdx.x, lane = tid & 63, wv = tid >> 6;
  const int wr = wv >> 1, wc = wv & 1;
  const int l16 = lane & 15, quad = lane >> 4;

  f32x4 acc[4][4];
  #pragma unroll
  for (int i=0;i<4;i++)
    #pragma unroll
    for (int j=0;j<4;j++) acc[i][j]=(f32x4)(0.f);

  // staging: lane covers physical granule; row = granule>>3, logical slot = (g&7)^(row&7)
  const int sg = lane >> 3;
  const int lg = (lane & 7) ^ sg;
  size_t aoff[4], boff[4];
  #pragma unroll
  for (int i=0;i<4;i++){
    aoff[i] = (size_t)(bm + wv*32 + i*8 + sg)*Kpad + lg*8;
    boff[i] = (size_t)(bn + wv*32 + i*8 + sg)*Kpad + lg*8;
  }
  const int swz = (l16 & 7) << 3;            // read-side XOR (elements)

  auto STAGE = [&](int buf, int t){
    const int k0 = t*64;
    #pragma unroll
    for (int i=0;i<4;i++){
      gl16(A + aoff[i] + k0, (char*)&As[buf][0] + ((wv*4+i) << 10));
      gl16(Wt + boff[i] + k0, (char*)&Bs[buf][0] + ((wv*4+i) << 10));
    }
  };
  auto COMPUTE = [&](int buf){
    short8 af[4][2], bf[4][2];
    #pragma unroll
    for (int mt=0; mt<4; ++mt)
      #pragma unroll
      for (int ks=0; ks<2; ++ks)
        af[mt][ks] = *(const short8*)&As[buf][(wr*64 + mt*16 + l16)*64 + ((ks*32 + quad*8) ^ swz)];
    #pragma unroll
    for (int nt=0; nt<4; ++nt)
      #pragma unroll
      for (int ks=0; ks<2; ++ks)
        bf[nt][ks] = *(const short8*)&Bs[buf][(wc*64 + nt*16 + l16)*64 + ((ks*32 + quad*8) ^ swz)];
    #pragma unroll
    for (int ks=0; ks<2; ++ks)
      #pragma unroll
      for (int mt=0; mt<4; ++mt)
        #pragma unroll
        for (int nt=0; nt<4; ++nt)
          acc[mt][nt] = __builtin_amdgcn_mfma_f32_16x16x32_bf16(af[mt][ks], bf[nt][ks], acc[mt][nt], 0, 0, 0);
  };

  const int NT = Kpad >> 6;
  STAGE(0, 0);
  PIPE_SYNC;
  int cur = 0;
  for (int t = 0; t < NT; ++t){
    if (t+1 < NT) STAGE(cur^1, t+1);
    COMPUTE(cur);
    if (t+1 < NT) PIPE_SYNC;
    cur ^= 1;
  }

  if (MODE == 0){
    #pragma unroll
    for (int mt=0; mt<4; ++mt){
      int rb = bm + wr*64 + mt*16 + quad*4;
      #pragma unroll
      for (int nt=0; nt<4; ++nt){
        int col = bn + wc*64 + nt*16 + l16;
        float bv = bias ? bias[col] : 0.f;
        #pragma unroll
        for (int j=0;j<4;j++){
          float v = acc[mt][nt][j]*scale + bv;
          if (act==ACT_GELU) v = gelu_f(v);
          C[(size_t)(rb+j)*EE + col] = v;
        }
      }
    }
  } else {
    const int group = gstart + (bn >> 9);
    const int hh = ((bn & 511) >> 6) + wc;     // wave-uniform head (64-col span)
    const float lkh = lkappa(hh);
    const float scl = (group == 1) ? INV_SQRT_D : 1.f;
    const float dsg = (group == 1) ? -1.f : 1.f;
    #pragma unroll
    for (int mt=0; mt<4; ++mt){
      int rb = bm + wr*64 + mt*16 + quad*4;
      float e0[4], e1[4];
      if (group < 2){
        #pragma unroll
        for (int j=0;j<4;j++){
          float x = dsg*lkh*(float)tsi[rb+j];
          e0[j] = __expf(x); e1[j] = __expf(-x);
        }
      }
      int bloc = rb >> 9, m0 = rb & 511;
      #pragma unroll
      for (int nt=0; nt<4; ++nt){
        int ccol = (bn & 511) + wc*64 + nt*16 + l16;   // col within logical 512-wide output
        int ee = nt*16 + l16;                          // col within head
        size_t taddr = (((size_t)bloc*HH + hh)*DH + ee)*SS + m0;
        float vals[4];
        #pragma unroll
        for (int j=0;j<4;j++) vals[j] = acc[mt][nt][j]*scl;
        if (group == 0){
          #pragma unroll
          for (int j=0;j<4;j++) qlo[(size_t)(rb+j)*EE + ccol] = f2bs(vals[j]*e0[j]);
          if (ENC){
            #pragma unroll
            for (int j=0;j<4;j++) qhi[(size_t)(rb+j)*EE + ccol] = f2bs(vals[j]*e1[j]);
          }
        } else if (group == 1){
          short4v pk;
          #pragma unroll
          for (int j=0;j<4;j++){
            unsigned short v = f2bs(vals[j]*e0[j]);
            klo[(size_t)(rb+j)*EE + ccol] = v;
            pk[j] = (short)v;
          }
          *(short4v*)&kloT[taddr] = pk;
          if (ENC){
            short4v pk2;
            #pragma unroll
            for (int j=0;j<4;j++){
              unsigned short v = f2bs(vals[j]*e1[j]);
              khi[(size_t)(rb+j)*EE + ccol] = v;
              pk2[j] = (short)v;
            }
            *(short4v*)&khiT[taddr] = pk2;
          }
        } else {
          short4v pk;
          #pragma unroll
          for (int j=0;j<4;j++) pk[j] = (short)f2bs(vals[j]);
          *(short4v*)&vT[taddr] = pk;
        }
      }
    }
  }
}

// ---------------- SwiGLU GEMM (128x64, dual weight): swo = silu(A@Wg)*(A@Wp) ----------------
__global__ __launch_bounds__(256) void gemm_sw_kernel(
    const unsigned short* __restrict__ A, const unsigned short* __restrict__ Wt,
    const unsigned short* __restrict__ Wt2, unsigned short* __restrict__ swo)
{
  __shared__ unsigned short As[2][128*64];
  __shared__ unsigned short Bs[2][64*64];
  __shared__ unsigned short Bs2[2][64*64];
  const int bm = blockIdx.y*128, bn = blockIdx.x*64;
  const int tid = threadIdx.x, lane = tid & 63, wv = tid >> 6;
  const int wr = wv >> 1, wc = wv & 1;
  const int l16 = lane & 15, quad = lane >> 4;

  f32x4 acc[4][2], acc2[4][2];
  #pragma unroll
  for (int i=0;i<4;i++){
    acc[i][0]=(f32x4)(0.f); acc[i][1]=(f32x4)(0.f);
    acc2[i][0]=(f32x4)(0.f); acc2[i][1]=(f32x4)(0.f);
  }

  const int sg = lane >> 3;
  const int lg = (lane & 7) ^ sg;
  size_t aoff[4], boff[2];
  #pragma unroll
  for (int i=0;i<4;i++)
    aoff[i] = (size_t)(bm + (wv*4+i)*8 + sg)*EE + lg*8;
  #pragma unroll
  for (int i=0;i<2;i++)
    boff[i] = (size_t)(bn + (wv*2+i)*8 + sg)*EE + lg*8;

  const int swz = (l16 & 7) << 3;

  auto STAGE = [&](int buf, int t){
    const int k0 = t*64;
    #pragma unroll
    for (int i=0;i<4;i++)
      gl16(A + aoff[i] + k0, (char*)&As[buf][0] + ((wv*4+i) << 10));
    #pragma unroll
    for (int i=0;i<2;i++){
      gl16(Wt + boff[i] + k0, (char*)&Bs[buf][0] + ((wv*2+i) << 10));
      gl16(Wt2 + boff[i] + k0, (char*)&Bs2[buf][0] + ((wv*2+i) << 10));
    }
  };
  auto COMPUTE = [&](int buf){
    short8 af[4][2], bf[2][2], bf2[2][2];
    #pragma unroll
    for (int mt=0; mt<4; ++mt)
      #pragma unroll
      for (int ks=0; ks<2; ++ks)
        af[mt][ks] = *(const short8*)&As[buf][(wr*64 + mt*16 + l16)*64 + ((ks*32 + quad*8) ^ swz)];
    #pragma unroll
    for (int nt=0; nt<2; ++nt)
      #pragma unroll
      for (int ks=0; ks<2; ++ks){
        bf[nt][ks]  = *(const short8*)&Bs[buf][(wc*32 + nt*16 + l16)*64 + ((ks*32 + quad*8) ^ swz)];
        bf2[nt][ks] = *(const short8*)&Bs2[buf][(wc*32 + nt*16 + l16)*64 + ((ks*32 + quad*8) ^ swz)];
      }
    #pragma unroll
    for (int ks=0; ks<2; ++ks)
      #pragma unroll
      for (int mt=0; mt<4; ++mt)
        #pragma unroll
        for (int nt=0; nt<2; ++nt){
          acc[mt][nt]  = __builtin_amdgcn_mfma_f32_16x16x32_bf16(af[mt][ks], bf[nt][ks],  acc[mt][nt],  0, 0, 0);
          acc2[mt][nt] = __builtin_amdgcn_mfma_f32_16x16x32_bf16(af[mt][ks], bf2[nt][ks], acc2[mt][nt], 0, 0, 0);
        }
  };

  STAGE(0, 0);
  PIPE_SYNC;
  int cur = 0;
  for (int t = 0; t < 8; ++t){
    if (t+1 < 8) STAGE(cur^1, t+1);
    COMPUTE(cur);
    if (t+1 < 8) PIPE_SYNC;
    cur ^= 1;
  }

  #pragma unroll
  for (int mt=0; mt<4; ++mt){
    int rb = bm + wr*64 + mt*16 + quad*4;
    #pragma unroll
    for (int nt=0; nt<2; ++nt){
      int col = bn + wc*32 + nt*16 + l16;
      #pragma unroll
      for (int j=0;j<4;j++)
        swo[(size_t)(rb+j)*EE + col] = f2bs(silu_f(acc[mt][nt][j])*acc2[mt][nt][j]);
    }
  }
}

// ---------------- rmsnorm: wave-per-row, no LDS / barriers ----------------
__global__ __launch_bounds__(256) void norm_b_kernel(
    const float* __restrict__ af, const unsigned short* __restrict__ ab,
    const float* __restrict__ res, const unsigned short* __restrict__ resb,
    const float* __restrict__ w, unsigned short* __restrict__ o1,
    unsigned short* __restrict__ o2, const unsigned short* __restrict__ peb,
    int mode)
{
  const int row = blockIdx.x*4 + (threadIdx.x >> 6);
  const int lane = threadIdx.x & 63;
  const size_t base = (size_t)row*EE + lane*8;
  float t[8];
  if (ab){
    short8 av = *(const short8*)&ab[base];
    #pragma unroll
    for (int e=0;e<8;++e) t[e] = bs2f((unsigned short)av[e]);
  } else {
    float4 a0 = *(const float4*)&af[base];
    float4 a1 = *(const float4*)&af[base+4];
    t[0]=a0.x;t[1]=a0.y;t[2]=a0.z;t[3]=a0.w;t[4]=a1.x;t[5]=a1.y;t[6]=a1.z;t[7]=a1.w;
  }
  if (mode == NORM_ADD){
    if (resb){
      short8 rv = *(const short8*)&resb[base];
      #pragma unroll
      for (int e=0;e<8;++e) t[e] += bs2f((unsigned short)rv[e]);
    } else {
      float4 r0 = *(const float4*)&res[base];
      float4 r1 = *(const float4*)&res[base+4];
      t[0]+=r0.x;t[1]+=r0.y;t[2]+=r0.z;t[3]+=r0.w;t[4]+=r1.x;t[5]+=r1.y;t[6]+=r1.z;t[7]+=r1.w;
    }
  }
  float ss = 0.f;
  #pragma unroll
  for (int e=0;e<8;++e) ss += t[e]*t[e];
  #pragma unroll
  for (int o=32;o;o>>=1) ss += __shfl_xor(ss, o);
  float r = 1.f/sqrtf(ss/(float)EE + 1e-6f);
  float4 w0 = *(const float4*)&w[lane*8];
  float4 w1 = *(const float4*)&w[lane*8+4];
  float y[8];
  y[0]=t[0]*r*w0.x; y[1]=t[1]*r*w0.y; y[2]=t[2]*r*w0.z; y[3]=t[3]*r*w0.w;
  y[4]=t[4]*r*w1.x; y[5]=t[5]*r*w1.y; y[6]=t[6]*r*w1.z; y[7]=t[7]*r*w1.w;
  short8 pk;
  #pragma unroll
  for (int e=0;e<8;++e) pk[e] = (short)f2bs(y[e]);
  *(short8*)&o1[base] = pk;
  if (o2){
    short8 pv = *(const short8*)&peb[base];
    short8 pz;
    #pragma unroll
    for (int e=0;e<8;++e) pz[e] = (short)f2bs(y[e] + bs2f((unsigned short)pv[e]));
    *(short8*)&o2[base] = pz;
  }
}

// obs norm: wave-per-row, fp32 [MM][128] -> bf16
__global__ __launch_bounds__(256) void norm_obs_kernel(
    const float* __restrict__ a, const float* __restrict__ w, unsigned short* __restrict__ o)
{
  const int row = blockIdx.x*4 + (threadIdx.x >> 6);
  const int lane = threadIdx.x & 63;
  const size_t base = (size_t)row*OBSD + lane*2;
  float2 av = *(const float2*)&a[base];
  float ss = av.x*av.x + av.y*av.y;
  #pragma unroll
  for (int off=32;off;off>>=1) ss += __shfl_xor(ss, off);
  float r = 1.f/sqrtf(ss/(float)OBSD + 1e-6f);
  float2 wv2 = *(const float2*)&w[lane*2];
  unsigned int pk = (unsigned int)f2bs(av.x*r*wv2.x) | ((unsigned int)f2bs(av.y*r*wv2.y) << 16);
  *(unsigned int*)&o[base] = pk;
}

// action embed: fp32 [MM][17] -> bf16 [MM][64] zero-padded
__global__ __launch_bounds__(256) void act_embed_kernel(
    const float* __restrict__ a, unsigned short* __restrict__ o)
{
  int idx = blockIdx.x*256 + threadIdx.x;
  int row = idx >> 6, col = idx & 63;
  o[idx] = (col < ACTD) ? f2bs(a[(size_t)row*ACTD + col]) : 0;
}

// ---------------- fused chunk-state + scan ----------------
// Per (b,h): forward pass over 8 chunks computes Wc_lo = vT@kloT^T in-register,
// writes prefix (elk*h0^T + sum_{c'<c}) as bf16 wcum_lo[c], accumulates, emits
// h_new = e^{lk*tm}*(elk*h0^T + sum_all). Encoder: second reverse pass for
// suffix sums of Wc_hi -> wcum_hi[c].
__global__ __launch_bounds__(256) void wchunkscan_kernel(
    const unsigned short* __restrict__ kloT, const unsigned short* __restrict__ khiT,
    const unsigned short* __restrict__ vT,
    const float* __restrict__ h0, const float* __restrict__ tmx,
    unsigned short* __restrict__ wcum_lo, unsigned short* __restrict__ wcum_hi,
    float* __restrict__ hnew, int enc)
{
  __shared__ unsigned short vsh[64*72];
  __shared__ unsigned short ksh[64*72];
  const int h = blockIdx.x, b = blockIdx.y;
  const int tid = threadIdx.x, lane = tid & 63, wv = tid >> 6;
  const int quad = lane >> 4, l16 = lane & 15;
  const float lk = lkappa(h);
  const float elk = __expf(lk);
  const float etm = __expf(lk*tmx[b]);
  const size_t wbase = ((size_t)b*HH + h)*8*4096;
  const size_t hbase = (size_t)b*(LL*HH*DH*DH) + (size_t)h*(DH*DH);
  const int e0r = wv*16 + quad*4;           // e (row of W^T layout) base; +j
  const int sr = tid >> 2, sseg = (tid & 3)*16;

  f32x4 cum[4];
  #pragma unroll
  for (int dt=0; dt<4; ++dt)
    #pragma unroll
    for (int j=0;j<4;j++)
      cum[dt][j] = elk * h0[hbase + (size_t)(dt*16+l16)*64 + e0r + j];

  for (int c = 0; c < 8; ++c){
    __syncthreads();
    {
      const unsigned short* vrow = vT   + (((size_t)b*HH + h)*DH + sr)*SS + c*64 + sseg;
      const unsigned short* krow = kloT + (((size_t)b*HH + h)*DH + sr)*SS + c*64 + sseg;
      #pragma unroll
      for (int i = 0; i < 2; ++i){
        *(short8*)&vsh[sr*72 + sseg + i*8] = *(const short8*)(vrow + i*8);
        *(short8*)&ksh[sr*72 + sseg + i*8] = *(const short8*)(krow + i*8);
      }
    }
    __syncthreads();
    short8 av[2];
    #pragma unroll
    for (int ks=0; ks<2; ++ks)
      av[ks] = *(const short8*)&vsh[(wv*16 + l16)*72 + ks*32 + quad*8];
    f32x4 acc[4];
    #pragma unroll
    for (int dt=0; dt<4; ++dt) acc[dt] = (f32x4)(0.f);
    #pragma unroll
    for (int ks=0; ks<2; ++ks)
      #pragma unroll
      for (int dt=0; dt<4; ++dt){
        short8 kb = *(const short8*)&ksh[(dt*16 + l16)*72 + ks*32 + quad*8];
        acc[dt] = __builtin_amdgcn_mfma_f32_16x16x32_bf16(av[ks], kb, acc[dt], 0, 0, 0);
      }
    #pragma unroll
    for (int dt=0; dt<4; ++dt)
      #pragma unroll
      for (int j=0;j<4;j++){
        wcum_lo[wbase + (size_t)c*4096 + (size_t)(e0r+j)*64 + dt*16 + l16] = f2bs(cum[dt][j]);
        cum[dt][j] += acc[dt][j];
      }
  }
  #pragma unroll
  for (int dt=0; dt<4; ++dt)
    #pragma unroll
    for (int j=0;j<4;j++)
      hnew[hbase + (size_t)(dt*16+l16)*64 + e0r + j] = etm * cum[dt][j];

  if (enc){
    f32x4 suf[4];
    #pragma unroll
    for (int dt=0; dt<4; ++dt) suf[dt] = (f32x4)(0.f);
    for (int c = 7; c >= 0; --c){
      __syncthreads();
      {
        const unsigned short* vrow = vT   + (((size_t)b*HH + h)*DH + sr)*SS + c*64 + sseg;
        const unsigned short* krow = khiT + (((size_t)b*HH + h)*DH + sr)*SS + c*64 + sseg;
        #pragma unroll
        for (int i = 0; i < 2; ++i){
          *(short8*)&vsh[sr*72 + sseg + i*8] = *(const short8*)(vrow + i*8);
          *(short8*)&ksh[sr*72 + sseg + i*8] = *(const short8*)(krow + i*8);
        }
      }
      __syncthreads();
      short8 av[2];
      #pragma unroll
      for (int ks=0; ks<2; ++ks)
        av[ks] = *(const short8*)&vsh[(wv*16 + l16)*72 + ks*32 + quad*8];
      f32x4 acc[4];
      #pragma unroll
      for (int dt=0; dt<4; ++dt) acc[dt] = (f32x4)(0.f);
      #pragma unroll
      for (int ks=0; ks<2; ++ks)
        #pragma unroll
        for (int dt=0; dt<4; ++dt){
          short8 kb = *(const short8*)&ksh[(dt*16 + l16)*72 + ks*32 + quad*8];
          acc[dt] = __builtin_amdgcn_mfma_f32_16x16x32_bf16(av[ks], kb, acc[dt], 0, 0, 0);
        }
      #pragma unroll
      for (int dt=0; dt<4; ++dt)
        #pragma unroll
        for (int j=0;j<4;j++){
          wcum_hi[wbase + (size_t)c*4096 + (size_t)(e0r+j)*64 + dt*16 + l16] = f2bs(suf[dt][j]);
          suf[dt][j] += acc[dt][j];
        }
    }
  }
}

// ---------------- retention (chunked-recurrent) ----------------
template<int ENC>
__global__ __launch_bounds__(256) void retention2_kernel(
    const unsigned short* __restrict__ qlo, const unsigned short* __restrict__ qhi,
    const unsigned short* __restrict__ klo, const unsigned short* __restrict__ khi,
    const unsigned short* __restrict__ vT,
    const unsigned short* __restrict__ wlo, const unsigned short* __restrict__ whi,
    const int* __restrict__ tsi, unsigned short* __restrict__ outp)
{
  __shared__ unsigned short qsh[64*72];        // reused as psh in boundary
  __shared__ unsigned short wsh[64*72];
  __shared__ unsigned short ksh[64*72];
  __shared__ unsigned short vsh[64*72];
  __shared__ unsigned short qsh2[ENC ? 64*72 : 2];  // reused as ksh2 in boundary
  __shared__ unsigned short wsh2[ENC ? 64*72 : 2];
  __shared__ float tsf[SS];
  const int b = blockIdx.z, h = blockIdx.y, t = blockIdx.x;
  const int n0 = t*64;
  const int tid = threadIdx.x, lane = tid & 63, wv = tid >> 6;
  const int quad = lane >> 4, l16 = lane & 15;

  for (int i = tid; i < SS; i += 256) tsf[i] = (float)tsi[b*SS + i];
  {
    const int n = tid >> 2, seg = (tid & 3)*16;
    const unsigned short* qr = qlo + ((size_t)b*SS + n0 + n)*EE + h*DH + seg;
    #pragma unroll
    for (int i = 0; i < 2; ++i)
      *(short8*)&qsh[n*72 + seg + i*8] = *(const short8*)(qr + i*8);
    const unsigned short* wr = wlo + (((size_t)b*HH + h)*8 + t)*4096 + (size_t)n*64 + seg;
    #pragma unroll
    for (int i = 0; i < 2; ++i)
      *(short8*)&wsh[n*72 + seg + i*8] = *(const short8*)(wr + i*8);
    if (ENC){
      const unsigned short* qr2 = qhi + ((size_t)b*SS + n0 + n)*EE + h*DH + seg;
      #pragma unroll
      for (int i = 0; i < 2; ++i)
        *(short8*)&qsh2[n*72 + seg + i*8] = *(const short8*)(qr2 + i*8);
      const unsigned short* wr2 = whi + (((size_t)b*HH + h)*8 + t)*4096 + (size_t)n*64 + seg;
      #pragma unroll
      for (int i = 0; i < 2; ++i)
        *(short8*)&wsh2[n*72 + seg + i*8] = *(const short8*)(wr2 + i*8);
    }
  }
  __syncthreads();

  const int rowbase = wv*16;
  short8 qa[2], qa2[2];
  #pragma unroll
  for (int ks=0; ks<2; ++ks)
    qa[ks] = *(const short8*)&qsh[(rowbase + l16)*72 + ks*32 + quad*8];
  if (ENC){
    #pragma unroll
    for (int ks=0; ks<2; ++ks)
      qa2[ks] = *(const short8*)&qsh2[(rowbase + l16)*72 + ks*32 + quad*8];
  }

  float tn = tsf[n0 + lane];
  float maxn = tn, minn = tn;
  #pragma unroll
  for (int o=32;o;o>>=1){
    maxn = fmaxf(maxn, __shfl_xor(maxn, o));
    minn = fminf(minn, __shfl_xor(minn, o));
  }

  // cross-chunk + h0 contribution
  f32x4 acc_o[4];
  #pragma unroll
  for (int et=0; et<4; ++et){
    f32x4 a = (f32x4)(0.f);
    #pragma unroll
    for (int ks=0; ks<2; ++ks){
      short8 wb = *(const short8*)&wsh[(et*16 + l16)*72 + ks*32 + quad*8];
      a = __builtin_amdgcn_mfma_f32_16x16x32_bf16(qa[ks], wb, a, 0, 0, 0);
    }
    if (ENC){
      #pragma unroll
      for (int ks=0; ks<2; ++ks){
        short8 wb2 = *(const short8*)&wsh2[(et*16 + l16)*72 + ks*32 + quad*8];
        a = __builtin_amdgcn_mfma_f32_16x16x32_bf16(qa2[ks], wb2, a, 0, 0, 0);
      }
    }
    acc_o[et] = a;
  }

  // boundary chunk(s)
  for (int c = 0; c < 8; ++c){
    const int mc = c*64;
    float tmv = tsf[mc + lane];
    float maxm = tmv, minm = tmv;
    #pragma unroll
    for (int o=32;o;o>>=1){
      maxm = fmaxf(maxm, __shfl_xor(maxm, o));
      minm = fminf(minm, __shfl_xor(minm, o));
    }
    if (ENC){
      if (maxm <= minn) continue;
      if (minm >= maxn) continue;
    } else {
      if ((maxm < minn) || (maxm == minn && (mc + 63) < n0)) continue;
      if (minm > maxn) continue;
    }
    __syncthreads();
    {
      const int m = tid >> 2, cb = (tid & 3)*16;
      const unsigned short* krow = klo + ((size_t)b*SS + mc + m)*EE + h*DH + cb;
      #pragma unroll
      for (int i = 0; i < 2; ++i)
        *(short8*)&ksh[m*72 + cb + i*8] = *(const short8*)(krow + i*8);
      const unsigned short* vrow = vT + (((size_t)b*HH + h)*DH + m)*SS + mc + cb;
      #pragma unroll
      for (int i = 0; i < 2; ++i)
        *(short8*)&vsh[m*72 + cb + i*8] = *(const short8*)(vrow + i*8);
      if (ENC){
        const unsigned short* k2row = khi + ((size_t)b*SS + mc + m)*EE + h*DH + cb;
        #pragma unroll
        for (int i = 0; i < 2; ++i)
          *(short8*)&qsh2[m*72 + cb + i*8] = *(const short8*)(k2row + i*8);
      }
    }
    __syncthreads();
    f32x4 sacc[4], sacc2[4];
    #pragma unroll
    for (int mt=0; mt<4; ++mt){
      f32x4 a = (f32x4)(0.f);
      #pragma unroll
      for (int ks=0; ks<2; ++ks){
        short8 kb = *(const short8*)&ksh[(mt*16 + l16)*72 + ks*32 + quad*8];
        a = __builtin_amdgcn_mfma_f32_16x16x32_bf16(qa[ks], kb, a, 0, 0, 0);
      }
      sacc[mt] = a;
      if (ENC){
        f32x4 a2 = (f32x4)(0.f);
        #pragma unroll
        for (int ks=0; ks<2; ++ks){
          short8 kb2 = *(const short8*)&qsh2[(mt*16 + l16)*72 + ks*32 + quad*8];
          a2 = __builtin_amdgcn_mfma_f32_16x16x32_bf16(qa2[ks], kb2, a2, 0, 0, 0);
        }
        sacc2[mt] = a2;
      }
    }
    float tsm[4]; int mg[4];
    #pragma unroll
    for (int mt=0; mt<4; ++mt){ mg[mt] = mc + mt*16 + l16; tsm[mt] = tsf[mg[mt]]; }
    #pragma unroll
    for (int j=0;j<4;j++){
      int nloc = rowbase + quad*4 + j;
      int n = n0 + nloc;
      float tsn = tsf[n];
      #pragma unroll
      for (int mt=0; mt<4; ++mt){
        float diff = tsn - tsm[mt];
        float p;
        if (ENC) p = (diff >= 0.f) ? sacc[mt][j] : sacc2[mt][j];
        else     p = ((diff > 0.f) || (diff == 0.f && n >= mg[mt])) ? sacc[mt][j] : 0.f;
        qsh[nloc*72 + mt*16 + l16] = f2bs(p);   // qsh reused as psh
      }
    }
    #pragma unroll
    for (int ks=0; ks<2; ++ks){
      short8 pa = *(const short8*)&qsh[(rowbase + l16)*72 + ks*32 + quad*8];
      #pragma unroll
      for (int et=0; et<4; ++et){
        short8 vb = *(const short8*)&vsh[(et*16 + l16)*72 + ks*32 + quad*8];
        acc_o[et] = __builtin_amdgcn_mfma_f32_16x16x32_bf16(pa, vb, acc_o[et], 0, 0, 0);
      }
    }
  }
  #pragma unroll
  for (int j=0;j<4;j++){
    size_t rbase = ((size_t)b*SS + n0 + rowbase + quad*4 + j)*EE + h*DH;
    #pragma unroll
    for (int et=0; et<4; ++et)
      outp[rbase + et*16 + l16] = f2bs(acc_o[et][j]);
  }
}

// ---------------- small helpers ----------------
__global__ void tsmax_kernel(const int* __restrict__ tsi, float* __restrict__ tmx){
  __shared__ int red[4];
  int b = blockIdx.x, tid = threadIdx.x;
  int m = max(tsi[b*SS+tid], tsi[b*SS+256+tid]);
  #pragma unroll
  for (int o=32;o;o>>=1) m = max(m, __shfl_down(m,o));
  if ((tid&63)==0) red[tid>>6]=m;
  __syncthreads();
  if (tid==0) tmx[b] = (float)max(max(red[0],red[1]),max(red[2],red[3]));
}

__global__ void pe_kernel(const int* __restrict__ tsi, unsigned short* __restrict__ peb){
  int idx = blockIdx.x*256 + threadIdx.x;
  int row = idx >> 9, j = idx & 511;
  float ts = (float)tsi[row];
  int jj = j & 255;
  float freq = expf(-9.210340371976184f*(float)jj*(1.f/256.f));
  float ang = ts*freq;
  peb[idx] = f2bs((j < 256) ? sinf(ang) : cosf(ang));
}

__global__ __launch_bounds__(256) void value_head_kernel(
    const unsigned short* __restrict__ x, const float* __restrict__ w,
    const float* __restrict__ bias, float* __restrict__ outp)
{
  const int tid = threadIdx.x, lane = tid & 63, wv = tid >> 6;
  const int r8 = lane >> 3, seg = lane & 7;
  const int row = blockIdx.x*32 + wv*8 + r8;
  const unsigned short* xr = x + (size_t)row*EE + seg*64;
  const float* wr = w + seg*64;
  float s = 0.f;
  #pragma unroll
  for (int i = 0; i < 8; ++i){
    short8 xv = *(const short8*)(xr + i*8);
    #pragma unroll
    for (int e = 0; e < 8; ++e)
      s += bs2f((unsigned short)xv[e]) * wr[i*8 + e];
  }
  s += __shfl_xor(s, 1); s += __shfl_xor(s, 2); s += __shfl_xor(s, 4);
  if (seg == 0) outp[row] = s + bias[0];
}

__global__ __launch_bounds__(256) void logits_head_kernel(
    const unsigned short* __restrict__ x, const float* __restrict__ w,
    const float* __restrict__ bias, float* __restrict__ outp)
{
  __shared__ unsigned short xsh[16*520];
  __shared__ unsigned short wsh[16*520];
  const int tid = threadIdx.x;
  const int row0 = blockIdx.x*16;
  {
    const int r = tid >> 4, kc = (tid & 15)*32;
    const unsigned short* xr = x + (size_t)(row0 + r)*EE + kc;
    #pragma unroll
    for (int i = 0; i < 4; ++i)
      *(short8*)&xsh[r*520 + kc + i*8] = *(const short8*)(xr + i*8);
    const int j = r;
    #pragma unroll
    for (int kk = 0; kk < 32; ++kk)
      wsh[j*520 + kc + kk] = f2bs(w[(size_t)(kc + kk)*16 + j]);
  }
  __syncthreads();
  const int r = tid >> 4, j = tid & 15;
  float s = 0.f;
  for (int k = 0; k < EE; k += 8){
    short8 xv = *(const short8*)&xsh[r*520 + k];
    short8 wv = *(const short8*)&wsh[j*520 + k];
    #pragma unroll
    for (int e = 0; e < 8; ++e)
      s += bs2f((unsigned short)xv[e]) * bs2f((unsigned short)wv[e]);
  }
  outp[(size_t)(row0 + r)*16 + j] = s + bias[j];
}

// ---------------- orchestration ----------------
extern "C" void kernel_launch(void* const* d_in, const int* in_sizes, int n_in,
                              void* d_out, int out_size, void* d_ws, size_t ws_size,
                              hipStream_t stream)
{
  const float* obs     = (const float*)d_in[0];
  const float* action  = (const float*)d_in[1];
  const float* enc_hs  = (const float*)d_in[2];
  const float* dec_hs1 = (const float*)d_in[3];
  const float* dec_hs2 = (const float*)d_in[4];
  const int*   stepc   = (const int*)d_in[5];
  const float* eoln = (const float*)d_in[6];
  const float* eow  = (const float*)d_in[7];
  const float* eln  = (const float*)d_in[8];
  const float* ewq  = (const float*)d_in[9];
  const float* ewk  = (const float*)d_in[10];
  const float* ewv  = (const float*)d_in[11];
  const float* ewo  = (const float*)d_in[12];
  const float* eln1 = (const float*)d_in[13];
  const float* eln2 = (const float*)d_in[14];
  const float* efg  = (const float*)d_in[15];
  const float* efp  = (const float*)d_in[16];
  const float* ehw1 = (const float*)d_in[17];
  const float* ehb1 = (const float*)d_in[18];
  const float* ehln = (const float*)d_in[19];
  const float* ehw2 = (const float*)d_in[20];
  const float* ehb2 = (const float*)d_in[21];
  const float* daw  = (const float*)d_in[22];
  const float* dln  = (const float*)d_in[23];
  const float* dwq1 = (const float*)d_in[24];
  const float* dwk1 = (const float*)d_in[25];
  const float* dwv1 = (const float*)d_in[26];
  const float* dwo1 = (const float*)d_in[27];
  const float* dwq2 = (const float*)d_in[28];
  const float* dwk2 = (const float*)d_in[29];
  const float* dwv2 = (const float*)d_in[30];
  const float* dwo2 = (const float*)d_in[31];
  const float* dln1 = (const float*)d_in[32];
  const float* dln2 = (const float*)d_in[33];
  const float* dln3 = (const float*)d_in[34];
  const float* dfg  = (const float*)d_in[35];
  const float* dfp  = (const float*)d_in[36];
  const float* dhw1 = (const float*)d_in[37];
  const float* dhb1 = (const float*)d_in[38];
  const float* dhln = (const float*)d_in[39];
  const float* dhw2 = (const float*)d_in[40];
  const float* dhb2 = (const float*)d_in[41];

  const size_t BUF = (size_t)MM*EE;
  // fp32 region
  float* wsf  = (float*)d_ws;
  float* f32a = wsf;              // obs_rep / wo-out / gelu heads ; also Wcum_lo+Wcum_hi (bf16)
  float* f32b = f32a + BUF;       // sw_b (bf16)
  float* tmx  = f32b + BUF;
  // retention / FFN scratch aliases
  unsigned short* wcum_lo = (unsigned short*)f32a;      // [B][H][8][4096] bf16
  unsigned short* wcum_hi = wcum_lo + BUF;              // [B][H][8][4096] bf16 (enc)
  unsigned short* sw_b    = (unsigned short*)f32b;      // silu(g)*p bf16
  // bf16 region
  unsigned short* ub = (unsigned short*)(tmx + 64);
  unsigned short* xrep_b    = ub;  ub += BUF;
  unsigned short* xrep_pe_b = ub;  ub += BUF;
  unsigned short* x_b       = ub;  ub += BUF;
  unsigned short* x_pe_b    = ub;  ub += BUF;
  unsigned short* t1_b      = ub;  ub += BUF;
  unsigned short* t1_pe_b   = ub;  ub += BUF;   // decoder-only; aliased as qhi_b (encoder-only)
  unsigned short* peb       = ub;  ub += BUF;
  unsigned short* qlo_b     = ub;  ub += BUF;
  unsigned short* klo_b     = ub;  ub += BUF;
  unsigned short* kloT_b    = ub;  ub += BUF;
  unsigned short* khi_b     = ub;  ub += BUF;
  unsigned short* khiT_b    = ub;  ub += BUF;
  unsigned short* vT_b      = ub;  ub += BUF;   // [B][H][64][512]
  unsigned short* obs_n     = ub;  ub += (size_t)MM*OBSD;
  unsigned short* act_b     = obs_n;            // aliased (obs_n dead by decoder embed)
  unsigned short* qhi_b     = t1_pe_b;          // alias
  // weights
  const size_t W55 = (size_t)EE*EE;
  unsigned short* wts = ub;  ub += 50*W55;
  unsigned short* wt_eow = ub; ub += (size_t)EE*OBSD;
  unsigned short* wt_daw = ub; ub += (size_t)EE*64;
  size_t need = (char*)ub - (char*)d_ws;
  if (ws_size < need) return;

  // fused-weight layout (z index into wts):
  // 0..8  : enc [q,k,v] x3 layers     9..11 : ewo
  // 12..14: efg   15..17: efp   18: ehw1
  // 19..27: dec1 [q,k,v] x3           28..30: dwo1
  // 31..36: dec2 [k,v] x3             37..39: dwq2
  // 40..42: dwo2  43..45: dfg  46..48: dfp   49: dhw1
  unsigned short* wt_eqkv  = wts + 0*W55;   // +3*i per layer
  unsigned short* wt_ewo   = wts + 9*W55;
  unsigned short* wt_efg   = wts + 12*W55;
  unsigned short* wt_efp   = wts + 15*W55;
  unsigned short* wt_ehw1  = wts + 18*W55;
  unsigned short* wt_dqkv1 = wts + 19*W55;  // +3*i
  unsigned short* wt_dwo1  = wts + 28*W55;
  unsigned short* wt_dkv2  = wts + 31*W55;  // +2*i
  unsigned short* wt_dwq2  = wts + 37*W55;
  unsigned short* wt_dwo2  = wts + 40*W55;
  unsigned short* wt_dfg   = wts + 43*W55;
  unsigned short* wt_dfp   = wts + 46*W55;
  unsigned short* wt_dhw1  = wts + 49*W55;

  float* out        = (float*)d_out;
  float* value_out  = out;
  float* logits_out = out + 8192;
  float* enc_out    = logits_out + (size_t)MM*16;
  float* d1_out     = enc_out + (size_t)BB*LL*HH*DH*DH;
  float* d2_out     = d1_out  + (size_t)BB*LL*HH*DH*DH;

  const size_t HS_L = (size_t)HH*DH*DH;

  {
    TP50 tp;
    int z = 0;
    auto add = [&](const float* p){ tp.s[z] = p; tp.d[z] = wts + (size_t)z*W55; ++z; };
    for (int i=0;i<3;++i){ add(ewq+i*W55); add(ewk+i*W55); add(ewv+i*W55); }
    for (int i=0;i<3;++i) add(ewo+i*W55);
    for (int i=0;i<3;++i) add(efg+i*W55);
    for (int i=0;i<3;++i) add(efp+i*W55);
    add(ehw1);
    for (int i=0;i<3;++i){ add(dwq1+i*W55); add(dwk1+i*W55); add(dwv1+i*W55); }
    for (int i=0;i<3;++i) add(dwo1+i*W55);
    for (int i=0;i<3;++i){ add(dwk2+i*W55); add(dwv2+i*W55); }
    for (int i=0;i<3;++i) add(dwq2+i*W55);
    for (int i=0;i<3;++i) add(dwo2+i*W55);
    for (int i=0;i<3;++i) add(dfg+i*W55);
    for (int i=0;i<3;++i) add(dfp+i*W55);
    add(dhw1);
    wtpose_batch_kernel<<<dim3(16,16,50), dim3(32,8), 0, stream>>>(tp);
  }
  wtpose_kernel<<<dim3(4,16), dim3(32,8), 0, stream>>>(eow, wt_eow, OBSD, OBSD);
  wtpose_kernel<<<dim3(2,16), dim3(32,8), 0, stream>>>(daw, wt_daw, ACTD, 64);

  pe_kernel<<<(MM*EE)/256, 256, 0, stream>>>(stepc, peb);
  tsmax_kernel<<<BB, 256, 0, stream>>>(stepc, tmx);

  auto gemmF = [&](const unsigned short* A, const unsigned short* Wt, const float* bias,
                   float* C, int Kpad, float scale, int act){
    gemm128_kernel<0,0><<<dim3(EE/128, MM/128), 256, 0, stream>>>(A, Wt, bias, C,
        Kpad, scale, act, 0, nullptr,
        nullptr, nullptr, nullptr, nullptr, nullptr, nullptr, nullptr);
  };
  auto gemmQKV = [&](const unsigned short* A, const unsigned short* Wt, int enc){
    if (enc)
      gemm128_kernel<1,1><<<dim3(12, MM/128), 256, 0, stream>>>(A, Wt, nullptr, nullptr,
          EE, 1.f, ACT_NONE, 0, stepc,
          qlo_b, qhi_b, klo_b, kloT_b, khi_b, khiT_b, vT_b);
    else
      gemm128_kernel<1,0><<<dim3(12, MM/128), 256, 0, stream>>>(A, Wt, nullptr, nullptr,
          EE, 1.f, ACT_NONE, 0, stepc,
          qlo_b, nullptr, klo_b, kloT_b, nullptr, nullptr, vT_b);
  };
  auto gemmKV = [&](const unsigned short* A, const unsigned short* Wt){
    gemm128_kernel<1,0><<<dim3(8, MM/128), 256, 0, stream>>>(A, Wt, nullptr, nullptr,
        EE, 1.f, ACT_NONE, 1, stepc,
        nullptr, nullptr, klo_b, kloT_b, nullptr, nullptr, vT_b);
  };
  auto gemmQ2 = [&](const unsigned short* A, const unsigned short* Wt){
    gemm128_kernel<1,0><<<dim3(4, MM/128), 256, 0, stream>>>(A, Wt, nullptr, nullptr,
        EE, 1.f, ACT_NONE, 0, stepc,
        qlo_b, nullptr, nullptr, nullptr, nullptr, nullptr, nullptr);
  };
  auto gemmSW = [&](const unsigned short* A, const unsigned short* Wg, const unsigned short* Wp){
    gemm_sw_kernel<<<dim3(EE/64, MM/128), 256, 0, stream>>>(A, Wg, Wp, sw_b);
  };
  auto norm = [&](const float* af, const unsigned short* ab, const float* res,
                  const unsigned short* resb, const float* w,
                  unsigned short* o1, unsigned short* o2, int mode){
    norm_b_kernel<<<MM/4, 256, 0, stream>>>(af, ab, res, resb, w, o1, o2, peb, mode);
  };
  auto retention = [&](const float* h0, float* hnew, unsigned short* o, int enc){
    wchunkscan_kernel<<<dim3(HH, BB), 256, 0, stream>>>(kloT_b, khiT_b, vT_b,
        h0, tmx, wcum_lo, enc ? wcum_hi : wcum_lo, hnew, enc);
    if (enc)
      retention2_kernel<1><<<dim3(8, HH, BB), 256, 0, stream>>>(
          qlo_b, qhi_b, klo_b, khi_b, vT_b, wcum_lo, wcum_hi, stepc, o);
    else
      retention2_kernel<0><<<dim3(8, HH, BB), 256, 0, stream>>>(
          qlo_b, nullptr, klo_b, nullptr, vT_b, wcum_lo, nullptr, stepc, o);
  };

  // ---- encoder embed ----
  norm_obs_kernel<<<MM/4, 256, 0, stream>>>(obs, eoln, obs_n);
  gemmF(obs_n, wt_eow, nullptr, f32a, OBSD, 1.f, ACT_GELU);   // f32a = obs_rep

  // ---- encoder layers ----
  for (int i = 0; i < LL; ++i){
    if (i == 0) norm(f32a, nullptr, nullptr, nullptr, eln, x_b, x_pe_b, NORM_PLAIN);
    else        norm(nullptr, xrep_b, nullptr, nullptr, eln, x_b, x_pe_b, NORM_PLAIN);
    gemmQKV(x_pe_b, wt_eqkv + (size_t)3*i*W55, 1);
    retention(enc_hs + i*HS_L, enc_out + i*HS_L, t1_b, 1);
    gemmF(t1_b, wt_ewo + i*W55, nullptr, f32a, EE, 1.f, ACT_NONE);
    norm(nullptr, x_b, f32a, nullptr, eln1 + i*EE, t1_b, nullptr, NORM_ADD);
    gemmSW(t1_b, wt_efg + i*W55, wt_efp + i*W55);
    norm(nullptr, t1_b, nullptr, sw_b, eln2 + i*EE, xrep_b, xrep_pe_b, NORM_ADD);
  }

  // ---- value head ----
  gemmF(xrep_b, wt_ehw1, ehb1, f32a, EE, 1.f, ACT_GELU);
  norm(f32a, nullptr, nullptr, nullptr, ehln, t1_b, nullptr, NORM_PLAIN);
  value_head_kernel<<<MM/32, 256, 0, stream>>>(t1_b, ehw2, ehb2, value_out);

  // ---- decoder embed ----
  act_embed_kernel<<<(MM*64)/256, 256, 0, stream>>>(action, act_b);
  gemmF(act_b, wt_daw, nullptr, f32a, 64, 1.f, ACT_GELU);
  norm(f32a, nullptr, nullptr, nullptr, dln, x_b, x_pe_b, NORM_PLAIN);

  // ---- decoder layers ----
  for (int i = 0; i < LL; ++i){
    gemmQKV(x_pe_b, wt_dqkv1 + (size_t)3*i*W55, 0);
    retention(dec_hs1 + i*HS_L, d1_out + i*HS_L, t1_b, 0);
    gemmF(t1_b, wt_dwo1 + i*W55, nullptr, f32a, EE, 1.f, ACT_NONE);
    norm(nullptr, x_b, f32a, nullptr, dln1 + i*EE, t1_b, t1_pe_b, NORM_ADD);   // r
    gemmQ2(xrep_pe_b, wt_dwq2 + i*W55);
    gemmKV(t1_pe_b, wt_dkv2 + (size_t)2*i*W55);
    retention(dec_hs2 + i*HS_L, d2_out + i*HS_L, t1_b, 0);
    gemmF(t1_b, wt_dwo2 + i*W55, nullptr, f32a, EE, 1.f, ACT_NONE);
    norm(nullptr, xrep_b, f32a, nullptr, dln2 + i*EE, x_b, nullptr, NORM_ADD); // y
    gemmSW(x_b, wt_dfg + i*W55, wt_dfp + i*W55);
    norm(nullptr, x_b, nullptr, sw_b, dln3 + i*EE, x_b, x_pe_b, NORM_ADD);
  }

  // ---- logits head ----
  gemmF(x_b, wt_dhw1, dhb1, f32a, EE, 1.f, ACT_GELU);
  norm(f32a, nullptr, nullptr, nullptr, dhln, t1_b, nullptr, NORM_PLAIN);
  logits_head_kernel<<<MM/16, 256, 0, stream>>>(t1_b, dhw2, dhb2, logits_out);
}

// Round 6
// 1169.253 us; speedup vs baseline: 1.5242x; 1.0667x over previous
//
#include <hip/hip_runtime.h>
#include <hip/hip_bf16.h>
#include <math.h>

typedef __attribute__((ext_vector_type(8))) short short8;     // 8 bf16 = 4 VGPRs
typedef __attribute__((ext_vector_type(4))) short short4v;    // 4 bf16 = 8B
typedef __attribute__((ext_vector_type(4))) float f32x4;

#define BB 16
#define SS 512
#define EE 512
#define HH 8
#define DH 64
#define LL 3
#define MM (BB*SS)
#define OBSD 128
#define ACTD 17
#define INV_SQRT_D 0.125f

#define ACT_NONE 0
#define ACT_GELU 1

#define NORM_PLAIN 0
#define NORM_ADD 1

__device__ __forceinline__ float gelu_f(float x){
  float x3 = x*x*x;
  return 0.5f*x*(1.f + tanhf(0.7978845608028654f*(x + 0.044715f*x3)));
}
__device__ __forceinline__ float silu_f(float x){ return x/(1.f+expf(-x)); }
__device__ __forceinline__ float lkappa(int h){ return logf(1.f - exp2f(-5.f - (float)h)); }
__device__ __forceinline__ unsigned short f2bs(float f){
  unsigned int u = __float_as_uint(f);
  u += 0x7FFFu + ((u >> 16) & 1u);
  return (unsigned short)(u >> 16);
}
__device__ __forceinline__ float bs2f(unsigned short u){
  return __uint_as_float(((unsigned int)u) << 16);
}

// async global->LDS, 16B per lane. LDS dest = wave-uniform base + lane*16 (linear).
typedef const __attribute__((address_space(1))) unsigned int* gas1_t;
typedef __attribute__((address_space(3))) unsigned int* las3_t;
__device__ __forceinline__ void gl16(const void* g, void* l){
  __builtin_amdgcn_global_load_lds((gas1_t)g, (las3_t)l, 16, 0, 0);
}

// raw pipeline sync: wait own async loads, block barrier, pin scheduler.
#define PIPE_SYNC do{ asm volatile("s_waitcnt vmcnt(0)" ::: "memory"); \
                      __builtin_amdgcn_s_barrier(); \
                      __builtin_amdgcn_sched_barrier(0); }while(0)

// ---------------- weight transpose: W[K][512] fp32 -> Wt[512][Kpad] bf16 ----------------
__global__ __launch_bounds__(256) void wtpose_kernel(
    const float* __restrict__ src, unsigned short* __restrict__ dst, int K, int Kpad)
{
  __shared__ float t[32][33];
  const int gx = blockIdx.x, gy = blockIdx.y;
  const int tx = threadIdx.x, ty = threadIdx.y;
  #pragma unroll
  for (int i = 0; i < 4; ++i){
    int k = gx*32 + ty + i*8, n = gy*32 + tx;
    t[ty+i*8][tx] = (k < K) ? src[(size_t)k*EE + n] : 0.f;
  }
  __syncthreads();
  #pragma unroll
  for (int i = 0; i < 4; ++i){
    int k = gx*32 + tx, n = gy*32 + ty + i*8;
    dst[(size_t)n*Kpad + k] = f2bs(t[tx][ty+i*8]);
  }
}

struct TP50 { const float* s[50]; unsigned short* d[50]; };
__global__ __launch_bounds__(256) void wtpose_batch_kernel(TP50 tp)
{
  __shared__ float t[32][33];
  const float* src = tp.s[blockIdx.z];
  unsigned short* dst = tp.d[blockIdx.z];
  const int gx = blockIdx.x, gy = blockIdx.y;
  const int tx = threadIdx.x, ty = threadIdx.y;
  #pragma unroll
  for (int i = 0; i < 4; ++i){
    int k = gx*32 + ty + i*8, n = gy*32 + tx;
    t[ty+i*8][tx] = src[(size_t)k*EE + n];
  }
  __syncthreads();
  #pragma unroll
  for (int i = 0; i < 4; ++i){
    int k = gx*32 + tx, n = gy*32 + ty + i*8;
    dst[(size_t)n*EE + k] = f2bs(t[tx][ty+i*8]);
  }
}

// ---------------- 128x128 MFMA GEMM (double-buffered global_load_lds, XOR-swizzled LDS) ----------------
// MODE 0: Cb = bf16( act(scale*(A@W) + bias) ).
// MODE 1: QKV raw epilogue. group = gstart + (bn>>9):
//   0: raw q row-major ; 1: k row-major (scale 1/8) ; 2: V -> vT [b][h][e][m]
template<int MODE>
__global__ __launch_bounds__(256) void gemm128_kernel(
    const unsigned short* __restrict__ A, const unsigned short* __restrict__ Wt,
    const float* __restrict__ bias, unsigned short* __restrict__ Cb,
    int Kpad, float scale, int act, int gstart,
    unsigned short* __restrict__ qout, unsigned short* __restrict__ kout,
    unsigned short* __restrict__ vT)
{
  __shared__ unsigned short As[2][128*64];
  __shared__ unsigned short Bs[2][128*64];
  const int bm = blockIdx.y*128, bn = blockIdx.x*128;
  const int tid = threadIdx.x, lane = tid & 63, wv = tid >> 6;
  const int wr = wv >> 1, wc = wv & 1;
  const int l16 = lane & 15, quad = lane >> 4;

  f32x4 acc[4][4];
  #pragma unroll
  for (int i=0;i<4;i++)
    #pragma unroll
    for (int j=0;j<4;j++) acc[i][j]=(f32x4)(0.f);

  // staging: lane covers physical granule; row = granule>>3, logical slot = (g&7)^(row&7)
  const int sg = lane >> 3;
  const int lg = (lane & 7) ^ sg;
  size_t aoff[4], boff[4];
  #pragma unroll
  for (int i=0;i<4;i++){
    aoff[i] = (size_t)(bm + wv*32 + i*8 + sg)*Kpad + lg*8;
    boff[i] = (size_t)(bn + wv*32 + i*8 + sg)*Kpad + lg*8;
  }
  const int swz = (l16 & 7) << 3;            // read-side XOR (elements)

  auto STAGE = [&](int buf, int t){
    const int k0 = t*64;
    #pragma unroll
    for (int i=0;i<4;i++){
      gl16(A + aoff[i] + k0, (char*)&As[buf][0] + ((wv*4+i) << 10));
      gl16(Wt + boff[i] + k0, (char*)&Bs[buf][0] + ((wv*4+i) << 10));
    }
  };
  auto COMPUTE = [&](int buf){
    short8 af[4][2], bf[4][2];
    #pragma unroll
    for (int mt=0; mt<4; ++mt)
      #pragma unroll
      for (int ks=0; ks<2; ++ks)
        af[mt][ks] = *(const short8*)&As[buf][(wr*64 + mt*16 + l16)*64 + ((ks*32 + quad*8) ^ swz)];
    #pragma unroll
    for (int nt=0; nt<4; ++nt)
      #pragma unroll
      for (int ks=0; ks<2; ++ks)
        bf[nt][ks] = *(const short8*)&Bs[buf][(wc*64 + nt*16 + l16)*64 + ((ks*32 + quad*8) ^ swz)];
    #pragma unroll
    for (int ks=0; ks<2; ++ks)
      #pragma unroll
      for (int mt=0; mt<4; ++mt)
        #pragma unroll
        for (int nt=0; nt<4; ++nt)
          acc[mt][nt] = __builtin_amdgcn_mfma_f32_16x16x32_bf16(af[mt][ks], bf[nt][ks], acc[mt][nt], 0, 0, 0);
  };

  const int NT = Kpad >> 6;
  STAGE(0, 0);
  PIPE_SYNC;
  int cur = 0;
  for (int t = 0; t < NT; ++t){
    if (t+1 < NT) STAGE(cur^1, t+1);
    COMPUTE(cur);
    if (t+1 < NT) PIPE_SYNC;
    cur ^= 1;
  }

  if (MODE == 0){
    #pragma unroll
    for (int mt=0; mt<4; ++mt){
      int rb = bm + wr*64 + mt*16 + quad*4;
      #pragma unroll
      for (int nt=0; nt<4; ++nt){
        int col = bn + wc*64 + nt*16 + l16;
        float bv = bias ? bias[col] : 0.f;
        #pragma unroll
        for (int j=0;j<4;j++){
          float v = acc[mt][nt][j]*scale + bv;
          if (act==ACT_GELU) v = gelu_f(v);
          Cb[(size_t)(rb+j)*EE + col] = f2bs(v);
        }
      }
    }
  } else {
    const int group = gstart + (bn >> 9);
    if (group <= 1){
      unsigned short* O = (group == 0) ? qout : kout;
      const float scl = (group == 1) ? INV_SQRT_D : 1.f;
      #pragma unroll
      for (int mt=0; mt<4; ++mt){
        int rb = bm + wr*64 + mt*16 + quad*4;
        #pragma unroll
        for (int nt=0; nt<4; ++nt){
          int ccol = (bn & 511) + wc*64 + nt*16 + l16;
          #pragma unroll
          for (int j=0;j<4;j++)
            O[(size_t)(rb+j)*EE + ccol] = f2bs(acc[mt][nt][j]*scl);
        }
      }
    } else {
      const int hh = ((bn & 511) >> 6) + wc;   // wave-uniform head
      #pragma unroll
      for (int mt=0; mt<4; ++mt){
        int rb = bm + wr*64 + mt*16 + quad*4;
        int bloc = rb >> 9, m0 = rb & 511;
        #pragma unroll
        for (int nt=0; nt<4; ++nt){
          int ee = nt*16 + l16;
          size_t taddr = (((size_t)bloc*HH + hh)*DH + ee)*SS + m0;
          short4v pk;
          #pragma unroll
          for (int j=0;j<4;j++) pk[j] = (short)f2bs(acc[mt][nt][j]);
          *(short4v*)&vT[taddr] = pk;
        }
      }
    }
  }
}

// ---------------- SwiGLU GEMM (128x64, dual weight): swo = silu(A@Wg)*(A@Wp) ----------------
__global__ __launch_bounds__(256) void gemm_sw_kernel(
    const unsigned short* __restrict__ A, const unsigned short* __restrict__ Wt,
    const unsigned short* __restrict__ Wt2, unsigned short* __restrict__ swo)
{
  __shared__ unsigned short As[2][128*64];
  __shared__ unsigned short Bs[2][64*64];
  __shared__ unsigned short Bs2[2][64*64];
  const int bm = blockIdx.y*128, bn = blockIdx.x*64;
  const int tid = threadIdx.x, lane = tid & 63, wv = tid >> 6;
  const int wr = wv >> 1, wc = wv & 1;
  const int l16 = lane & 15, quad = lane >> 4;

  f32x4 acc[4][2], acc2[4][2];
  #pragma unroll
  for (int i=0;i<4;i++){
    acc[i][0]=(f32x4)(0.f); acc[i][1]=(f32x4)(0.f);
    acc2[i][0]=(f32x4)(0.f); acc2[i][1]=(f32x4)(0.f);
  }

  const int sg = lane >> 3;
  const int lg = (lane & 7) ^ sg;
  size_t aoff[4], boff[2];
  #pragma unroll
  for (int i=0;i<4;i++)
    aoff[i] = (size_t)(bm + (wv*4+i)*8 + sg)*EE + lg*8;
  #pragma unroll
  for (int i=0;i<2;i++)
    boff[i] = (size_t)(bn + (wv*2+i)*8 + sg)*EE + lg*8;

  const int swz = (l16 & 7) << 3;

  auto STAGE = [&](int buf, int t){
    const int k0 = t*64;
    #pragma unroll
    for (int i=0;i<4;i++)
      gl16(A + aoff[i] + k0, (char*)&As[buf][0] + ((wv*4+i) << 10));
    #pragma unroll
    for (int i=0;i<2;i++){
      gl16(Wt + boff[i] + k0, (char*)&Bs[buf][0] + ((wv*2+i) << 10));
      gl16(Wt2 + boff[i] + k0, (char*)&Bs2[buf][0] + ((wv*2+i) << 10));
    }
  };
  auto COMPUTE = [&](int buf){
    short8 af[4][2], bf[2][2], bf2[2][2];
    #pragma unroll
    for (int mt=0; mt<4; ++mt)
      #pragma unroll
      for (int ks=0; ks<2; ++ks)
        af[mt][ks] = *(const short8*)&As[buf][(wr*64 + mt*16 + l16)*64 + ((ks*32 + quad*8) ^ swz)];
    #pragma unroll
    for (int nt=0; nt<2; ++nt)
      #pragma unroll
      for (int ks=0; ks<2; ++ks){
        bf[nt][ks]  = *(const short8*)&Bs[buf][(wc*32 + nt*16 + l16)*64 + ((ks*32 + quad*8) ^ swz)];
        bf2[nt][ks] = *(const short8*)&Bs2[buf][(wc*32 + nt*16 + l16)*64 + ((ks*32 + quad*8) ^ swz)];
      }
    #pragma unroll
    for (int ks=0; ks<2; ++ks)
      #pragma unroll
      for (int mt=0; mt<4; ++mt)
        #pragma unroll
        for (int nt=0; nt<2; ++nt){
          acc[mt][nt]  = __builtin_amdgcn_mfma_f32_16x16x32_bf16(af[mt][ks], bf[nt][ks],  acc[mt][nt],  0, 0, 0);
          acc2[mt][nt] = __builtin_amdgcn_mfma_f32_16x16x32_bf16(af[mt][ks], bf2[nt][ks], acc2[mt][nt], 0, 0, 0);
        }
  };

  STAGE(0, 0);
  PIPE_SYNC;
  int cur = 0;
  for (int t = 0; t < 8; ++t){
    if (t+1 < 8) STAGE(cur^1, t+1);
    COMPUTE(cur);
    if (t+1 < 8) PIPE_SYNC;
    cur ^= 1;
  }

  #pragma unroll
  for (int mt=0; mt<4; ++mt){
    int rb = bm + wr*64 + mt*16 + quad*4;
    #pragma unroll
    for (int nt=0; nt<2; ++nt){
      int col = bn + wc*32 + nt*16 + l16;
      #pragma unroll
      for (int j=0;j<4;j++)
        swo[(size_t)(rb+j)*EE + col] = f2bs(silu_f(acc[mt][nt][j])*acc2[mt][nt][j]);
    }
  }
}

// ---------------- rmsnorm: wave-per-row, no LDS / barriers ----------------
__global__ __launch_bounds__(256) void norm_b_kernel(
    const unsigned short* __restrict__ ab, const unsigned short* __restrict__ resb,
    const float* __restrict__ w, unsigned short* __restrict__ o1,
    unsigned short* __restrict__ o2, const unsigned short* __restrict__ peb,
    int mode)
{
  const int row = blockIdx.x*4 + (threadIdx.x >> 6);
  const int lane = threadIdx.x & 63;
  const size_t base = (size_t)row*EE + lane*8;
  float t[8];
  {
    short8 av = *(const short8*)&ab[base];
    #pragma unroll
    for (int e=0;e<8;++e) t[e] = bs2f((unsigned short)av[e]);
  }
  if (mode == NORM_ADD){
    short8 rv = *(const short8*)&resb[base];
    #pragma unroll
    for (int e=0;e<8;++e) t[e] += bs2f((unsigned short)rv[e]);
  }
  float ss = 0.f;
  #pragma unroll
  for (int e=0;e<8;++e) ss += t[e]*t[e];
  #pragma unroll
  for (int o=32;o;o>>=1) ss += __shfl_xor(ss, o);
  float r = 1.f/sqrtf(ss/(float)EE + 1e-6f);
  float4 w0 = *(const float4*)&w[lane*8];
  float4 w1 = *(const float4*)&w[lane*8+4];
  float y[8];
  y[0]=t[0]*r*w0.x; y[1]=t[1]*r*w0.y; y[2]=t[2]*r*w0.z; y[3]=t[3]*r*w0.w;
  y[4]=t[4]*r*w1.x; y[5]=t[5]*r*w1.y; y[6]=t[6]*r*w1.z; y[7]=t[7]*r*w1.w;
  short8 pk;
  #pragma unroll
  for (int e=0;e<8;++e) pk[e] = (short)f2bs(y[e]);
  *(short8*)&o1[base] = pk;
  if (o2){
    short8 pv = *(const short8*)&peb[base];
    short8 pz;
    #pragma unroll
    for (int e=0;e<8;++e) pz[e] = (short)f2bs(y[e] + bs2f((unsigned short)pv[e]));
    *(short8*)&o2[base] = pz;
  }
}

// obs norm: wave-per-row, fp32 [MM][128] -> bf16
__global__ __launch_bounds__(256) void norm_obs_kernel(
    const float* __restrict__ a, const float* __restrict__ w, unsigned short* __restrict__ o)
{
  const int row = blockIdx.x*4 + (threadIdx.x >> 6);
  const int lane = threadIdx.x & 63;
  const size_t base = (size_t)row*OBSD + lane*2;
  float2 av = *(const float2*)&a[base];
  float ss = av.x*av.x + av.y*av.y;
  #pragma unroll
  for (int off=32;off;off>>=1) ss += __shfl_xor(ss, off);
  float r = 1.f/sqrtf(ss/(float)OBSD + 1e-6f);
  float2 wv2 = *(const float2*)&w[lane*2];
  unsigned int pk = (unsigned int)f2bs(av.x*r*wv2.x) | ((unsigned int)f2bs(av.y*r*wv2.y) << 16);
  *(unsigned int*)&o[base] = pk;
}

// action embed: fp32 [MM][17] -> bf16 [MM][64] zero-padded
__global__ __launch_bounds__(256) void act_embed_kernel(
    const float* __restrict__ a, unsigned short* __restrict__ o)
{
  int idx = blockIdx.x*256 + threadIdx.x;
  int row = idx >> 6, col = idx & 63;
  o[idx] = (col < ACTD) ? f2bs(a[(size_t)row*ACTD + col]) : 0;
}

// ---------------- fused chunk-state + scan (raw k, scales applied in staging) ----------------
__global__ __launch_bounds__(256) void wchunkscan_kernel(
    const unsigned short* __restrict__ k, const unsigned short* __restrict__ vT,
    const float* __restrict__ h0, const float* __restrict__ tmx,
    const int* __restrict__ tsi,
    unsigned short* __restrict__ wcum_lo, unsigned short* __restrict__ wcum_hi,
    float* __restrict__ hnew, int enc)
{
  __shared__ unsigned short vsh[64*72];
  __shared__ unsigned short ksh[64*72];
  const int h = blockIdx.x, b = blockIdx.y;
  const int tid = threadIdx.x, lane = tid & 63, wv = tid >> 6;
  const int quad = lane >> 4, l16 = lane & 15;
  const float lk = lkappa(h);
  const float elk = __expf(lk);
  const float etm = __expf(lk*tmx[b]);
  const size_t wbase = ((size_t)b*HH + h)*8*4096;
  const size_t hbase = (size_t)b*(LL*HH*DH*DH) + (size_t)h*(DH*DH);
  const int e0r = wv*16 + quad*4;           // e base; +j
  const int sr = tid >> 2, sseg = (tid & 3)*16;

  f32x4 cum[4];
  #pragma unroll
  for (int dt=0; dt<4; ++dt)
    #pragma unroll
    for (int j=0;j<4;j++)
      cum[dt][j] = elk * h0[hbase + (size_t)(dt*16+l16)*64 + e0r + j];

  for (int c = 0; c < 8; ++c){
    __syncthreads();
    {
      const unsigned short* vrow = vT + (((size_t)b*HH + h)*DH + sr)*SS + c*64 + sseg;
      #pragma unroll
      for (int i = 0; i < 2; ++i)
        *(short8*)&vsh[sr*72 + sseg + i*8] = *(const short8*)(vrow + i*8);
      // transpose-stage k row (m = sr) into ksh[d][m], scaled by e^{-lk*ts[m]}
      float els = __expf(-lk * (float)tsi[b*SS + c*64 + sr]);
      const unsigned short* krow = k + ((size_t)b*SS + c*64 + sr)*EE + h*DH + sseg;
      #pragma unroll
      for (int i = 0; i < 2; ++i){
        short8 kv = *(const short8*)(krow + i*8);
        #pragma unroll
        for (int e = 0; e < 8; ++e)
          ksh[(sseg + i*8 + e)*72 + sr] = f2bs(bs2f((unsigned short)kv[e])*els);
      }
    }
    __syncthreads();
    short8 av[2];
    #pragma unroll
    for (int ks=0; ks<2; ++ks)
      av[ks] = *(const short8*)&vsh[(wv*16 + l16)*72 + ks*32 + quad*8];
    f32x4 acc[4];
    #pragma unroll
    for (int dt=0; dt<4; ++dt) acc[dt] = (f32x4)(0.f);
    #pragma unroll
    for (int ks=0; ks<2; ++ks)
      #pragma unroll
      for (int dt=0; dt<4; ++dt){
        short8 kb = *(const short8*)&ksh[(dt*16 + l16)*72 + ks*32 + quad*8];
        acc[dt] = __builtin_amdgcn_mfma_f32_16x16x32_bf16(av[ks], kb, acc[dt], 0, 0, 0);
      }
    #pragma unroll
    for (int dt=0; dt<4; ++dt)
      #pragma unroll
      for (int j=0;j<4;j++){
        wcum_lo[wbase + (size_t)c*4096 + (size_t)(e0r+j)*64 + dt*16 + l16] = f2bs(cum[dt][j]);
        cum[dt][j] += acc[dt][j];
      }
  }
  #pragma unroll
  for (int dt=0; dt<4; ++dt)
    #pragma unroll
    for (int j=0;j<4;j++)
      hnew[hbase + (size_t)(dt*16+l16)*64 + e0r + j] = etm * cum[dt][j];

  if (enc){
    f32x4 suf[4];
    #pragma unroll
    for (int dt=0; dt<4; ++dt) suf[dt] = (f32x4)(0.f);
    for (int c = 7; c >= 0; --c){
      __syncthreads();
      {
        const unsigned short* vrow = vT + (((size_t)b*HH + h)*DH + sr)*SS + c*64 + sseg;
        #pragma unroll
        for (int i = 0; i < 2; ++i)
          *(short8*)&vsh[sr*72 + sseg + i*8] = *(const short8*)(vrow + i*8);
        float ehs = __expf(lk * (float)tsi[b*SS + c*64 + sr]);
        const unsigned short* krow = k + ((size_t)b*SS + c*64 + sr)*EE + h*DH + sseg;
        #pragma unroll
        for (int i = 0; i < 2; ++i){
          short8 kv = *(const short8*)(krow + i*8);
          #pragma unroll
          for (int e = 0; e < 8; ++e)
            ksh[(sseg + i*8 + e)*72 + sr] = f2bs(bs2f((unsigned short)kv[e])*ehs);
        }
      }
      __syncthreads();
      short8 av[2];
      #pragma unroll
      for (int ks=0; ks<2; ++ks)
        av[ks] = *(const short8*)&vsh[(wv*16 + l16)*72 + ks*32 + quad*8];
      f32x4 acc[4];
      #pragma unroll
      for (int dt=0; dt<4; ++dt) acc[dt] = (f32x4)(0.f);
      #pragma unroll
      for (int ks=0; ks<2; ++ks)
        #pragma unroll
        for (int dt=0; dt<4; ++dt){
          short8 kb = *(const short8*)&ksh[(dt*16 + l16)*72 + ks*32 + quad*8];
          acc[dt] = __builtin_amdgcn_mfma_f32_16x16x32_bf16(av[ks], kb, acc[dt], 0, 0, 0);
        }
      #pragma unroll
      for (int dt=0; dt<4; ++dt)
        #pragma unroll
        for (int j=0;j<4;j++){
          wcum_hi[wbase + (size_t)c*4096 + (size_t)(e0r+j)*64 + dt*16 + l16] = f2bs(suf[dt][j]);
          suf[dt][j] += acc[dt][j];
        }
    }
  }
}

// ---------------- retention (chunked-recurrent, raw q/k with staged scaling) ----------------
template<int ENC>
__global__ __launch_bounds__(256) void retention2_kernel(
    const unsigned short* __restrict__ q, const unsigned short* __restrict__ k,
    const unsigned short* __restrict__ vT,
    const unsigned short* __restrict__ wlo, const unsigned short* __restrict__ whi,
    const int* __restrict__ tsi, unsigned short* __restrict__ outp)
{
  __shared__ unsigned short qsh[64*72];        // reused as psh in boundary
  __shared__ unsigned short wsh[64*72];
  __shared__ unsigned short ksh[64*72];
  __shared__ unsigned short vsh[64*72];
  __shared__ unsigned short qsh2[ENC ? 64*72 : 2];  // reused as ksh2 in boundary
  __shared__ unsigned short wsh2[ENC ? 64*72 : 2];
  __shared__ float tsf[SS];
  const int b = blockIdx.z, h = blockIdx.y, t = blockIdx.x;
  const int n0 = t*64;
  const int tid = threadIdx.x, lane = tid & 63, wv = tid >> 6;
  const int quad = lane >> 4, l16 = lane & 15;
  const float lk = lkappa(h);

  for (int i = tid; i < SS; i += 256) tsf[i] = (float)tsi[b*SS + i];
  {
    const int n = tid >> 2, seg = (tid & 3)*16;
    float ts_n = (float)tsi[b*SS + n0 + n];
    float e0 = __expf(lk*ts_n);
    float e1 = ENC ? __expf(-lk*ts_n) : 0.f;
    const unsigned short* qr = q + ((size_t)b*SS + n0 + n)*EE + h*DH + seg;
    #pragma unroll
    for (int i = 0; i < 2; ++i){
      short8 v = *(const short8*)(qr + i*8);
      short8 o, o2;
      #pragma unroll
      for (int e=0;e<8;++e){
        float f = bs2f((unsigned short)v[e]);
        o[e] = (short)f2bs(f*e0);
        if (ENC) o2[e] = (short)f2bs(f*e1);
      }
      *(short8*)&qsh[n*72 + seg + i*8] = o;
      if (ENC) *(short8*)&qsh2[n*72 + seg + i*8] = o2;
    }
    const unsigned short* wr = wlo + (((size_t)b*HH + h)*8 + t)*4096 + (size_t)n*64 + seg;
    #pragma unroll
    for (int i = 0; i < 2; ++i)
      *(short8*)&wsh[n*72 + seg + i*8] = *(const short8*)(wr + i*8);
    if (ENC){
      const unsigned short* wr2 = whi + (((size_t)b*HH + h)*8 + t)*4096 + (size_t)n*64 + seg;
      #pragma unroll
      for (int i = 0; i < 2; ++i)
        *(short8*)&wsh2[n*72 + seg + i*8] = *(const short8*)(wr2 + i*8);
    }
  }
  __syncthreads();

  const int rowbase = wv*16;
  short8 qa[2], qa2[2];
  #pragma unroll
  for (int ks=0; ks<2; ++ks)
    qa[ks] = *(const short8*)&qsh[(rowbase + l16)*72 + ks*32 + quad*8];
  if (ENC){
    #pragma unroll
    for (int ks=0; ks<2; ++ks)
      qa2[ks] = *(const short8*)&qsh2[(rowbase + l16)*72 + ks*32 + quad*8];
  }

  float tn = tsf[n0 + lane];
  float maxn = tn, minn = tn;
  #pragma unroll
  for (int o=32;o;o>>=1){
    maxn = fmaxf(maxn, __shfl_xor(maxn, o));
    minn = fminf(minn, __shfl_xor(minn, o));
  }

  // cross-chunk + h0 contribution
  f32x4 acc_o[4];
  #pragma unroll
  for (int et=0; et<4; ++et){
    f32x4 a = (f32x4)(0.f);
    #pragma unroll
    for (int ks=0; ks<2; ++ks){
      short8 wb = *(const short8*)&wsh[(et*16 + l16)*72 + ks*32 + quad*8];
      a = __builtin_amdgcn_mfma_f32_16x16x32_bf16(qa[ks], wb, a, 0, 0, 0);
    }
    if (ENC){
      #pragma unroll
      for (int ks=0; ks<2; ++ks){
        short8 wb2 = *(const short8*)&wsh2[(et*16 + l16)*72 + ks*32 + quad*8];
        a = __builtin_amdgcn_mfma_f32_16x16x32_bf16(qa2[ks], wb2, a, 0, 0, 0);
      }
    }
    acc_o[et] = a;
  }

  // boundary chunk(s)
  for (int c = 0; c < 8; ++c){
    const int mc = c*64;
    float tmv = tsf[mc + lane];
    float maxm = tmv, minm = tmv;
    #pragma unroll
    for (int o=32;o;o>>=1){
      maxm = fmaxf(maxm, __shfl_xor(maxm, o));
      minm = fminf(minm, __shfl_xor(minm, o));
    }
    if (ENC){
      if (maxm <= minn) continue;
      if (minm >= maxn) continue;
    } else {
      if ((maxm < minn) || (maxm == minn && (mc + 63) < n0)) continue;
      if (minm > maxn) continue;
    }
    __syncthreads();
    {
      const int m = tid >> 2, cb = (tid & 3)*16;
      float ts_m = tsf[mc + m];
      float ek0 = __expf(-lk*ts_m);
      float ek1 = ENC ? __expf(lk*ts_m) : 0.f;
      const unsigned short* krow = k + ((size_t)b*SS + mc + m)*EE + h*DH + cb;
      #pragma unroll
      for (int i = 0; i < 2; ++i){
        short8 kv = *(const short8*)(krow + i*8);
        short8 o, o2;
        #pragma unroll
        for (int e=0;e<8;++e){
          float f = bs2f((unsigned short)kv[e]);
          o[e] = (short)f2bs(f*ek0);
          if (ENC) o2[e] = (short)f2bs(f*ek1);
        }
        *(short8*)&ksh[m*72 + cb + i*8] = o;
        if (ENC) *(short8*)&qsh2[m*72 + cb + i*8] = o2;
      }
      const unsigned short* vrow = vT + (((size_t)b*HH + h)*DH + m)*SS + mc + cb;
      #pragma unroll
      for (int i = 0; i < 2; ++i)
        *(short8*)&vsh[m*72 + cb + i*8] = *(const short8*)(vrow + i*8);
    }
    __syncthreads();
    f32x4 sacc[4], sacc2[4];
    #pragma unroll
    for (int mt=0; mt<4; ++mt){
      f32x4 a = (f32x4)(0.f);
      #pragma unroll
      for (int ks=0; ks<2; ++ks){
        short8 kb = *(const short8*)&ksh[(mt*16 + l16)*72 + ks*32 + quad*8];
        a = __builtin_amdgcn_mfma_f32_16x16x32_bf16(qa[ks], kb, a, 0, 0, 0);
      }
      sacc[mt] = a;
      if (ENC){
        f32x4 a2 = (f32x4)(0.f);
        #pragma unroll
        for (int ks=0; ks<2; ++ks){
          short8 kb2 = *(const short8*)&qsh2[(mt*16 + l16)*72 + ks*32 + quad*8];
          a2 = __builtin_amdgcn_mfma_f32_16x16x32_bf16(qa2[ks], kb2, a2, 0, 0, 0);
        }
        sacc2[mt] = a2;
      }
    }
    float tsm[4]; int mg[4];
    #pragma unroll
    for (int mt=0; mt<4; ++mt){ mg[mt] = mc + mt*16 + l16; tsm[mt] = tsf[mg[mt]]; }
    #pragma unroll
    for (int j=0;j<4;j++){
      int nloc = rowbase + quad*4 + j;
      int n = n0 + nloc;
      float tsn = tsf[n];
      #pragma unroll
      for (int mt=0; mt<4; ++mt){
        float diff = tsn - tsm[mt];
        float p;
        if (ENC) p = (diff >= 0.f) ? sacc[mt][j] : sacc2[mt][j];
        else     p = ((diff > 0.f) || (diff == 0.f && n >= mg[mt])) ? sacc[mt][j] : 0.f;
        qsh[nloc*72 + mt*16 + l16] = f2bs(p);   // qsh reused as psh
      }
    }
    #pragma unroll
    for (int ks=0; ks<2; ++ks){
      short8 pa = *(const short8*)&qsh[(rowbase + l16)*72 + ks*32 + quad*8];
      #pragma unroll
      for (int et=0; et<4; ++et){
        short8 vb = *(const short8*)&vsh[(et*16 + l16)*72 + ks*32 + quad*8];
        acc_o[et] = __builtin_amdgcn_mfma_f32_16x16x32_bf16(pa, vb, acc_o[et], 0, 0, 0);
      }
    }
  }
  #pragma unroll
  for (int j=0;j<4;j++){
    size_t rbase = ((size_t)b*SS + n0 + rowbase + quad*4 + j)*EE + h*DH;
    #pragma unroll
    for (int et=0; et<4; ++et)
      outp[rbase + et*16 + l16] = f2bs(acc_o[et][j]);
  }
}

// ---------------- small helpers ----------------
__global__ void tsmax_kernel(const int* __restrict__ tsi, float* __restrict__ tmx){
  __shared__ int red[4];
  int b = blockIdx.x, tid = threadIdx.x;
  int m = max(tsi[b*SS+tid], tsi[b*SS+256+tid]);
  #pragma unroll
  for (int o=32;o;o>>=1) m = max(m, __shfl_down(m,o));
  if ((tid&63)==0) red[tid>>6]=m;
  __syncthreads();
  if (tid==0) tmx[b] = (float)max(max(red[0],red[1]),max(red[2],red[3]));
}

__global__ void pe_kernel(const int* __restrict__ tsi, unsigned short* __restrict__ peb){
  int idx = blockIdx.x*256 + threadIdx.x;
  int row = idx >> 9, j = idx & 511;
  float ts = (float)tsi[row];
  int jj = j & 255;
  float freq = expf(-9.210340371976184f*(float)jj*(1.f/256.f));
  float ang = ts*freq;
  peb[idx] = f2bs((j < 256) ? sinf(ang) : cosf(ang));
}

__global__ __launch_bounds__(256) void value_head_kernel(
    const unsigned short* __restrict__ x, const float* __restrict__ w,
    const float* __restrict__ bias, float* __restrict__ outp)
{
  const int tid = threadIdx.x, lane = tid & 63, wv = tid >> 6;
  const int r8 = lane >> 3, seg = lane & 7;
  const int row = blockIdx.x*32 + wv*8 + r8;
  const unsigned short* xr = x + (size_t)row*EE + seg*64;
  const float* wr = w + seg*64;
  float s = 0.f;
  #pragma unroll
  for (int i = 0; i < 8; ++i){
    short8 xv = *(const short8*)(xr + i*8);
    #pragma unroll
    for (int e = 0; e < 8; ++e)
      s += bs2f((unsigned short)xv[e]) * wr[i*8 + e];
  }
  s += __shfl_xor(s, 1); s += __shfl_xor(s, 2); s += __shfl_xor(s, 4);
  if (seg == 0) outp[row] = s + bias[0];
}

__global__ __launch_bounds__(256) void logits_head_kernel(
    const unsigned short* __restrict__ x, const float* __restrict__ w,
    const float* __restrict__ bias, float* __restrict__ outp)
{
  __shared__ unsigned short xsh[16*520];
  __shared__ unsigned short wsh[16*520];
  const int tid = threadIdx.x;
  const int row0 = blockIdx.x*16;
  {
    const int r = tid >> 4, kc = (tid & 15)*32;
    const unsigned short* xr = x + (size_t)(row0 + r)*EE + kc;
    #pragma unroll
    for (int i = 0; i < 4; ++i)
      *(short8*)&xsh[r*520 + kc + i*8] = *(const short8*)(xr + i*8);
    const int j = r;
    #pragma unroll
    for (int kk = 0; kk < 32; ++kk)
      wsh[j*520 + kc + kk] = f2bs(w[(size_t)(kc + kk)*16 + j]);
  }
  __syncthreads();
  const int r = tid >> 4, j = tid & 15;
  float s = 0.f;
  for (int k = 0; k < EE; k += 8){
    short8 xv = *(const short8*)&xsh[r*520 + k];
    short8 wv = *(const short8*)&wsh[j*520 + k];
    #pragma unroll
    for (int e = 0; e < 8; ++e)
      s += bs2f((unsigned short)xv[e]) * bs2f((unsigned short)wv[e]);
  }
  outp[(size_t)(row0 + r)*16 + j] = s + bias[j];
}

// ---------------- orchestration ----------------
extern "C" void kernel_launch(void* const* d_in, const int* in_sizes, int n_in,
                              void* d_out, int out_size, void* d_ws, size_t ws_size,
                              hipStream_t stream)
{
  const float* obs     = (const float*)d_in[0];
  const float* action  = (const float*)d_in[1];
  const float* enc_hs  = (const float*)d_in[2];
  const float* dec_hs1 = (const float*)d_in[3];
  const float* dec_hs2 = (const float*)d_in[4];
  const int*   stepc   = (const int*)d_in[5];
  const float* eoln = (const float*)d_in[6];
  const float* eow  = (const float*)d_in[7];
  const float* eln  = (const float*)d_in[8];
  const float* ewq  = (const float*)d_in[9];
  const float* ewk  = (const float*)d_in[10];
  const float* ewv  = (const float*)d_in[11];
  const float* ewo  = (const float*)d_in[12];
  const float* eln1 = (const float*)d_in[13];
  const float* eln2 = (const float*)d_in[14];
  const float* efg  = (const float*)d_in[15];
  const float* efp  = (const float*)d_in[16];
  const float* ehw1 = (const float*)d_in[17];
  const float* ehb1 = (const float*)d_in[18];
  const float* ehln = (const float*)d_in[19];
  const float* ehw2 = (const float*)d_in[20];
  const float* ehb2 = (const float*)d_in[21];
  const float* daw  = (const float*)d_in[22];
  const float* dln  = (const float*)d_in[23];
  const float* dwq1 = (const float*)d_in[24];
  const float* dwk1 = (const float*)d_in[25];
  const float* dwv1 = (const float*)d_in[26];
  const float* dwo1 = (const float*)d_in[27];
  const float* dwq2 = (const float*)d_in[28];
  const float* dwk2 = (const float*)d_in[29];
  const float* dwv2 = (const float*)d_in[30];
  const float* dwo2 = (const float*)d_in[31];
  const float* dln1 = (const float*)d_in[32];
  const float* dln2 = (const float*)d_in[33];
  const float* dln3 = (const float*)d_in[34];
  const float* dfg  = (const float*)d_in[35];
  const float* dfp  = (const float*)d_in[36];
  const float* dhw1 = (const float*)d_in[37];
  const float* dhb1 = (const float*)d_in[38];
  const float* dhln = (const float*)d_in[39];
  const float* dhw2 = (const float*)d_in[40];
  const float* dhb2 = (const float*)d_in[41];

  const size_t BUF = (size_t)MM*EE;
  // region A: wcum_lo + wcum_hi (bf16) ; gf_b (bf16 gemmF out) aliases wcum_lo (disjoint lifetimes)
  float* wsf  = (float*)d_ws;
  float* f32a = wsf;
  float* f32b = f32a + BUF;
  float* tmx  = f32b + BUF;
  unsigned short* wcum_lo = (unsigned short*)f32a;      // [B][H][8][4096] bf16
  unsigned short* wcum_hi = wcum_lo + BUF;              // [B][H][8][4096] bf16 (enc)
  unsigned short* gf_b    = wcum_lo;                    // alias: gemmF bf16 out
  unsigned short* sw_b    = (unsigned short*)f32b;      // silu(g)*p bf16
  // bf16 region
  unsigned short* ub = (unsigned short*)(tmx + 64);
  unsigned short* xrep_b    = ub;  ub += BUF;
  unsigned short* xrep_pe_b = ub;  ub += BUF;
  unsigned short* x_b       = ub;  ub += BUF;
  unsigned short* x_pe_b    = ub;  ub += BUF;
  unsigned short* t1_b      = ub;  ub += BUF;
  unsigned short* t1_pe_b   = ub;  ub += BUF;   // decoder r+pe
  unsigned short* peb       = ub;  ub += BUF;
  unsigned short* q_b       = ub;  ub += BUF;   // raw q
  unsigned short* k_b       = ub;  ub += BUF;   // raw k * 1/sqrt(D)
  unsigned short* vT_b      = ub;  ub += BUF;   // [B][H][64][512]
  unsigned short* obs_n     = ub;  ub += (size_t)MM*OBSD;
  unsigned short* act_b     = obs_n;            // aliased (obs_n dead by decoder embed)
  // weights
  const size_t W55 = (size_t)EE*EE;
  unsigned short* wts = ub;  ub += 50*W55;
  unsigned short* wt_eow = ub; ub += (size_t)EE*OBSD;
  unsigned short* wt_daw = ub; ub += (size_t)EE*64;
  size_t need = (char*)ub - (char*)d_ws;
  if (ws_size < need) return;

  // fused-weight layout (z index into wts):
  // 0..8  : enc [q,k,v] x3 layers     9..11 : ewo
  // 12..14: efg   15..17: efp   18: ehw1
  // 19..27: dec1 [q,k,v] x3           28..30: dwo1
  // 31..36: dec2 [k,v] x3             37..39: dwq2
  // 40..42: dwo2  43..45: dfg  46..48: dfp   49: dhw1
  unsigned short* wt_eqkv  = wts + 0*W55;   // +3*i per layer
  unsigned short* wt_ewo   = wts + 9*W55;
  unsigned short* wt_efg   = wts + 12*W55;
  unsigned short* wt_efp   = wts + 15*W55;
  unsigned short* wt_ehw1  = wts + 18*W55;
  unsigned short* wt_dqkv1 = wts + 19*W55;  // +3*i
  unsigned short* wt_dwo1  = wts + 28*W55;
  unsigned short* wt_dkv2  = wts + 31*W55;  // +2*i
  unsigned short* wt_dwq2  = wts + 37*W55;
  unsigned short* wt_dwo2  = wts + 40*W55;
  unsigned short* wt_dfg   = wts + 43*W55;
  unsigned short* wt_dfp   = wts + 46*W55;
  unsigned short* wt_dhw1  = wts + 49*W55;

  float* out        = (float*)d_out;
  float* value_out  = out;
  float* logits_out = out + 8192;
  float* enc_out    = logits_out + (size_t)MM*16;
  float* d1_out     = enc_out + (size_t)BB*LL*HH*DH*DH;
  float* d2_out     = d1_out  + (size_t)BB*LL*HH*DH*DH;

  const size_t HS_L = (size_t)HH*DH*DH;

  {
    TP50 tp;
    int z = 0;
    auto add = [&](const float* p){ tp.s[z] = p; tp.d[z] = wts + (size_t)z*W55; ++z; };
    for (int i=0;i<3;++i){ add(ewq+i*W55); add(ewk+i*W55); add(ewv+i*W55); }
    for (int i=0;i<3;++i) add(ewo+i*W55);
    for (int i=0;i<3;++i) add(efg+i*W55);
    for (int i=0;i<3;++i) add(efp+i*W55);
    add(ehw1);
    for (int i=0;i<3;++i){ add(dwq1+i*W55); add(dwk1+i*W55); add(dwv1+i*W55); }
    for (int i=0;i<3;++i) add(dwo1+i*W55);
    for (int i=0;i<3;++i){ add(dwk2+i*W55); add(dwv2+i*W55); }
    for (int i=0;i<3;++i) add(dwq2+i*W55);
    for (int i=0;i<3;++i) add(dwo2+i*W55);
    for (int i=0;i<3;++i) add(dfg+i*W55);
    for (int i=0;i<3;++i) add(dfp+i*W55);
    add(dhw1);
    wtpose_batch_kernel<<<dim3(16,16,50), dim3(32,8), 0, stream>>>(tp);
  }
  wtpose_kernel<<<dim3(4,16), dim3(32,8), 0, stream>>>(eow, wt_eow, OBSD, OBSD);
  wtpose_kernel<<<dim3(2,16), dim3(32,8), 0, stream>>>(daw, wt_daw, ACTD, 64);

  pe_kernel<<<(MM*EE)/256, 256, 0, stream>>>(stepc, peb);
  tsmax_kernel<<<BB, 256, 0, stream>>>(stepc, tmx);

  auto gemmF = [&](const unsigned short* A, const unsigned short* Wt, const float* bias,
                   unsigned short* Cb, int Kpad, float scale, int act){
    gemm128_kernel<0><<<dim3(EE/128, MM/128), 256, 0, stream>>>(A, Wt, bias, Cb,
        Kpad, scale, act, 0, nullptr, nullptr, nullptr);
  };
  auto gemmQKV = [&](const unsigned short* A, const unsigned short* Wt){
    gemm128_kernel<1><<<dim3(12, MM/128), 256, 0, stream>>>(A, Wt, nullptr, nullptr,
        EE, 1.f, ACT_NONE, 0, q_b, k_b, vT_b);
  };
  auto gemmKV = [&](const unsigned short* A, const unsigned short* Wt){
    gemm128_kernel<1><<<dim3(8, MM/128), 256, 0, stream>>>(A, Wt, nullptr, nullptr,
        EE, 1.f, ACT_NONE, 1, nullptr, k_b, vT_b);
  };
  auto gemmQ2 = [&](const unsigned short* A, const unsigned short* Wt){
    gemm128_kernel<1><<<dim3(4, MM/128), 256, 0, stream>>>(A, Wt, nullptr, nullptr,
        EE, 1.f, ACT_NONE, 0, q_b, nullptr, nullptr);
  };
  auto gemmSW = [&](const unsigned short* A, const unsigned short* Wg, const unsigned short* Wp){
    gemm_sw_kernel<<<dim3(EE/64, MM/128), 256, 0, stream>>>(A, Wg, Wp, sw_b);
  };
  auto norm = [&](const unsigned short* ab, const unsigned short* resb, const float* w,
                  unsigned short* o1, unsigned short* o2, int mode){
    norm_b_kernel<<<MM/4, 256, 0, stream>>>(ab, resb, w, o1, o2, peb, mode);
  };
  auto retention = [&](const float* h0, float* hnew, unsigned short* o, int enc){
    wchunkscan_kernel<<<dim3(HH, BB), 256, 0, stream>>>(k_b, vT_b,
        h0, tmx, stepc, wcum_lo, enc ? wcum_hi : wcum_lo, hnew, enc);
    if (enc)
      retention2_kernel<1><<<dim3(8, HH, BB), 256, 0, stream>>>(
          q_b, k_b, vT_b, wcum_lo, wcum_hi, stepc, o);
    else
      retention2_kernel<0><<<dim3(8, HH, BB), 256, 0, stream>>>(
          q_b, k_b, vT_b, wcum_lo, nullptr, stepc, o);
  };

  // ---- encoder embed ----
  norm_obs_kernel<<<MM/4, 256, 0, stream>>>(obs, eoln, obs_n);
  gemmF(obs_n, wt_eow, nullptr, gf_b, OBSD, 1.f, ACT_GELU);   // gf_b = obs_rep (bf16)

  // ---- encoder layers ----
  for (int i = 0; i < LL; ++i){
    if (i == 0) norm(gf_b, nullptr, eln, x_b, x_pe_b, NORM_PLAIN);
    else        norm(xrep_b, nullptr, eln, x_b, x_pe_b, NORM_PLAIN);
    gemmQKV(x_pe_b, wt_eqkv + (size_t)3*i*W55);
    retention(enc_hs + i*HS_L, enc_out + i*HS_L, t1_b, 1);
    gemmF(t1_b, wt_ewo + i*W55, nullptr, gf_b, EE, 1.f, ACT_NONE);
    norm(x_b, gf_b, eln1 + i*EE, t1_b, nullptr, NORM_ADD);
    gemmSW(t1_b, wt_efg + i*W55, wt_efp + i*W55);
    norm(t1_b, sw_b, eln2 + i*EE, xrep_b, xrep_pe_b, NORM_ADD);
  }

  // ---- value head ----
  gemmF(xrep_b, wt_ehw1, ehb1, gf_b, EE, 1.f, ACT_GELU);
  norm(gf_b, nullptr, ehln, t1_b, nullptr, NORM_PLAIN);
  value_head_kernel<<<MM/32, 256, 0, stream>>>(t1_b, ehw2, ehb2, value_out);

  // ---- decoder embed ----
  act_embed_kernel<<<(MM*64)/256, 256, 0, stream>>>(action, act_b);
  gemmF(act_b, wt_daw, nullptr, gf_b, 64, 1.f, ACT_GELU);
  norm(gf_b, nullptr, dln, x_b, x_pe_b, NORM_PLAIN);

  // ---- decoder layers ----
  for (int i = 0; i < LL; ++i){
    gemmQKV(x_pe_b, wt_dqkv1 + (size_t)3*i*W55);
    retention(dec_hs1 + i*HS_L, d1_out + i*HS_L, t1_b, 0);
    gemmF(t1_b, wt_dwo1 + i*W55, nullptr, gf_b, EE, 1.f, ACT_NONE);
    norm(x_b, gf_b, dln1 + i*EE, t1_b, t1_pe_b, NORM_ADD);   // r
    gemmQ2(xrep_pe_b, wt_dwq2 + i*W55);
    gemmKV(t1_pe_b, wt_dkv2 + (size_t)2*i*W55);
    retention(dec_hs2 + i*HS_L, d2_out + i*HS_L, t1_b, 0);
    gemmF(t1_b, wt_dwo2 + i*W55, nullptr, gf_b, EE, 1.f, ACT_NONE);
    norm(xrep_b, gf_b, dln2 + i*EE, x_b, nullptr, NORM_ADD); // y
    gemmSW(x_b, wt_dfg + i*W55, wt_dfp + i*W55);
    norm(x_b, sw_b, dln3 + i*EE, x_b, x_pe_b, NORM_ADD);
  }

  // ---- logits head ----
  gemmF(x_b, wt_dhw1, dhb1, gf_b, EE, 1.f, ACT_GELU);
  norm(gf_b, nullptr, dhln, t1_b, nullptr, NORM_PLAIN);
  logits_head_kernel<<<MM/16, 256, 0, stream>>>(t1_b, dhw2, dhb2, logits_out);
}

// Round 8
// 1137.175 us; speedup vs baseline: 1.5671x; 1.0282x over previous
//
#include <hip/hip_runtime.h>
#include <hip/hip_bf16.h>
#include <math.h>

typedef __attribute__((ext_vector_type(8))) short short8;     // 8 bf16 = 4 VGPRs
typedef __attribute__((ext_vector_type(4))) short short4v;    // 4 bf16 = 8B
typedef __attribute__((ext_vector_type(4))) float f32x4;

#define BB 16
#define SS 512
#define EE 512
#define HH 8
#define DH 64
#define LL 3
#define MM (BB*SS)
#define OBSD 128
#define ACTD 17
#define INV_SQRT_D 0.125f

#define ACT_NONE 0
#define ACT_GELU 1

#define NORM_PLAIN 0
#define NORM_ADD 1

__device__ __forceinline__ float gelu_f(float x){
  float x3 = x*x*x;
  return 0.5f*x*(1.f + tanhf(0.7978845608028654f*(x + 0.044715f*x3)));
}
__device__ __forceinline__ float silu_f(float x){ return x/(1.f+expf(-x)); }
__device__ __forceinline__ float lkappa(int h){ return logf(1.f - exp2f(-5.f - (float)h)); }
__device__ __forceinline__ unsigned short f2bs(float f){
  unsigned int u = __float_as_uint(f);
  u += 0x7FFFu + ((u >> 16) & 1u);
  return (unsigned short)(u >> 16);
}
__device__ __forceinline__ float bs2f(unsigned short u){
  return __uint_as_float(((unsigned int)u) << 16);
}

// async global->LDS, 16B per lane. LDS dest = wave-uniform base + lane*16 (linear).
typedef const __attribute__((address_space(1))) unsigned int* gas1_t;
typedef __attribute__((address_space(3))) unsigned int* las3_t;
__device__ __forceinline__ void gl16(const void* g, void* l){
  __builtin_amdgcn_global_load_lds((gas1_t)g, (las3_t)l, 16, 0, 0);
}

// raw pipeline sync: wait own async loads, block barrier, pin scheduler.
#define PIPE_SYNC do{ asm volatile("s_waitcnt vmcnt(0)" ::: "memory"); \
                      __builtin_amdgcn_s_barrier(); \
                      __builtin_amdgcn_sched_barrier(0); }while(0)

// ---------------- weight transpose: W[K][512] fp32 -> Wt[512][Kpad] bf16 ----------------
__global__ __launch_bounds__(256) void wtpose_kernel(
    const float* __restrict__ src, unsigned short* __restrict__ dst, int K, int Kpad)
{
  __shared__ float t[32][33];
  const int gx = blockIdx.x, gy = blockIdx.y;
  const int tx = threadIdx.x, ty = threadIdx.y;
  #pragma unroll
  for (int i = 0; i < 4; ++i){
    int k = gx*32 + ty + i*8, n = gy*32 + tx;
    t[ty+i*8][tx] = (k < K) ? src[(size_t)k*EE + n] : 0.f;
  }
  __syncthreads();
  #pragma unroll
  for (int i = 0; i < 4; ++i){
    int k = gx*32 + tx, n = gy*32 + ty + i*8;
    dst[(size_t)n*Kpad + k] = f2bs(t[tx][ty+i*8]);
  }
}

struct TP50 { const float* s[50]; unsigned short* d[50]; };
__global__ __launch_bounds__(256) void wtpose_batch_kernel(TP50 tp)
{
  __shared__ float t[32][33];
  const float* src = tp.s[blockIdx.z];
  unsigned short* dst = tp.d[blockIdx.z];
  const int gx = blockIdx.x, gy = blockIdx.y;
  const int tx = threadIdx.x, ty = threadIdx.y;
  #pragma unroll
  for (int i = 0; i < 4; ++i){
    int k = gx*32 + ty + i*8, n = gy*32 + tx;
    t[ty+i*8][tx] = src[(size_t)k*EE + n];
  }
  __syncthreads();
  #pragma unroll
  for (int i = 0; i < 4; ++i){
    int k = gx*32 + tx, n = gy*32 + ty + i*8;
    dst[(size_t)n*EE + k] = f2bs(t[tx][ty+i*8]);
  }
}

// ---------------- 128x128 MFMA GEMM (double-buffered global_load_lds, XOR-swizzled LDS) ----------------
// MODE 0: Cb = bf16( act(scale*(A@W) + bias) ).
// MODE 1: QKV raw epilogue with optional second input region:
//   blocks with bn >= split_bn read A2/Wt2 at local bn (bnl = bn - split_bn),
//   group = g2 + (bnl>>9); else group = gstart + (bn>>9).
//   group 0: raw q row-major ; 1: k row-major (scale 1/8) ; 2: V -> vT [b][h][e][m]
template<int MODE>
__global__ __launch_bounds__(256) void gemm128_kernel(
    const unsigned short* __restrict__ A, const unsigned short* __restrict__ Wt,
    const float* __restrict__ bias, unsigned short* __restrict__ Cb,
    int Kpad, float scale, int act, int gstart,
    const unsigned short* __restrict__ A2, const unsigned short* __restrict__ Wt2,
    int split_bn, int g2,
    unsigned short* __restrict__ qout, unsigned short* __restrict__ kout,
    unsigned short* __restrict__ vT)
{
  __shared__ unsigned short As[2][128*64];
  __shared__ unsigned short Bs[2][128*64];
  const int bm = blockIdx.y*128, bn = blockIdx.x*128;
  const int tid = threadIdx.x, lane = tid & 63, wv = tid >> 6;
  const int wr = wv >> 1, wc = wv & 1;
  const int l16 = lane & 15, quad = lane >> 4;

  const unsigned short* Ap = A;
  const unsigned short* Wp = Wt;
  int bnl = bn;
  int group = 0;
  if (MODE == 1){
    if (bn >= split_bn){ Ap = A2; Wp = Wt2; bnl = bn - split_bn; group = g2 + (bnl >> 9); }
    else group = gstart + (bnl >> 9);
  }

  f32x4 acc[4][4];
  #pragma unroll
  for (int i=0;i<4;i++)
    #pragma unroll
    for (int j=0;j<4;j++) acc[i][j]=(f32x4)(0.f);

  // staging: lane covers physical granule; row = granule>>3, logical slot = (g&7)^(row&7)
  const int sg = lane >> 3;
  const int lg = (lane & 7) ^ sg;
  size_t aoff[4], boff[4];
  #pragma unroll
  for (int i=0;i<4;i++){
    aoff[i] = (size_t)(bm + wv*32 + i*8 + sg)*Kpad + lg*8;
    boff[i] = (size_t)(bnl + wv*32 + i*8 + sg)*Kpad + lg*8;
  }
  const int swz = (l16 & 7) << 3;            // read-side XOR (elements)

  auto STAGE = [&](int buf, int t){
    const int k0 = t*64;
    #pragma unroll
    for (int i=0;i<4;i++){
      gl16(Ap + aoff[i] + k0, (char*)&As[buf][0] + ((wv*4+i) << 10));
      gl16(Wp + boff[i] + k0, (char*)&Bs[buf][0] + ((wv*4+i) << 10));
    }
  };
  auto COMPUTE = [&](int buf){
    short8 af[4][2], bf[4][2];
    #pragma unroll
    for (int mt=0; mt<4; ++mt)
      #pragma unroll
      for (int ks=0; ks<2; ++ks)
        af[mt][ks] = *(const short8*)&As[buf][(wr*64 + mt*16 + l16)*64 + ((ks*32 + quad*8) ^ swz)];
    #pragma unroll
    for (int nt=0; nt<4; ++nt)
      #pragma unroll
      for (int ks=0; ks<2; ++ks)
        bf[nt][ks] = *(const short8*)&Bs[buf][(wc*64 + nt*16 + l16)*64 + ((ks*32 + quad*8) ^ swz)];
    #pragma unroll
    for (int ks=0; ks<2; ++ks)
      #pragma unroll
      for (int mt=0; mt<4; ++mt)
        #pragma unroll
        for (int nt=0; nt<4; ++nt)
          acc[mt][nt] = __builtin_amdgcn_mfma_f32_16x16x32_bf16(af[mt][ks], bf[nt][ks], acc[mt][nt], 0, 0, 0);
  };

  const int NT = Kpad >> 6;
  STAGE(0, 0);
  PIPE_SYNC;
  int cur = 0;
  for (int t = 0; t < NT; ++t){
    if (t+1 < NT) STAGE(cur^1, t+1);
    COMPUTE(cur);
    if (t+1 < NT) PIPE_SYNC;
    cur ^= 1;
  }

  if (MODE == 0){
    #pragma unroll
    for (int mt=0; mt<4; ++mt){
      int rb = bm + wr*64 + mt*16 + quad*4;
      #pragma unroll
      for (int nt=0; nt<4; ++nt){
        int col = bn + wc*64 + nt*16 + l16;
        float bv = bias ? bias[col] : 0.f;
        #pragma unroll
        for (int j=0;j<4;j++){
          float v = acc[mt][nt][j]*scale + bv;
          if (act==ACT_GELU) v = gelu_f(v);
          Cb[(size_t)(rb+j)*EE + col] = f2bs(v);
        }
      }
    }
  } else {
    if (group <= 1){
      unsigned short* O = (group == 0) ? qout : kout;
      const float scl = (group == 1) ? INV_SQRT_D : 1.f;
      #pragma unroll
      for (int mt=0; mt<4; ++mt){
        int rb = bm + wr*64 + mt*16 + quad*4;
        #pragma unroll
        for (int nt=0; nt<4; ++nt){
          int ccol = (bnl & 511) + wc*64 + nt*16 + l16;
          #pragma unroll
          for (int j=0;j<4;j++)
            O[(size_t)(rb+j)*EE + ccol] = f2bs(acc[mt][nt][j]*scl);
        }
      }
    } else {
      const int hh = ((bnl & 511) >> 6) + wc;   // wave-uniform head
      #pragma unroll
      for (int mt=0; mt<4; ++mt){
        int rb = bm + wr*64 + mt*16 + quad*4;
        int bloc = rb >> 9, m0 = rb & 511;
        #pragma unroll
        for (int nt=0; nt<4; ++nt){
          int ee = nt*16 + l16;
          size_t taddr = (((size_t)bloc*HH + hh)*DH + ee)*SS + m0;
          short4v pk;
          #pragma unroll
          for (int j=0;j<4;j++) pk[j] = (short)f2bs(acc[mt][nt][j]);
          *(short4v*)&vT[taddr] = pk;
        }
      }
    }
  }
}

// ---------------- SwiGLU GEMM (128x64, dual weight): swo = silu(A@Wg)*(A@Wp) ----------------
__global__ __launch_bounds__(256) void gemm_sw_kernel(
    const unsigned short* __restrict__ A, const unsigned short* __restrict__ Wt,
    const unsigned short* __restrict__ Wt2, unsigned short* __restrict__ swo)
{
  __shared__ unsigned short As[2][128*64];
  __shared__ unsigned short Bs[2][64*64];
  __shared__ unsigned short Bs2[2][64*64];
  const int bm = blockIdx.y*128, bn = blockIdx.x*64;
  const int tid = threadIdx.x, lane = tid & 63, wv = tid >> 6;
  const int wr = wv >> 1, wc = wv & 1;
  const int l16 = lane & 15, quad = lane >> 4;

  f32x4 acc[4][2], acc2[4][2];
  #pragma unroll
  for (int i=0;i<4;i++){
    acc[i][0]=(f32x4)(0.f); acc[i][1]=(f32x4)(0.f);
    acc2[i][0]=(f32x4)(0.f); acc2[i][1]=(f32x4)(0.f);
  }

  const int sg = lane >> 3;
  const int lg = (lane & 7) ^ sg;
  size_t aoff[4], boff[2];
  #pragma unroll
  for (int i=0;i<4;i++)
    aoff[i] = (size_t)(bm + (wv*4+i)*8 + sg)*EE + lg*8;
  #pragma unroll
  for (int i=0;i<2;i++)
    boff[i] = (size_t)(bn + (wv*2+i)*8 + sg)*EE + lg*8;

  const int swz = (l16 & 7) << 3;

  auto STAGE = [&](int buf, int t){
    const int k0 = t*64;
    #pragma unroll
    for (int i=0;i<4;i++)
      gl16(A + aoff[i] + k0, (char*)&As[buf][0] + ((wv*4+i) << 10));
    #pragma unroll
    for (int i=0;i<2;i++){
      gl16(Wt + boff[i] + k0, (char*)&Bs[buf][0] + ((wv*2+i) << 10));
      gl16(Wt2 + boff[i] + k0, (char*)&Bs2[buf][0] + ((wv*2+i) << 10));
    }
  };
  auto COMPUTE = [&](int buf){
    short8 af[4][2], bf[2][2], bf2[2][2];
    #pragma unroll
    for (int mt=0; mt<4; ++mt)
      #pragma unroll
      for (int ks=0; ks<2; ++ks)
        af[mt][ks] = *(const short8*)&As[buf][(wr*64 + mt*16 + l16)*64 + ((ks*32 + quad*8) ^ swz)];
    #pragma unroll
    for (int nt=0; nt<2; ++nt)
      #pragma unroll
      for (int ks=0; ks<2; ++ks){
        bf[nt][ks]  = *(const short8*)&Bs[buf][(wc*32 + nt*16 + l16)*64 + ((ks*32 + quad*8) ^ swz)];
        bf2[nt][ks] = *(const short8*)&Bs2[buf][(wc*32 + nt*16 + l16)*64 + ((ks*32 + quad*8) ^ swz)];
      }
    #pragma unroll
    for (int ks=0; ks<2; ++ks)
      #pragma unroll
      for (int mt=0; mt<4; ++mt)
        #pragma unroll
        for (int nt=0; nt<2; ++nt){
          acc[mt][nt]  = __builtin_amdgcn_mfma_f32_16x16x32_bf16(af[mt][ks], bf[nt][ks],  acc[mt][nt],  0, 0, 0);
          acc2[mt][nt] = __builtin_amdgcn_mfma_f32_16x16x32_bf16(af[mt][ks], bf2[nt][ks], acc2[mt][nt], 0, 0, 0);
        }
  };

  STAGE(0, 0);
  PIPE_SYNC;
  int cur = 0;
  for (int t = 0; t < 8; ++t){
    if (t+1 < 8) STAGE(cur^1, t+1);
    COMPUTE(cur);
    if (t+1 < 8) PIPE_SYNC;
    cur ^= 1;
  }

  #pragma unroll
  for (int mt=0; mt<4; ++mt){
    int rb = bm + wr*64 + mt*16 + quad*4;
    #pragma unroll
    for (int nt=0; nt<2; ++nt){
      int col = bn + wc*32 + nt*16 + l16;
      #pragma unroll
      for (int j=0;j<4;j++)
        swo[(size_t)(rb+j)*EE + col] = f2bs(silu_f(acc[mt][nt][j])*acc2[mt][nt][j]);
    }
  }
}

// ---------------- rmsnorm: wave-per-row, no LDS / barriers ----------------
__global__ __launch_bounds__(256) void norm_b_kernel(
    const unsigned short* __restrict__ ab, const unsigned short* __restrict__ resb,
    const float* __restrict__ w, unsigned short* __restrict__ o1,
    unsigned short* __restrict__ o2, const unsigned short* __restrict__ peb,
    int mode)
{
  const int row = blockIdx.x*4 + (threadIdx.x >> 6);
  const int lane = threadIdx.x & 63;
  const size_t base = (size_t)row*EE + lane*8;
  float t[8];
  {
    short8 av = *(const short8*)&ab[base];
    #pragma unroll
    for (int e=0;e<8;++e) t[e] = bs2f((unsigned short)av[e]);
  }
  if (mode == NORM_ADD){
    short8 rv = *(const short8*)&resb[base];
    #pragma unroll
    for (int e=0;e<8;++e) t[e] += bs2f((unsigned short)rv[e]);
  }
  float ss = 0.f;
  #pragma unroll
  for (int e=0;e<8;++e) ss += t[e]*t[e];
  #pragma unroll
  for (int o=32;o;o>>=1) ss += __shfl_xor(ss, o);
  float r = 1.f/sqrtf(ss/(float)EE + 1e-6f);
  float4 w0 = *(const float4*)&w[lane*8];
  float4 w1 = *(const float4*)&w[lane*8+4];
  float y[8];
  y[0]=t[0]*r*w0.x; y[1]=t[1]*r*w0.y; y[2]=t[2]*r*w0.z; y[3]=t[3]*r*w0.w;
  y[4]=t[4]*r*w1.x; y[5]=t[5]*r*w1.y; y[6]=t[6]*r*w1.z; y[7]=t[7]*r*w1.w;
  short8 pk;
  #pragma unroll
  for (int e=0;e<8;++e) pk[e] = (short)f2bs(y[e]);
  *(short8*)&o1[base] = pk;
  if (o2){
    short8 pv = *(const short8*)&peb[base];
    short8 pz;
    #pragma unroll
    for (int e=0;e<8;++e) pz[e] = (short)f2bs(y[e] + bs2f((unsigned short)pv[e]));
    *(short8*)&o2[base] = pz;
  }
}

// obs norm: wave-per-row, fp32 [MM][128] -> bf16
__global__ __launch_bounds__(256) void norm_obs_kernel(
    const float* __restrict__ a, const float* __restrict__ w, unsigned short* __restrict__ o)
{
  const int row = blockIdx.x*4 + (threadIdx.x >> 6);
  const int lane = threadIdx.x & 63;
  const size_t base = (size_t)row*OBSD + lane*2;
  float2 av = *(const float2*)&a[base];
  float ss = av.x*av.x + av.y*av.y;
  #pragma unroll
  for (int off=32;off;off>>=1) ss += __shfl_xor(ss, off);
  float r = 1.f/sqrtf(ss/(float)OBSD + 1e-6f);
  float2 wv2 = *(const float2*)&w[lane*2];
  unsigned int pk = (unsigned int)f2bs(av.x*r*wv2.x) | ((unsigned int)f2bs(av.y*r*wv2.y) << 16);
  *(unsigned int*)&o[base] = pk;
}

// action embed: fp32 [MM][17] -> bf16 [MM][64] zero-padded
__global__ __launch_bounds__(256) void act_embed_kernel(
    const float* __restrict__ a, unsigned short* __restrict__ o)
{
  int idx = blockIdx.x*256 + threadIdx.x;
  int row = idx >> 6, col = idx & 63;
  o[idx] = (col < ACTD) ? f2bs(a[(size_t)row*ACTD + col]) : 0;
}

// ---------------- fused chunk-state + scan, d-split + pass-split, async double-buffer ----------------
// grid: (ENC?4:2, HH, BB). x: dhalf = x&1, pass = x>>1 (enc only; pass1 = hi suffix).
// pass0: wcum_lo[c] = elk*h0^T + sum_{c'<c} Wc_lo (k scaled e^{-lk ts}), hnew.
// pass1: wcum_hi[c] = sum_{c'>c} Wc_hi (k scaled e^{+lk ts}).
template<int ENC>
__global__ __launch_bounds__(256) void wchunkscan_kernel(
    const unsigned short* __restrict__ k, const unsigned short* __restrict__ vT,
    const float* __restrict__ h0, const float* __restrict__ tmx,
    const int* __restrict__ tsi,
    unsigned short* __restrict__ wcum_lo, unsigned short* __restrict__ wcum_hi,
    float* __restrict__ hnew)
{
  __shared__ unsigned short vsh[2][64*72];
  __shared__ unsigned short ksh[2][32*72];
  const int gx = blockIdx.x, h = blockIdx.y, b = blockIdx.z;
  const int dhalf = gx & 1;
  const int pass = ENC ? (gx >> 1) : 0;
  const int tid = threadIdx.x, lane = tid & 63, wv = tid >> 6;
  const int quad = lane >> 4, l16 = lane & 15;
  const float lk = lkappa(h);
  const float elk = __expf(lk);
  const float etm = __expf(lk*tmx[b]);
  const size_t wbase = ((size_t)b*HH + h)*8*4096;
  const size_t hbase = (size_t)b*(LL*HH*DH*DH) + (size_t)h*(DH*DH);
  const int e0r = wv*16 + quad*4;           // e base; +j
  const int rv = tid >> 2, segv = (tid & 3)*16;
  const int kact = ((tid & 3) < 2), segk = (tid & 1)*16;
  const int rk = tid >> 2;
  const float ksgn = pass ? lk : -lk;
  unsigned short* wout = pass ? wcum_hi : wcum_lo;
  const int c0 = pass ? 7 : 0, dc = pass ? -1 : 1;

  f32x4 cum[2];
  #pragma unroll
  for (int dt=0; dt<2; ++dt)
    #pragma unroll
    for (int j=0;j<4;j++)
      cum[dt][j] = pass ? 0.f
        : elk * h0[hbase + (size_t)(dhalf*32 + dt*16 + l16)*64 + e0r + j];

  short8 vv0, vv1, kv0, kv1;
  float kts = 0.f;
  auto LOADR = [&](int c){
    const unsigned short* vrow = vT + (((size_t)b*HH + h)*DH + rv)*SS + c*64 + segv;
    vv0 = *(const short8*)(vrow);
    vv1 = *(const short8*)(vrow + 8);
    if (kact){
      const unsigned short* krow = k + ((size_t)b*SS + c*64 + rk)*EE + h*DH + dhalf*32 + segk;
      kv0 = *(const short8*)(krow);
      kv1 = *(const short8*)(krow + 8);
      kts = (float)tsi[b*SS + c*64 + rk];
    }
  };
  auto WRITE = [&](int buf){
    *(short8*)&vsh[buf][rv*72 + segv] = vv0;
    *(short8*)&vsh[buf][rv*72 + segv + 8] = vv1;
    if (kact){
      float els = __expf(ksgn*kts);
      #pragma unroll
      for (int e=0;e<8;++e){
        ksh[buf][(segk + e)*72 + rk]     = f2bs(bs2f((unsigned short)kv0[e])*els);
        ksh[buf][(segk + 8 + e)*72 + rk] = f2bs(bs2f((unsigned short)kv1[e])*els);
      }
    }
  };

  LOADR(c0);
  WRITE(0);
  __syncthreads();
  int cur = 0;
  for (int i=0;i<8;++i){
    const int c = c0 + dc*i;
    if (i<7) LOADR(c + dc);
    short8 av0 = *(const short8*)&vsh[cur][(wv*16 + l16)*72 + quad*8];
    short8 av1 = *(const short8*)&vsh[cur][(wv*16 + l16)*72 + 32 + quad*8];
    f32x4 acc[2];
    #pragma unroll
    for (int dt=0; dt<2; ++dt){
      f32x4 a = (f32x4)(0.f);
      short8 kb0 = *(const short8*)&ksh[cur][(dt*16 + l16)*72 + quad*8];
      short8 kb1 = *(const short8*)&ksh[cur][(dt*16 + l16)*72 + 32 + quad*8];
      a = __builtin_amdgcn_mfma_f32_16x16x32_bf16(av0, kb0, a, 0, 0, 0);
      a = __builtin_amdgcn_mfma_f32_16x16x32_bf16(av1, kb1, a, 0, 0, 0);
      acc[dt] = a;
    }
    #pragma unroll
    for (int dt=0; dt<2; ++dt)
      #pragma unroll
      for (int j=0;j<4;j++){
        wout[wbase + (size_t)c*4096 + (size_t)(e0r+j)*64 + dhalf*32 + dt*16 + l16] = f2bs(cum[dt][j]);
        cum[dt][j] += acc[dt][j];
      }
    if (i<7){ WRITE(cur^1); __syncthreads(); cur ^= 1; }
  }
  if (!pass){
    #pragma unroll
    for (int dt=0; dt<2; ++dt)
      #pragma unroll
      for (int j=0;j<4;j++)
        hnew[hbase + (size_t)(dhalf*32 + dt*16 + l16)*64 + e0r + j] = etm * cum[dt][j];
  }
}

// ---------------- retention (chunked-recurrent, raw q/k with staged scaling) ----------------
template<int ENC>
__global__ __launch_bounds__(256) void retention2_kernel(
    const unsigned short* __restrict__ q, const unsigned short* __restrict__ k,
    const unsigned short* __restrict__ vT,
    const unsigned short* __restrict__ wlo, const unsigned short* __restrict__ whi,
    const int* __restrict__ tsi, unsigned short* __restrict__ outp)
{
  __shared__ unsigned short qsh[64*72];        // reused as psh in boundary
  __shared__ unsigned short wsh[64*72];
  __shared__ unsigned short ksh[64*72];
  __shared__ unsigned short vsh[64*72];
  __shared__ unsigned short qsh2[ENC ? 64*72 : 2];  // reused as ksh2 in boundary
  __shared__ unsigned short wsh2[ENC ? 64*72 : 2];
  __shared__ float tsf[SS];
  const int b = blockIdx.z, h = blockIdx.y, t = blockIdx.x;
  const int n0 = t*64;
  const int tid = threadIdx.x, lane = tid & 63, wv = tid >> 6;
  const int quad = lane >> 4, l16 = lane & 15;
  const float lk = lkappa(h);

  for (int i = tid; i < SS; i += 256) tsf[i] = (float)tsi[b*SS + i];
  {
    const int n = tid >> 2, seg = (tid & 3)*16;
    float ts_n = (float)tsi[b*SS + n0 + n];
    float e0 = __expf(lk*ts_n);
    float e1 = ENC ? __expf(-lk*ts_n) : 0.f;
    const unsigned short* qr = q + ((size_t)b*SS + n0 + n)*EE + h*DH + seg;
    #pragma unroll
    for (int i = 0; i < 2; ++i){
      short8 v = *(const short8*)(qr + i*8);
      short8 o, o2;
      #pragma unroll
      for (int e=0;e<8;++e){
        float f = bs2f((unsigned short)v[e]);
        o[e] = (short)f2bs(f*e0);
        if (ENC) o2[e] = (short)f2bs(f*e1);
      }
      *(short8*)&qsh[n*72 + seg + i*8] = o;
      if (ENC) *(short8*)&qsh2[n*72 + seg + i*8] = o2;
    }
    const unsigned short* wr = wlo + (((size_t)b*HH + h)*8 + t)*4096 + (size_t)n*64 + seg;
    #pragma unroll
    for (int i = 0; i < 2; ++i)
      *(short8*)&wsh[n*72 + seg + i*8] = *(const short8*)(wr + i*8);
    if (ENC){
      const unsigned short* wr2 = whi + (((size_t)b*HH + h)*8 + t)*4096 + (size_t)n*64 + seg;
      #pragma unroll
      for (int i = 0; i < 2; ++i)
        *(short8*)&wsh2[n*72 + seg + i*8] = *(const short8*)(wr2 + i*8);
    }
  }
  __syncthreads();

  const int rowbase = wv*16;
  short8 qa[2], qa2[2];
  #pragma unroll
  for (int ks=0; ks<2; ++ks)
    qa[ks] = *(const short8*)&qsh[(rowbase + l16)*72 + ks*32 + quad*8];
  if (ENC){
    #pragma unroll
    for (int ks=0; ks<2; ++ks)
      qa2[ks] = *(const short8*)&qsh2[(rowbase + l16)*72 + ks*32 + quad*8];
  }

  float tn = tsf[n0 + lane];
  float maxn = tn, minn = tn;
  #pragma unroll
  for (int o=32;o;o>>=1){
    maxn = fmaxf(maxn, __shfl_xor(maxn, o));
    minn = fminf(minn, __shfl_xor(minn, o));
  }

  // cross-chunk + h0 contribution
  f32x4 acc_o[4];
  #pragma unroll
  for (int et=0; et<4; ++et){
    f32x4 a = (f32x4)(0.f);
    #pragma unroll
    for (int ks=0; ks<2; ++ks){
      short8 wb = *(const short8*)&wsh[(et*16 + l16)*72 + ks*32 + quad*8];
      a = __builtin_amdgcn_mfma_f32_16x16x32_bf16(qa[ks], wb, a, 0, 0, 0);
    }
    if (ENC){
      #pragma unroll
      for (int ks=0; ks<2; ++ks){
        short8 wb2 = *(const short8*)&wsh2[(et*16 + l16)*72 + ks*32 + quad*8];
        a = __builtin_amdgcn_mfma_f32_16x16x32_bf16(qa2[ks], wb2, a, 0, 0, 0);
      }
    }
    acc_o[et] = a;
  }

  // boundary chunk(s)
  for (int c = 0; c < 8; ++c){
    const int mc = c*64;
    float tmv = tsf[mc + lane];
    float maxm = tmv, minm = tmv;
    #pragma unroll
    for (int o=32;o;o>>=1){
      maxm = fmaxf(maxm, __shfl_xor(maxm, o));
      minm = fminf(minm, __shfl_xor(minm, o));
    }
    if (ENC){
      if (maxm <= minn) continue;
      if (minm >= maxn) continue;
    } else {
      if ((maxm < minn) || (maxm == minn && (mc + 63) < n0)) continue;
      if (minm > maxn) continue;
    }
    __syncthreads();
    {
      const int m = tid >> 2, cb = (tid & 3)*16;
      float ts_m = tsf[mc + m];
      float ek0 = __expf(-lk*ts_m);
      float ek1 = ENC ? __expf(lk*ts_m) : 0.f;
      const unsigned short* krow = k + ((size_t)b*SS + mc + m)*EE + h*DH + cb;
      #pragma unroll
      for (int i = 0; i < 2; ++i){
        short8 kv = *(const short8*)(krow + i*8);
        short8 o, o2;
        #pragma unroll
        for (int e=0;e<8;++e){
          float f = bs2f((unsigned short)kv[e]);
          o[e] = (short)f2bs(f*ek0);
          if (ENC) o2[e] = (short)f2bs(f*ek1);
        }
        *(short8*)&ksh[m*72 + cb + i*8] = o;
        if (ENC) *(short8*)&qsh2[m*72 + cb + i*8] = o2;
      }
      const unsigned short* vrow = vT + (((size_t)b*HH + h)*DH + m)*SS + mc + cb;
      #pragma unroll
      for (int i = 0; i < 2; ++i)
        *(short8*)&vsh[m*72 + cb + i*8] = *(const short8*)(vrow + i*8);
    }
    __syncthreads();
    f32x4 sacc[4], sacc2[4];
    #pragma unroll
    for (int mt=0; mt<4; ++mt){
      f32x4 a = (f32x4)(0.f);
      #pragma unroll
      for (int ks=0; ks<2; ++ks){
        short8 kb = *(const short8*)&ksh[(mt*16 + l16)*72 + ks*32 + quad*8];
        a = __builtin_amdgcn_mfma_f32_16x16x32_bf16(qa[ks], kb, a, 0, 0, 0);
      }
      sacc[mt] = a;
      if (ENC){
        f32x4 a2 = (f32x4)(0.f);
        #pragma unroll
        for (int ks=0; ks<2; ++ks){
          short8 kb2 = *(const short8*)&qsh2[(mt*16 + l16)*72 + ks*32 + quad*8];
          a2 = __builtin_amdgcn_mfma_f32_16x16x32_bf16(qa2[ks], kb2, a2, 0, 0, 0);
        }
        sacc2[mt] = a2;
      }
    }
    float tsm[4]; int mg[4];
    #pragma unroll
    for (int mt=0; mt<4; ++mt){ mg[mt] = mc + mt*16 + l16; tsm[mt] = tsf[mg[mt]]; }
    #pragma unroll
    for (int j=0;j<4;j++){
      int nloc = rowbase + quad*4 + j;
      int n = n0 + nloc;
      float tsn = tsf[n];
      #pragma unroll
      for (int mt=0; mt<4; ++mt){
        float diff = tsn - tsm[mt];
        float p;
        if (ENC) p = (diff >= 0.f) ? sacc[mt][j] : sacc2[mt][j];
        else     p = ((diff > 0.f) || (diff == 0.f && n >= mg[mt])) ? sacc[mt][j] : 0.f;
        qsh[nloc*72 + mt*16 + l16] = f2bs(p);   // qsh reused as psh
      }
    }
    #pragma unroll
    for (int ks=0; ks<2; ++ks){
      short8 pa = *(const short8*)&qsh[(rowbase + l16)*72 + ks*32 + quad*8];
      #pragma unroll
      for (int et=0; et<4; ++et){
        short8 vb = *(const short8*)&vsh[(et*16 + l16)*72 + ks*32 + quad*8];
        acc_o[et] = __builtin_amdgcn_mfma_f32_16x16x32_bf16(pa, vb, acc_o[et], 0, 0, 0);
      }
    }
  }
  #pragma unroll
  for (int j=0;j<4;j++){
    size_t rbase = ((size_t)b*SS + n0 + rowbase + quad*4 + j)*EE + h*DH;
    #pragma unroll
    for (int et=0; et<4; ++et)
      outp[rbase + et*16 + l16] = f2bs(acc_o[et][j]);
  }
}

// ---------------- small helpers ----------------
__global__ void tsmax_kernel(const int* __restrict__ tsi, float* __restrict__ tmx){
  __shared__ int red[4];
  int b = blockIdx.x, tid = threadIdx.x;
  int m = max(tsi[b*SS+tid], tsi[b*SS+256+tid]);
  #pragma unroll
  for (int o=32;o;o>>=1) m = max(m, __shfl_down(m,o));
  if ((tid&63)==0) red[tid>>6]=m;
  __syncthreads();
  if (tid==0) tmx[b] = (float)max(max(red[0],red[1]),max(red[2],red[3]));
}

__global__ void pe_kernel(const int* __restrict__ tsi, unsigned short* __restrict__ peb){
  int idx = blockIdx.x*256 + threadIdx.x;
  int row = idx >> 9, j = idx & 511;
  float ts = (float)tsi[row];
  int jj = j & 255;
  float freq = expf(-9.210340371976184f*(float)jj*(1.f/256.f));
  float ang = ts*freq;
  peb[idx] = f2bs((j < 256) ? sinf(ang) : cosf(ang));
}

// fused rmsnorm + value head: out = (rms(x)·x·ln) @ w + b
__global__ __launch_bounds__(256) void value_head_kernel(
    const unsigned short* __restrict__ x, const float* __restrict__ ln,
    const float* __restrict__ w, const float* __restrict__ bias,
    float* __restrict__ outp)
{
  const int row = blockIdx.x*4 + (threadIdx.x >> 6);
  const int lane = threadIdx.x & 63;
  const size_t base = (size_t)row*EE + lane*8;
  short8 xv = *(const short8*)&x[base];
  float4 l0 = *(const float4*)&ln[lane*8];
  float4 l1 = *(const float4*)&ln[lane*8+4];
  float4 w0 = *(const float4*)&w[lane*8];
  float4 w1 = *(const float4*)&w[lane*8+4];
  float lw[8] = {l0.x*w0.x, l0.y*w0.y, l0.z*w0.z, l0.w*w0.w,
                 l1.x*w1.x, l1.y*w1.y, l1.z*w1.z, l1.w*w1.w};
  float ss = 0.f, dp = 0.f;
  #pragma unroll
  for (int e=0;e<8;++e){
    float f = bs2f((unsigned short)xv[e]);
    ss += f*f;
    dp += f*lw[e];
  }
  #pragma unroll
  for (int o=32;o;o>>=1){ ss += __shfl_xor(ss,o); dp += __shfl_xor(dp,o); }
  if (lane==0) outp[row] = dp*(1.f/sqrtf(ss/(float)EE + 1e-6f)) + bias[0];
}

// fused rmsnorm + logits head: out[j] = (rms(x)·x·ln) @ w2[:,j] + b[j]
__global__ __launch_bounds__(256) void logits_head_kernel(
    const unsigned short* __restrict__ x, const float* __restrict__ ln,
    const float* __restrict__ w, const float* __restrict__ bias,
    float* __restrict__ outp)
{
  __shared__ unsigned short ysh[16*528];
  __shared__ unsigned short wsh[16*520];
  const int tid = threadIdx.x;
  const int row0 = blockIdx.x*16;
  const int g = tid >> 4, j16 = tid & 15;
  {
    const int kc = j16*32;
    #pragma unroll
    for (int kk = 0; kk < 32; ++kk)
      wsh[g*520 + kc + kk] = f2bs(w[(size_t)(kc + kk)*16 + g]);
  }
  {
    const unsigned short* xr = x + (size_t)(row0+g)*EE + j16*32;
    float xs[32];
    float ss = 0.f;
    #pragma unroll
    for (int i=0;i<4;++i){
      short8 v = *(const short8*)(xr + i*8);
      #pragma unroll
      for (int e=0;e<8;++e){ float f = bs2f((unsigned short)v[e]); xs[i*8+e]=f; ss += f*f; }
    }
    ss += __shfl_xor(ss,1); ss += __shfl_xor(ss,2);
    ss += __shfl_xor(ss,4); ss += __shfl_xor(ss,8);
    float r = 1.f/sqrtf(ss/(float)EE + 1e-6f);
    #pragma unroll
    for (int i=0;i<4;++i){
      float4 la = *(const float4*)&ln[j16*32 + i*8];
      float4 lb = *(const float4*)&ln[j16*32 + i*8 + 4];
      short8 o;
      o[0]=(short)f2bs(xs[i*8+0]*r*la.x); o[1]=(short)f2bs(xs[i*8+1]*r*la.y);
      o[2]=(short)f2bs(xs[i*8+2]*r*la.z); o[3]=(short)f2bs(xs[i*8+3]*r*la.w);
      o[4]=(short)f2bs(xs[i*8+4]*r*lb.x); o[5]=(short)f2bs(xs[i*8+5]*r*lb.y);
      o[6]=(short)f2bs(xs[i*8+6]*r*lb.z); o[7]=(short)f2bs(xs[i*8+7]*r*lb.w);
      *(short8*)&ysh[g*528 + j16*32 + i*8] = o;
    }
  }
  __syncthreads();
  float s = 0.f;
  for (int kk = 0; kk < EE; kk += 8){
    short8 xv = *(const short8*)&ysh[g*528 + kk];
    short8 wv = *(const short8*)&wsh[j16*520 + kk];
    #pragma unroll
    for (int e = 0; e < 8; ++e)
      s += bs2f((unsigned short)xv[e]) * bs2f((unsigned short)wv[e]);
  }
  outp[(size_t)(row0 + g)*16 + j16] = s + bias[j16];
}

// ---------------- orchestration ----------------
extern "C" void kernel_launch(void* const* d_in, const int* in_sizes, int n_in,
                              void* d_out, int out_size, void* d_ws, size_t ws_size,
                              hipStream_t stream)
{
  const float* obs     = (const float*)d_in[0];
  const float* action  = (const float*)d_in[1];
  const float* enc_hs  = (const float*)d_in[2];
  const float* dec_hs1 = (const float*)d_in[3];
  const float* dec_hs2 = (const float*)d_in[4];
  const int*   stepc   = (const int*)d_in[5];
  const float* eoln = (const float*)d_in[6];
  const float* eow  = (const float*)d_in[7];
  const float* eln  = (const float*)d_in[8];
  const float* ewq  = (const float*)d_in[9];
  const float* ewk  = (const float*)d_in[10];
  const float* ewv  = (const float*)d_in[11];
  const float* ewo  = (const float*)d_in[12];
  const float* eln1 = (const float*)d_in[13];
  const float* eln2 = (const float*)d_in[14];
  const float* efg  = (const float*)d_in[15];
  const float* efp  = (const float*)d_in[16];
  const float* ehw1 = (const float*)d_in[17];
  const float* ehb1 = (const float*)d_in[18];
  const float* ehln = (const float*)d_in[19];
  const float* ehw2 = (const float*)d_in[20];
  const float* ehb2 = (const float*)d_in[21];
  const float* daw  = (const float*)d_in[22];
  const float* dln  = (const float*)d_in[23];
  const float* dwq1 = (const float*)d_in[24];
  const float* dwk1 = (const float*)d_in[25];
  const float* dwv1 = (const float*)d_in[26];
  const float* dwo1 = (const float*)d_in[27];
  const float* dwq2 = (const float*)d_in[28];
  const float* dwk2 = (const float*)d_in[29];
  const float* dwv2 = (const float*)d_in[30];
  const float* dwo2 = (const float*)d_in[31];
  const float* dln1 = (const float*)d_in[32];
  const float* dln2 = (const float*)d_in[33];
  const float* dln3 = (const float*)d_in[34];
  const float* dfg  = (const float*)d_in[35];
  const float* dfp  = (const float*)d_in[36];
  const float* dhw1 = (const float*)d_in[37];
  const float* dhb1 = (const float*)d_in[38];
  const float* dhln = (const float*)d_in[39];
  const float* dhw2 = (const float*)d_in[40];
  const float* dhb2 = (const float*)d_in[41];

  const size_t BUF = (size_t)MM*EE;
  // region A: wcum_lo + wcum_hi (bf16) ; gf_b (bf16 gemmF out) aliases wcum_lo (disjoint lifetimes)
  float* wsf  = (float*)d_ws;
  float* f32a = wsf;
  float* f32b = f32a + BUF;
  float* tmx  = f32b + BUF;
  unsigned short* wcum_lo = (unsigned short*)f32a;      // [B][H][8][4096] bf16
  unsigned short* wcum_hi = wcum_lo + BUF;              // [B][H][8][4096] bf16 (enc)
  unsigned short* gf_b    = wcum_lo;                    // alias: gemmF bf16 out
  unsigned short* sw_b    = (unsigned short*)f32b;      // silu(g)*p bf16
  // bf16 region
  unsigned short* ub = (unsigned short*)(tmx + 64);
  unsigned short* xrep_b    = ub;  ub += BUF;
  unsigned short* xrep_pe_b = ub;  ub += BUF;
  unsigned short* x_b       = ub;  ub += BUF;
  unsigned short* x_pe_b    = ub;  ub += BUF;
  unsigned short* t1_b      = ub;  ub += BUF;
  unsigned short* t1_pe_b   = ub;  ub += BUF;   // decoder r+pe
  unsigned short* peb       = ub;  ub += BUF;
  unsigned short* q_b       = ub;  ub += BUF;   // raw q
  unsigned short* k_b       = ub;  ub += BUF;   // raw k * 1/sqrt(D)
  unsigned short* vT_b      = ub;  ub += BUF;   // [B][H][64][512]
  unsigned short* obs_n     = ub;  ub += (size_t)MM*OBSD;
  unsigned short* act_b     = obs_n;            // aliased (obs_n dead by decoder embed)
  // weights
  const size_t W55 = (size_t)EE*EE;
  unsigned short* wts = ub;  ub += 50*W55;
  unsigned short* wt_eow = ub; ub += (size_t)EE*OBSD;
  unsigned short* wt_daw = ub; ub += (size_t)EE*64;
  size_t need = (char*)ub - (char*)d_ws;
  if (ws_size < need) return;

  // fused-weight layout (z index into wts):
  // 0..8  : enc [q,k,v] x3 layers     9..11 : ewo
  // 12..14: efg   15..17: efp   18: ehw1
  // 19..27: dec1 [q,k,v] x3           28..30: dwo1
  // 31..36: dec2 [k,v] x3             37..39: dwq2
  // 40..42: dwo2  43..45: dfg  46..48: dfp   49: dhw1
  unsigned short* wt_eqkv  = wts + 0*W55;   // +3*i per layer
  unsigned short* wt_ewo   = wts + 9*W55;
  unsigned short* wt_efg   = wts + 12*W55;
  unsigned short* wt_efp   = wts + 15*W55;
  unsigned short* wt_ehw1  = wts + 18*W55;
  unsigned short* wt_dqkv1 = wts + 19*W55;  // +3*i
  unsigned short* wt_dwo1  = wts + 28*W55;
  unsigned short* wt_dkv2  = wts + 31*W55;  // +2*i  ([k;v] contiguous per layer)
  unsigned short* wt_dwq2  = wts + 37*W55;
  unsigned short* wt_dwo2  = wts + 40*W55;
  unsigned short* wt_dfg   = wts + 43*W55;
  unsigned short* wt_dfp   = wts + 46*W55;
  unsigned short* wt_dhw1  = wts + 49*W55;

  float* out        = (float*)d_out;
  float* value_out  = out;
  float* logits_out = out + 8192;
  float* enc_out    = logits_out + (size_t)MM*16;
  float* d1_out     = enc_out + (size_t)BB*LL*HH*DH*DH;
  float* d2_out     = d1_out  + (size_t)BB*LL*HH*DH*DH;

  const size_t HS_L = (size_t)HH*DH*DH;

  {
    TP50 tp;
    int z = 0;
    auto add = [&](const float* p){ tp.s[z] = p; tp.d[z] = wts + (size_t)z*W55; ++z; };
    for (int i=0;i<3;++i){ add(ewq+i*W55); add(ewk+i*W55); add(ewv+i*W55); }
    for (int i=0;i<3;++i) add(ewo+i*W55);
    for (int i=0;i<3;++i) add(efg+i*W55);
    for (int i=0;i<3;++i) add(efp+i*W55);
    add(ehw1);
    for (int i=0;i<3;++i){ add(dwq1+i*W55); add(dwk1+i*W55); add(dwv1+i*W55); }
    for (int i=0;i<3;++i) add(dwo1+i*W55);
    for (int i=0;i<3;++i){ add(dwk2+i*W55); add(dwv2+i*W55); }
    for (int i=0;i<3;++i) add(dwq2+i*W55);
    for (int i=0;i<3;++i) add(dwo2+i*W55);
    for (int i=0;i<3;++i) add(dfg+i*W55);
    for (int i=0;i<3;++i) add(dfp+i*W55);
    add(dhw1);
    wtpose_batch_kernel<<<dim3(16,16,50), dim3(32,8), 0, stream>>>(tp);
  }
  wtpose_kernel<<<dim3(4,16), dim3(32,8), 0, stream>>>(eow, wt_eow, OBSD, OBSD);
  wtpose_kernel<<<dim3(2,16), dim3(32,8), 0, stream>>>(daw, wt_daw, ACTD, 64);

  pe_kernel<<<(MM*EE)/256, 256, 0, stream>>>(stepc, peb);
  tsmax_kernel<<<BB, 256, 0, stream>>>(stepc, tmx);

  auto gemmF = [&](const unsigned short* A, const unsigned short* Wt, const float* bias,
                   unsigned short* Cb, int Kpad, float scale, int act){
    gemm128_kernel<0><<<dim3(EE/128, MM/128), 256, 0, stream>>>(A, Wt, bias, Cb,
        Kpad, scale, act, 0, nullptr, nullptr, 1<<30, 0, nullptr, nullptr, nullptr);
  };
  auto gemmQKV = [&](const unsigned short* A, const unsigned short* Wt){
    gemm128_kernel<1><<<dim3(12, MM/128), 256, 0, stream>>>(A, Wt, nullptr, nullptr,
        EE, 1.f, ACT_NONE, 0, nullptr, nullptr, 1<<30, 0, q_b, k_b, vT_b);
  };
  // merged decoder layer-2 projections: blocks [0,4) q from A1@Wq2; [4,12) k,v from A2@[Wk2;Wv2]
  auto gemmQ2KV = [&](const unsigned short* A1, const unsigned short* Wq2,
                      const unsigned short* A2, const unsigned short* Wkv2){
    gemm128_kernel<1><<<dim3(12, MM/128), 256, 0, stream>>>(A1, Wq2, nullptr, nullptr,
        EE, 1.f, ACT_NONE, 0, A2, Wkv2, 512, 1, q_b, k_b, vT_b);
  };
  auto gemmSW = [&](const unsigned short* A, const unsigned short* Wg, const unsigned short* Wp){
    gemm_sw_kernel<<<dim3(EE/64, MM/128), 256, 0, stream>>>(A, Wg, Wp, sw_b);
  };
  auto norm = [&](const unsigned short* ab, const unsigned short* resb, const float* w,
                  unsigned short* o1, unsigned short* o2, int mode){
    norm_b_kernel<<<MM/4, 256, 0, stream>>>(ab, resb, w, o1, o2, peb, mode);
  };
  auto retention = [&](const float* h0, float* hnew, unsigned short* o, int enc){
    if (enc){
      wchunkscan_kernel<1><<<dim3(4, HH, BB), 256, 0, stream>>>(k_b, vT_b,
          h0, tmx, stepc, wcum_lo, wcum_hi, hnew);
      retention2_kernel<1><<<dim3(8, HH, BB), 256, 0, stream>>>(
          q_b, k_b, vT_b, wcum_lo, wcum_hi, stepc, o);
    } else {
      wchunkscan_kernel<0><<<dim3(2, HH, BB), 256, 0, stream>>>(k_b, vT_b,
          h0, tmx, stepc, wcum_lo, nullptr, hnew);
      retention2_kernel<0><<<dim3(8, HH, BB), 256, 0, stream>>>(
          q_b, k_b, vT_b, wcum_lo, nullptr, stepc, o);
    }
  };

  // ---- encoder embed ----
  norm_obs_kernel<<<MM/4, 256, 0, stream>>>(obs, eoln, obs_n);
  gemmF(obs_n, wt_eow, nullptr, gf_b, OBSD, 1.f, ACT_GELU);   // gf_b = obs_rep (bf16)

  // ---- encoder layers ----
  for (int i = 0; i < LL; ++i){
    if (i == 0) norm(gf_b, nullptr, eln, x_b, x_pe_b, NORM_PLAIN);
    else        norm(xrep_b, nullptr, eln, x_b, x_pe_b, NORM_PLAIN);
    gemmQKV(x_pe_b, wt_eqkv + (size_t)3*i*W55);
    retention(enc_hs + i*HS_L, enc_out + i*HS_L, t1_b, 1);
    gemmF(t1_b, wt_ewo + i*W55, nullptr, gf_b, EE, 1.f, ACT_NONE);
    norm(x_b, gf_b, eln1 + i*EE, t1_b, nullptr, NORM_ADD);
    gemmSW(t1_b, wt_efg + i*W55, wt_efp + i*W55);
    norm(t1_b, sw_b, eln2 + i*EE, xrep_b, xrep_pe_b, NORM_ADD);
  }

  // ---- value head (fused norm) ----
  gemmF(xrep_b, wt_ehw1, ehb1, gf_b, EE, 1.f, ACT_GELU);
  value_head_kernel<<<MM/4, 256, 0, stream>>>(gf_b, ehln, ehw2, ehb2, value_out);

  // ---- decoder embed ----
  act_embed_kernel<<<(MM*64)/256, 256, 0, stream>>>(action, act_b);
  gemmF(act_b, wt_daw, nullptr, gf_b, 64, 1.f, ACT_GELU);
  norm(gf_b, nullptr, dln, x_b, x_pe_b, NORM_PLAIN);

  // ---- decoder layers ----
  for (int i = 0; i < LL; ++i){
    gemmQKV(x_pe_b, wt_dqkv1 + (size_t)3*i*W55);
    retention(dec_hs1 + i*HS_L, d1_out + i*HS_L, t1_b, 0);
    gemmF(t1_b, wt_dwo1 + i*W55, nullptr, gf_b, EE, 1.f, ACT_NONE);
    norm(x_b, gf_b, dln1 + i*EE, t1_b, t1_pe_b, NORM_ADD);   // r
    gemmQ2KV(xrep_pe_b, wt_dwq2 + i*W55, t1_pe_b, wt_dkv2 + (size_t)2*i*W55);
    retention(dec_hs2 + i*HS_L, d2_out + i*HS_L, t1_b, 0);
    gemmF(t1_b, wt_dwo2 + i*W55, nullptr, gf_b, EE, 1.f, ACT_NONE);
    norm(xrep_b, gf_b, dln2 + i*EE, x_b, nullptr, NORM_ADD); // y
    gemmSW(x_b, wt_dfg + i*W55, wt_dfp + i*W55);
    norm(x_b, sw_b, dln3 + i*EE, x_b, x_pe_b, NORM_ADD);
  }

  // ---- logits head (fused norm) ----
  gemmF(x_b, wt_dhw1, dhb1, gf_b, EE, 1.f, ACT_GELU);
  logits_head_kernel<<<MM/16, 256, 0, stream>>>(gf_b, dhln, dhw2, dhb2, logits_out);
}

// Round 9
// 1120.104 us; speedup vs baseline: 1.5910x; 1.0152x over previous
//
#include <hip/hip_runtime.h>
#include <hip/hip_bf16.h>
#include <math.h>

typedef __attribute__((ext_vector_type(8))) short short8;     // 8 bf16 = 4 VGPRs
typedef __attribute__((ext_vector_type(4))) short short4v;    // 4 bf16 = 8B
typedef __attribute__((ext_vector_type(4))) float f32x4;

#define BB 16
#define SS 512
#define EE 512
#define HH 8
#define DH 64
#define LL 3
#define MM (BB*SS)
#define OBSD 128
#define ACTD 17
#define INV_SQRT_D 0.125f

#define ACT_NONE 0
#define ACT_GELU 1

#define NORM_PLAIN 0
#define NORM_ADD 1

__device__ __forceinline__ float gelu_f(float x){
  float x3 = x*x*x;
  return 0.5f*x*(1.f + tanhf(0.7978845608028654f*(x + 0.044715f*x3)));
}
__device__ __forceinline__ float silu_f(float x){ return x/(1.f+expf(-x)); }
__device__ __forceinline__ float lkappa(int h){ return logf(1.f - exp2f(-5.f - (float)h)); }
__device__ __forceinline__ unsigned short f2bs(float f){
  unsigned int u = __float_as_uint(f);
  u += 0x7FFFu + ((u >> 16) & 1u);
  return (unsigned short)(u >> 16);
}
__device__ __forceinline__ float bs2f(unsigned short u){
  return __uint_as_float(((unsigned int)u) << 16);
}
// XCD-aware chunked block remap (bijective; total must be divisible by 8).
__device__ __forceinline__ int xcd_swz(int p, int total){
  return (p & 7)*(total >> 3) + (p >> 3);
}

// async global->LDS, 16B per lane. LDS dest = wave-uniform base + lane*16 (linear).
typedef const __attribute__((address_space(1))) unsigned int* gas1_t;
typedef __attribute__((address_space(3))) unsigned int* las3_t;
__device__ __forceinline__ void gl16(const void* g, void* l){
  __builtin_amdgcn_global_load_lds((gas1_t)g, (las3_t)l, 16, 0, 0);
}

// raw pipeline sync: wait own async loads, block barrier, pin scheduler.
#define PIPE_SYNC do{ asm volatile("s_waitcnt vmcnt(0)" ::: "memory"); \
                      __builtin_amdgcn_s_barrier(); \
                      __builtin_amdgcn_sched_barrier(0); }while(0)

// ---------------- weight transpose: W[K][512] fp32 -> Wt[512][Kpad] bf16 ----------------
__global__ __launch_bounds__(256) void wtpose_kernel(
    const float* __restrict__ src, unsigned short* __restrict__ dst, int K, int Kpad)
{
  __shared__ float t[32][33];
  const int gx = blockIdx.x, gy = blockIdx.y;
  const int tx = threadIdx.x, ty = threadIdx.y;
  #pragma unroll
  for (int i = 0; i < 4; ++i){
    int k = gx*32 + ty + i*8, n = gy*32 + tx;
    t[ty+i*8][tx] = (k < K) ? src[(size_t)k*EE + n] : 0.f;
  }
  __syncthreads();
  #pragma unroll
  for (int i = 0; i < 4; ++i){
    int k = gx*32 + tx, n = gy*32 + ty + i*8;
    dst[(size_t)n*Kpad + k] = f2bs(t[tx][ty+i*8]);
  }
}

struct TP50 { const float* s[50]; unsigned short* d[50]; };
__global__ __launch_bounds__(256) void wtpose_batch_kernel(TP50 tp)
{
  __shared__ float t[32][33];
  const float* src = tp.s[blockIdx.z];
  unsigned short* dst = tp.d[blockIdx.z];
  const int gx = blockIdx.x, gy = blockIdx.y;
  const int tx = threadIdx.x, ty = threadIdx.y;
  #pragma unroll
  for (int i = 0; i < 4; ++i){
    int k = gx*32 + ty + i*8, n = gy*32 + tx;
    t[ty+i*8][tx] = src[(size_t)k*EE + n];
  }
  __syncthreads();
  #pragma unroll
  for (int i = 0; i < 4; ++i){
    int k = gx*32 + tx, n = gy*32 + ty + i*8;
    dst[(size_t)n*EE + k] = f2bs(t[tx][ty+i*8]);
  }
}

// ---------------- 128x128 MFMA GEMM (double-buffered global_load_lds, XOR-swizzled LDS) ----------------
// MODE 0: Cb = bf16( act(scale*(A@W) + bias) ).
// MODE 1: QKV raw epilogue with optional second input region:
//   blocks with bn >= split_bn read A2/Wt2 at local bn (bnl = bn - split_bn),
//   group = g2 + (bnl>>9); else group = gstart + (bn>>9).
//   group 0: raw q row-major ; 1: k row-major (scale 1/8) ; 2: V -> vT [b][h][e][m]
template<int MODE>
__global__ __launch_bounds__(256) void gemm128_kernel(
    const unsigned short* __restrict__ A, const unsigned short* __restrict__ Wt,
    const float* __restrict__ bias, unsigned short* __restrict__ Cb,
    int Kpad, float scale, int act, int gstart,
    const unsigned short* __restrict__ A2, const unsigned short* __restrict__ Wt2,
    int split_bn, int g2,
    unsigned short* __restrict__ qout, unsigned short* __restrict__ kout,
    unsigned short* __restrict__ vT)
{
  __shared__ unsigned short As[2][128*64];
  __shared__ unsigned short Bs[2][128*64];
  // XCD swizzle: consecutive logical blocks (sharing the A panel) -> same XCD
  const int P = blockIdx.y*gridDim.x + blockIdx.x;
  const int L = xcd_swz(P, gridDim.x*gridDim.y);
  const int bxl = L % gridDim.x, byl = L / gridDim.x;
  const int bm = byl*128, bn = bxl*128;
  const int tid = threadIdx.x, lane = tid & 63, wv = tid >> 6;
  const int wr = wv >> 1, wc = wv & 1;
  const int l16 = lane & 15, quad = lane >> 4;

  const unsigned short* Ap = A;
  const unsigned short* Wp = Wt;
  int bnl = bn;
  int group = 0;
  if (MODE == 1){
    if (bn >= split_bn){ Ap = A2; Wp = Wt2; bnl = bn - split_bn; group = g2 + (bnl >> 9); }
    else group = gstart + (bnl >> 9);
  }

  f32x4 acc[4][4];
  #pragma unroll
  for (int i=0;i<4;i++)
    #pragma unroll
    for (int j=0;j<4;j++) acc[i][j]=(f32x4)(0.f);

  // staging: lane covers physical granule; row = granule>>3, logical slot = (g&7)^(row&7)
  const int sg = lane >> 3;
  const int lg = (lane & 7) ^ sg;
  size_t aoff[4], boff[4];
  #pragma unroll
  for (int i=0;i<4;i++){
    aoff[i] = (size_t)(bm + wv*32 + i*8 + sg)*Kpad + lg*8;
    boff[i] = (size_t)(bnl + wv*32 + i*8 + sg)*Kpad + lg*8;
  }
  const int swz = (l16 & 7) << 3;            // read-side XOR (elements)

  auto STAGE = [&](int buf, int t){
    const int k0 = t*64;
    #pragma unroll
    for (int i=0;i<4;i++){
      gl16(Ap + aoff[i] + k0, (char*)&As[buf][0] + ((wv*4+i) << 10));
      gl16(Wp + boff[i] + k0, (char*)&Bs[buf][0] + ((wv*4+i) << 10));
    }
  };
  auto COMPUTE = [&](int buf){
    short8 af[4][2], bf[4][2];
    #pragma unroll
    for (int mt=0; mt<4; ++mt)
      #pragma unroll
      for (int ks=0; ks<2; ++ks)
        af[mt][ks] = *(const short8*)&As[buf][(wr*64 + mt*16 + l16)*64 + ((ks*32 + quad*8) ^ swz)];
    #pragma unroll
    for (int nt=0; nt<4; ++nt)
      #pragma unroll
      for (int ks=0; ks<2; ++ks)
        bf[nt][ks] = *(const short8*)&Bs[buf][(wc*64 + nt*16 + l16)*64 + ((ks*32 + quad*8) ^ swz)];
    #pragma unroll
    for (int ks=0; ks<2; ++ks)
      #pragma unroll
      for (int mt=0; mt<4; ++mt)
        #pragma unroll
        for (int nt=0; nt<4; ++nt)
          acc[mt][nt] = __builtin_amdgcn_mfma_f32_16x16x32_bf16(af[mt][ks], bf[nt][ks], acc[mt][nt], 0, 0, 0);
  };

  const int NT = Kpad >> 6;
  STAGE(0, 0);
  PIPE_SYNC;
  int cur = 0;
  for (int t = 0; t < NT; ++t){
    if (t+1 < NT) STAGE(cur^1, t+1);
    COMPUTE(cur);
    if (t+1 < NT) PIPE_SYNC;
    cur ^= 1;
  }

  if (MODE == 0){
    #pragma unroll
    for (int mt=0; mt<4; ++mt){
      int rb = bm + wr*64 + mt*16 + quad*4;
      #pragma unroll
      for (int nt=0; nt<4; ++nt){
        int col = bn + wc*64 + nt*16 + l16;
        float bv = bias ? bias[col] : 0.f;
        #pragma unroll
        for (int j=0;j<4;j++){
          float v = acc[mt][nt][j]*scale + bv;
          if (act==ACT_GELU) v = gelu_f(v);
          Cb[(size_t)(rb+j)*EE + col] = f2bs(v);
        }
      }
    }
  } else {
    if (group <= 1){
      unsigned short* O = (group == 0) ? qout : kout;
      const float scl = (group == 1) ? INV_SQRT_D : 1.f;
      #pragma unroll
      for (int mt=0; mt<4; ++mt){
        int rb = bm + wr*64 + mt*16 + quad*4;
        #pragma unroll
        for (int nt=0; nt<4; ++nt){
          int ccol = (bnl & 511) + wc*64 + nt*16 + l16;
          #pragma unroll
          for (int j=0;j<4;j++)
            O[(size_t)(rb+j)*EE + ccol] = f2bs(acc[mt][nt][j]*scl);
        }
      }
    } else {
      const int hh = ((bnl & 511) >> 6) + wc;   // wave-uniform head
      #pragma unroll
      for (int mt=0; mt<4; ++mt){
        int rb = bm + wr*64 + mt*16 + quad*4;
        int bloc = rb >> 9, m0 = rb & 511;
        #pragma unroll
        for (int nt=0; nt<4; ++nt){
          int ee = nt*16 + l16;
          size_t taddr = (((size_t)bloc*HH + hh)*DH + ee)*SS + m0;
          short4v pk;
          #pragma unroll
          for (int j=0;j<4;j++) pk[j] = (short)f2bs(acc[mt][nt][j]);
          *(short4v*)&vT[taddr] = pk;
        }
      }
    }
  }
}

// ---------------- SwiGLU GEMM (128x64, dual weight): swo = silu(A@Wg)*(A@Wp) ----------------
__global__ __launch_bounds__(256) void gemm_sw_kernel(
    const unsigned short* __restrict__ A, const unsigned short* __restrict__ Wt,
    const unsigned short* __restrict__ Wt2, unsigned short* __restrict__ swo)
{
  __shared__ unsigned short As[2][128*64];
  __shared__ unsigned short Bs[2][64*64];
  __shared__ unsigned short Bs2[2][64*64];
  const int P = blockIdx.y*gridDim.x + blockIdx.x;
  const int L = xcd_swz(P, gridDim.x*gridDim.y);
  const int bxl = L % gridDim.x, byl = L / gridDim.x;
  const int bm = byl*128, bn = bxl*64;
  const int tid = threadIdx.x, lane = tid & 63, wv = tid >> 6;
  const int wr = wv >> 1, wc = wv & 1;
  const int l16 = lane & 15, quad = lane >> 4;

  f32x4 acc[4][2], acc2[4][2];
  #pragma unroll
  for (int i=0;i<4;i++){
    acc[i][0]=(f32x4)(0.f); acc[i][1]=(f32x4)(0.f);
    acc2[i][0]=(f32x4)(0.f); acc2[i][1]=(f32x4)(0.f);
  }

  const int sg = lane >> 3;
  const int lg = (lane & 7) ^ sg;
  size_t aoff[4], boff[2];
  #pragma unroll
  for (int i=0;i<4;i++)
    aoff[i] = (size_t)(bm + (wv*4+i)*8 + sg)*EE + lg*8;
  #pragma unroll
  for (int i=0;i<2;i++)
    boff[i] = (size_t)(bn + (wv*2+i)*8 + sg)*EE + lg*8;

  const int swz = (l16 & 7) << 3;

  auto STAGE = [&](int buf, int t){
    const int k0 = t*64;
    #pragma unroll
    for (int i=0;i<4;i++)
      gl16(A + aoff[i] + k0, (char*)&As[buf][0] + ((wv*4+i) << 10));
    #pragma unroll
    for (int i=0;i<2;i++){
      gl16(Wt + boff[i] + k0, (char*)&Bs[buf][0] + ((wv*2+i) << 10));
      gl16(Wt2 + boff[i] + k0, (char*)&Bs2[buf][0] + ((wv*2+i) << 10));
    }
  };
  auto COMPUTE = [&](int buf){
    short8 af[4][2], bf[2][2], bf2[2][2];
    #pragma unroll
    for (int mt=0; mt<4; ++mt)
      #pragma unroll
      for (int ks=0; ks<2; ++ks)
        af[mt][ks] = *(const short8*)&As[buf][(wr*64 + mt*16 + l16)*64 + ((ks*32 + quad*8) ^ swz)];
    #pragma unroll
    for (int nt=0; nt<2; ++nt)
      #pragma unroll
      for (int ks=0; ks<2; ++ks){
        bf[nt][ks]  = *(const short8*)&Bs[buf][(wc*32 + nt*16 + l16)*64 + ((ks*32 + quad*8) ^ swz)];
        bf2[nt][ks] = *(const short8*)&Bs2[buf][(wc*32 + nt*16 + l16)*64 + ((ks*32 + quad*8) ^ swz)];
      }
    #pragma unroll
    for (int ks=0; ks<2; ++ks)
      #pragma unroll
      for (int mt=0; mt<4; ++mt)
        #pragma unroll
        for (int nt=0; nt<2; ++nt){
          acc[mt][nt]  = __builtin_amdgcn_mfma_f32_16x16x32_bf16(af[mt][ks], bf[nt][ks],  acc[mt][nt],  0, 0, 0);
          acc2[mt][nt] = __builtin_amdgcn_mfma_f32_16x16x32_bf16(af[mt][ks], bf2[nt][ks], acc2[mt][nt], 0, 0, 0);
        }
  };

  STAGE(0, 0);
  PIPE_SYNC;
  int cur = 0;
  for (int t = 0; t < 8; ++t){
    if (t+1 < 8) STAGE(cur^1, t+1);
    COMPUTE(cur);
    if (t+1 < 8) PIPE_SYNC;
    cur ^= 1;
  }

  #pragma unroll
  for (int mt=0; mt<4; ++mt){
    int rb = bm + wr*64 + mt*16 + quad*4;
    #pragma unroll
    for (int nt=0; nt<2; ++nt){
      int col = bn + wc*32 + nt*16 + l16;
      #pragma unroll
      for (int j=0;j<4;j++)
        swo[(size_t)(rb+j)*EE + col] = f2bs(silu_f(acc[mt][nt][j])*acc2[mt][nt][j]);
    }
  }
}

// ---------------- rmsnorm: wave-per-row, no LDS / barriers ----------------
__global__ __launch_bounds__(256) void norm_b_kernel(
    const unsigned short* __restrict__ ab, const unsigned short* __restrict__ resb,
    const float* __restrict__ w, unsigned short* __restrict__ o1,
    unsigned short* __restrict__ o2, const unsigned short* __restrict__ peb,
    int mode)
{
  const int row = blockIdx.x*4 + (threadIdx.x >> 6);
  const int lane = threadIdx.x & 63;
  const size_t base = (size_t)row*EE + lane*8;
  float t[8];
  {
    short8 av = *(const short8*)&ab[base];
    #pragma unroll
    for (int e=0;e<8;++e) t[e] = bs2f((unsigned short)av[e]);
  }
  if (mode == NORM_ADD){
    short8 rv = *(const short8*)&resb[base];
    #pragma unroll
    for (int e=0;e<8;++e) t[e] += bs2f((unsigned short)rv[e]);
  }
  float ss = 0.f;
  #pragma unroll
  for (int e=0;e<8;++e) ss += t[e]*t[e];
  #pragma unroll
  for (int o=32;o;o>>=1) ss += __shfl_xor(ss, o);
  float r = 1.f/sqrtf(ss/(float)EE + 1e-6f);
  float4 w0 = *(const float4*)&w[lane*8];
  float4 w1 = *(const float4*)&w[lane*8+4];
  float y[8];
  y[0]=t[0]*r*w0.x; y[1]=t[1]*r*w0.y; y[2]=t[2]*r*w0.z; y[3]=t[3]*r*w0.w;
  y[4]=t[4]*r*w1.x; y[5]=t[5]*r*w1.y; y[6]=t[6]*r*w1.z; y[7]=t[7]*r*w1.w;
  short8 pk;
  #pragma unroll
  for (int e=0;e<8;++e) pk[e] = (short)f2bs(y[e]);
  *(short8*)&o1[base] = pk;
  if (o2){
    short8 pv = *(const short8*)&peb[base];
    short8 pz;
    #pragma unroll
    for (int e=0;e<8;++e) pz[e] = (short)f2bs(y[e] + bs2f((unsigned short)pv[e]));
    *(short8*)&o2[base] = pz;
  }
}

// obs norm: wave-per-row, fp32 [MM][128] -> bf16
__global__ __launch_bounds__(256) void norm_obs_kernel(
    const float* __restrict__ a, const float* __restrict__ w, unsigned short* __restrict__ o)
{
  const int row = blockIdx.x*4 + (threadIdx.x >> 6);
  const int lane = threadIdx.x & 63;
  const size_t base = (size_t)row*OBSD + lane*2;
  float2 av = *(const float2*)&a[base];
  float ss = av.x*av.x + av.y*av.y;
  #pragma unroll
  for (int off=32;off;off>>=1) ss += __shfl_xor(ss, off);
  float r = 1.f/sqrtf(ss/(float)OBSD + 1e-6f);
  float2 wv2 = *(const float2*)&w[lane*2];
  unsigned int pk = (unsigned int)f2bs(av.x*r*wv2.x) | ((unsigned int)f2bs(av.y*r*wv2.y) << 16);
  *(unsigned int*)&o[base] = pk;
}

// action embed: fp32 [MM][17] -> bf16 [MM][64] zero-padded
__global__ __launch_bounds__(256) void act_embed_kernel(
    const float* __restrict__ a, unsigned short* __restrict__ o)
{
  int idx = blockIdx.x*256 + threadIdx.x;
  int row = idx >> 6, col = idx & 63;
  o[idx] = (col < ACTD) ? f2bs(a[(size_t)row*ACTD + col]) : 0;
}

// ---------------- fused chunk-state + scan, d-split + pass-split, async double-buffer ----------------
// grid: (ENC?4:2, HH, BB). x: dhalf = x&1, pass = x>>1 (enc only; pass1 = hi suffix).
// pass0: wcum_lo[c] = elk*h0^T + sum_{c'<c} Wc_lo (k scaled e^{-lk ts}), hnew.
// pass1: wcum_hi[c] = sum_{c'>c} Wc_hi (k scaled e^{+lk ts}).
template<int ENC>
__global__ __launch_bounds__(256) void wchunkscan_kernel(
    const unsigned short* __restrict__ k, const unsigned short* __restrict__ vT,
    const float* __restrict__ h0, const float* __restrict__ tmx,
    const int* __restrict__ tsi,
    unsigned short* __restrict__ wcum_lo, unsigned short* __restrict__ wcum_hi,
    float* __restrict__ hnew)
{
  __shared__ unsigned short vsh[2][64*72];
  __shared__ unsigned short ksh[2][32*72];
  const int P = (blockIdx.z*gridDim.y + blockIdx.y)*gridDim.x + blockIdx.x;
  const int L = xcd_swz(P, gridDim.x*gridDim.y*gridDim.z);
  const int gx = L % gridDim.x;
  const int h  = (L / gridDim.x) & 7;
  const int b  = L / (gridDim.x*8);
  const int dhalf = gx & 1;
  const int pass = ENC ? (gx >> 1) : 0;
  const int tid = threadIdx.x, lane = tid & 63, wv = tid >> 6;
  const int quad = lane >> 4, l16 = lane & 15;
  const float lk = lkappa(h);
  const float elk = __expf(lk);
  const float etm = __expf(lk*tmx[b]);
  const size_t wbase = ((size_t)b*HH + h)*8*4096;
  const size_t hbase = (size_t)b*(LL*HH*DH*DH) + (size_t)h*(DH*DH);
  const int e0r = wv*16 + quad*4;           // e base; +j
  const int rv = tid >> 2, segv = (tid & 3)*16;
  const int kact = ((tid & 3) < 2), segk = (tid & 1)*16;
  const int rk = tid >> 2;
  const float ksgn = pass ? lk : -lk;
  unsigned short* wout = pass ? wcum_hi : wcum_lo;
  const int c0 = pass ? 7 : 0, dc = pass ? -1 : 1;

  f32x4 cum[2];
  #pragma unroll
  for (int dt=0; dt<2; ++dt)
    #pragma unroll
    for (int j=0;j<4;j++)
      cum[dt][j] = pass ? 0.f
        : elk * h0[hbase + (size_t)(dhalf*32 + dt*16 + l16)*64 + e0r + j];

  short8 vv0, vv1, kv0, kv1;
  float kts = 0.f;
  auto LOADR = [&](int c){
    const unsigned short* vrow = vT + (((size_t)b*HH + h)*DH + rv)*SS + c*64 + segv;
    vv0 = *(const short8*)(vrow);
    vv1 = *(const short8*)(vrow + 8);
    if (kact){
      const unsigned short* krow = k + ((size_t)b*SS + c*64 + rk)*EE + h*DH + dhalf*32 + segk;
      kv0 = *(const short8*)(krow);
      kv1 = *(const short8*)(krow + 8);
      kts = (float)tsi[b*SS + c*64 + rk];
    }
  };
  auto WRITE = [&](int buf){
    *(short8*)&vsh[buf][rv*72 + segv] = vv0;
    *(short8*)&vsh[buf][rv*72 + segv + 8] = vv1;
    if (kact){
      float els = __expf(ksgn*kts);
      #pragma unroll
      for (int e=0;e<8;++e){
        ksh[buf][(segk + e)*72 + rk]     = f2bs(bs2f((unsigned short)kv0[e])*els);
        ksh[buf][(segk + 8 + e)*72 + rk] = f2bs(bs2f((unsigned short)kv1[e])*els);
      }
    }
  };

  LOADR(c0);
  WRITE(0);
  __syncthreads();
  int cur = 0;
  for (int i=0;i<8;++i){
    const int c = c0 + dc*i;
    if (i<7) LOADR(c + dc);
    short8 av0 = *(const short8*)&vsh[cur][(wv*16 + l16)*72 + quad*8];
    short8 av1 = *(const short8*)&vsh[cur][(wv*16 + l16)*72 + 32 + quad*8];
    f32x4 acc[2];
    #pragma unroll
    for (int dt=0; dt<2; ++dt){
      f32x4 a = (f32x4)(0.f);
      short8 kb0 = *(const short8*)&ksh[cur][(dt*16 + l16)*72 + quad*8];
      short8 kb1 = *(const short8*)&ksh[cur][(dt*16 + l16)*72 + 32 + quad*8];
      a = __builtin_amdgcn_mfma_f32_16x16x32_bf16(av0, kb0, a, 0, 0, 0);
      a = __builtin_amdgcn_mfma_f32_16x16x32_bf16(av1, kb1, a, 0, 0, 0);
      acc[dt] = a;
    }
    #pragma unroll
    for (int dt=0; dt<2; ++dt)
      #pragma unroll
      for (int j=0;j<4;j++){
        wout[wbase + (size_t)c*4096 + (size_t)(e0r+j)*64 + dhalf*32 + dt*16 + l16] = f2bs(cum[dt][j]);
        cum[dt][j] += acc[dt][j];
      }
    if (i<7){ WRITE(cur^1); __syncthreads(); cur ^= 1; }
  }
  if (!pass){
    #pragma unroll
    for (int dt=0; dt<2; ++dt)
      #pragma unroll
      for (int j=0;j<4;j++)
        hnew[hbase + (size_t)(dhalf*32 + dt*16 + l16)*64 + e0r + j] = etm * cum[dt][j];
  }
}

// ---------------- retention (chunked-recurrent, raw q/k with staged scaling) ----------------
template<int ENC>
__global__ __launch_bounds__(256) void retention2_kernel(
    const unsigned short* __restrict__ q, const unsigned short* __restrict__ k,
    const unsigned short* __restrict__ vT,
    const unsigned short* __restrict__ wlo, const unsigned short* __restrict__ whi,
    const int* __restrict__ tsi, unsigned short* __restrict__ outp)
{
  __shared__ unsigned short qsh[64*72];        // reused as psh in boundary
  __shared__ unsigned short wsh[64*72];
  __shared__ unsigned short ksh[64*72];
  __shared__ unsigned short vsh[64*72];
  __shared__ unsigned short qsh2[ENC ? 64*72 : 2];  // reused as ksh2 in boundary
  __shared__ unsigned short wsh2[ENC ? 64*72 : 2];
  __shared__ float tsf[SS];
  // XCD swizzle: the 8 t-blocks of one (b,h) share K/V/q -> same XCD
  const int P = (blockIdx.z*gridDim.y + blockIdx.y)*gridDim.x + blockIdx.x;
  const int L = xcd_swz(P, gridDim.x*gridDim.y*gridDim.z);
  const int t = L & 7, h = (L >> 3) & 7, b = L >> 6;
  const int n0 = t*64;
  const int tid = threadIdx.x, lane = tid & 63, wv = tid >> 6;
  const int quad = lane >> 4, l16 = lane & 15;
  const float lk = lkappa(h);

  for (int i = tid; i < SS; i += 256) tsf[i] = (float)tsi[b*SS + i];
  {
    const int n = tid >> 2, seg = (tid & 3)*16;
    float ts_n = (float)tsi[b*SS + n0 + n];
    float e0 = __expf(lk*ts_n);
    float e1 = ENC ? __expf(-lk*ts_n) : 0.f;
    const unsigned short* qr = q + ((size_t)b*SS + n0 + n)*EE + h*DH + seg;
    #pragma unroll
    for (int i = 0; i < 2; ++i){
      short8 v = *(const short8*)(qr + i*8);
      short8 o, o2;
      #pragma unroll
      for (int e=0;e<8;++e){
        float f = bs2f((unsigned short)v[e]);
        o[e] = (short)f2bs(f*e0);
        if (ENC) o2[e] = (short)f2bs(f*e1);
      }
      *(short8*)&qsh[n*72 + seg + i*8] = o;
      if (ENC) *(short8*)&qsh2[n*72 + seg + i*8] = o2;
    }
    const unsigned short* wr = wlo + (((size_t)b*HH + h)*8 + t)*4096 + (size_t)n*64 + seg;
    #pragma unroll
    for (int i = 0; i < 2; ++i)
      *(short8*)&wsh[n*72 + seg + i*8] = *(const short8*)(wr + i*8);
    if (ENC){
      const unsigned short* wr2 = whi + (((size_t)b*HH + h)*8 + t)*4096 + (size_t)n*64 + seg;
      #pragma unroll
      for (int i = 0; i < 2; ++i)
        *(short8*)&wsh2[n*72 + seg + i*8] = *(const short8*)(wr2 + i*8);
    }
  }
  __syncthreads();

  const int rowbase = wv*16;
  short8 qa[2], qa2[2];
  #pragma unroll
  for (int ks=0; ks<2; ++ks)
    qa[ks] = *(const short8*)&qsh[(rowbase + l16)*72 + ks*32 + quad*8];
  if (ENC){
    #pragma unroll
    for (int ks=0; ks<2; ++ks)
      qa2[ks] = *(const short8*)&qsh2[(rowbase + l16)*72 + ks*32 + quad*8];
  }

  float tn = tsf[n0 + lane];
  float maxn = tn, minn = tn;
  #pragma unroll
  for (int o=32;o;o>>=1){
    maxn = fmaxf(maxn, __shfl_xor(maxn, o));
    minn = fminf(minn, __shfl_xor(minn, o));
  }

  // cross-chunk + h0 contribution
  f32x4 acc_o[4];
  #pragma unroll
  for (int et=0; et<4; ++et){
    f32x4 a = (f32x4)(0.f);
    #pragma unroll
    for (int ks=0; ks<2; ++ks){
      short8 wb = *(const short8*)&wsh[(et*16 + l16)*72 + ks*32 + quad*8];
      a = __builtin_amdgcn_mfma_f32_16x16x32_bf16(qa[ks], wb, a, 0, 0, 0);
    }
    if (ENC){
      #pragma unroll
      for (int ks=0; ks<2; ++ks){
        short8 wb2 = *(const short8*)&wsh2[(et*16 + l16)*72 + ks*32 + quad*8];
        a = __builtin_amdgcn_mfma_f32_16x16x32_bf16(qa2[ks], wb2, a, 0, 0, 0);
      }
    }
    acc_o[et] = a;
  }

  // boundary chunk(s)
  for (int c = 0; c < 8; ++c){
    const int mc = c*64;
    float tmv = tsf[mc + lane];
    float maxm = tmv, minm = tmv;
    #pragma unroll
    for (int o=32;o;o>>=1){
      maxm = fmaxf(maxm, __shfl_xor(maxm, o));
      minm = fminf(minm, __shfl_xor(minm, o));
    }
    if (ENC){
      if (maxm <= minn) continue;
      if (minm >= maxn) continue;
    } else {
      if ((maxm < minn) || (maxm == minn && (mc + 63) < n0)) continue;
      if (minm > maxn) continue;
    }
    __syncthreads();
    {
      const int m = tid >> 2, cb = (tid & 3)*16;
      float ts_m = tsf[mc + m];
      float ek0 = __expf(-lk*ts_m);
      float ek1 = ENC ? __expf(lk*ts_m) : 0.f;
      const unsigned short* krow = k + ((size_t)b*SS + mc + m)*EE + h*DH + cb;
      #pragma unroll
      for (int i = 0; i < 2; ++i){
        short8 kv = *(const short8*)(krow + i*8);
        short8 o, o2;
        #pragma unroll
        for (int e=0;e<8;++e){
          float f = bs2f((unsigned short)kv[e]);
          o[e] = (short)f2bs(f*ek0);
          if (ENC) o2[e] = (short)f2bs(f*ek1);
        }
        *(short8*)&ksh[m*72 + cb + i*8] = o;
        if (ENC) *(short8*)&qsh2[m*72 + cb + i*8] = o2;
      }
      const unsigned short* vrow = vT + (((size_t)b*HH + h)*DH + m)*SS + mc + cb;
      #pragma unroll
      for (int i = 0; i < 2; ++i)
        *(short8*)&vsh[m*72 + cb + i*8] = *(const short8*)(vrow + i*8);
    }
    __syncthreads();
    f32x4 sacc[4], sacc2[4];
    #pragma unroll
    for (int mt=0; mt<4; ++mt){
      f32x4 a = (f32x4)(0.f);
      #pragma unroll
      for (int ks=0; ks<2; ++ks){
        short8 kb = *(const short8*)&ksh[(mt*16 + l16)*72 + ks*32 + quad*8];
        a = __builtin_amdgcn_mfma_f32_16x16x32_bf16(qa[ks], kb, a, 0, 0, 0);
      }
      sacc[mt] = a;
      if (ENC){
        f32x4 a2 = (f32x4)(0.f);
        #pragma unroll
        for (int ks=0; ks<2; ++ks){
          short8 kb2 = *(const short8*)&qsh2[(mt*16 + l16)*72 + ks*32 + quad*8];
          a2 = __builtin_amdgcn_mfma_f32_16x16x32_bf16(qa2[ks], kb2, a2, 0, 0, 0);
        }
        sacc2[mt] = a2;
      }
    }
    float tsm[4]; int mg[4];
    #pragma unroll
    for (int mt=0; mt<4; ++mt){ mg[mt] = mc + mt*16 + l16; tsm[mt] = tsf[mg[mt]]; }
    #pragma unroll
    for (int j=0;j<4;j++){
      int nloc = rowbase + quad*4 + j;
      int n = n0 + nloc;
      float tsn = tsf[n];
      #pragma unroll
      for (int mt=0; mt<4; ++mt){
        float diff = tsn - tsm[mt];
        float p;
        if (ENC) p = (diff >= 0.f) ? sacc[mt][j] : sacc2[mt][j];
        else     p = ((diff > 0.f) || (diff == 0.f && n >= mg[mt])) ? sacc[mt][j] : 0.f;
        qsh[nloc*72 + mt*16 + l16] = f2bs(p);   // qsh reused as psh
      }
    }
    #pragma unroll
    for (int ks=0; ks<2; ++ks){
      short8 pa = *(const short8*)&qsh[(rowbase + l16)*72 + ks*32 + quad*8];
      #pragma unroll
      for (int et=0; et<4; ++et){
        short8 vb = *(const short8*)&vsh[(et*16 + l16)*72 + ks*32 + quad*8];
        acc_o[et] = __builtin_amdgcn_mfma_f32_16x16x32_bf16(pa, vb, acc_o[et], 0, 0, 0);
      }
    }
  }
  #pragma unroll
  for (int j=0;j<4;j++){
    size_t rbase = ((size_t)b*SS + n0 + rowbase + quad*4 + j)*EE + h*DH;
    #pragma unroll
    for (int et=0; et<4; ++et)
      outp[rbase + et*16 + l16] = f2bs(acc_o[et][j]);
  }
}

// ---------------- small helpers ----------------
__global__ void tsmax_kernel(const int* __restrict__ tsi, float* __restrict__ tmx){
  __shared__ int red[4];
  int b = blockIdx.x, tid = threadIdx.x;
  int m = max(tsi[b*SS+tid], tsi[b*SS+256+tid]);
  #pragma unroll
  for (int o=32;o;o>>=1) m = max(m, __shfl_down(m,o));
  if ((tid&63)==0) red[tid>>6]=m;
  __syncthreads();
  if (tid==0) tmx[b] = (float)max(max(red[0],red[1]),max(red[2],red[3]));
}

__global__ void pe_kernel(const int* __restrict__ tsi, unsigned short* __restrict__ peb){
  int idx = blockIdx.x*256 + threadIdx.x;
  int row = idx >> 9, j = idx & 511;
  float ts = (float)tsi[row];
  int jj = j & 255;
  float freq = expf(-9.210340371976184f*(float)jj*(1.f/256.f));
  float ang = ts*freq;
  peb[idx] = f2bs((j < 256) ? sinf(ang) : cosf(ang));
}

// fused rmsnorm + value head: out = (rms(x)·x·ln) @ w + b
__global__ __launch_bounds__(256) void value_head_kernel(
    const unsigned short* __restrict__ x, const float* __restrict__ ln,
    const float* __restrict__ w, const float* __restrict__ bias,
    float* __restrict__ outp)
{
  const int row = blockIdx.x*4 + (threadIdx.x >> 6);
  const int lane = threadIdx.x & 63;
  const size_t base = (size_t)row*EE + lane*8;
  short8 xv = *(const short8*)&x[base];
  float4 l0 = *(const float4*)&ln[lane*8];
  float4 l1 = *(const float4*)&ln[lane*8+4];
  float4 w0 = *(const float4*)&w[lane*8];
  float4 w1 = *(const float4*)&w[lane*8+4];
  float lw[8] = {l0.x*w0.x, l0.y*w0.y, l0.z*w0.z, l0.w*w0.w,
                 l1.x*w1.x, l1.y*w1.y, l1.z*w1.z, l1.w*w1.w};
  float ss = 0.f, dp = 0.f;
  #pragma unroll
  for (int e=0;e<8;++e){
    float f = bs2f((unsigned short)xv[e]);
    ss += f*f;
    dp += f*lw[e];
  }
  #pragma unroll
  for (int o=32;o;o>>=1){ ss += __shfl_xor(ss,o); dp += __shfl_xor(dp,o); }
  if (lane==0) outp[row] = dp*(1.f/sqrtf(ss/(float)EE + 1e-6f)) + bias[0];
}

// fused rmsnorm + logits head: out[j] = (rms(x)·x·ln) @ w2[:,j] + b[j]
__global__ __launch_bounds__(256) void logits_head_kernel(
    const unsigned short* __restrict__ x, const float* __restrict__ ln,
    const float* __restrict__ w, const float* __restrict__ bias,
    float* __restrict__ outp)
{
  __shared__ unsigned short ysh[16*528];
  __shared__ unsigned short wsh[16*520];
  const int tid = threadIdx.x;
  const int row0 = blockIdx.x*16;
  const int g = tid >> 4, j16 = tid & 15;
  {
    const int kc = j16*32;
    #pragma unroll
    for (int kk = 0; kk < 32; ++kk)
      wsh[g*520 + kc + kk] = f2bs(w[(size_t)(kc + kk)*16 + g]);
  }
  {
    const unsigned short* xr = x + (size_t)(row0+g)*EE + j16*32;
    float xs[32];
    float ss = 0.f;
    #pragma unroll
    for (int i=0;i<4;++i){
      short8 v = *(const short8*)(xr + i*8);
      #pragma unroll
      for (int e=0;e<8;++e){ float f = bs2f((unsigned short)v[e]); xs[i*8+e]=f; ss += f*f; }
    }
    ss += __shfl_xor(ss,1); ss += __shfl_xor(ss,2);
    ss += __shfl_xor(ss,4); ss += __shfl_xor(ss,8);
    float r = 1.f/sqrtf(ss/(float)EE + 1e-6f);
    #pragma unroll
    for (int i=0;i<4;++i){
      float4 la = *(const float4*)&ln[j16*32 + i*8];
      float4 lb = *(const float4*)&ln[j16*32 + i*8 + 4];
      short8 o;
      o[0]=(short)f2bs(xs[i*8+0]*r*la.x); o[1]=(short)f2bs(xs[i*8+1]*r*la.y);
      o[2]=(short)f2bs(xs[i*8+2]*r*la.z); o[3]=(short)f2bs(xs[i*8+3]*r*la.w);
      o[4]=(short)f2bs(xs[i*8+4]*r*lb.x); o[5]=(short)f2bs(xs[i*8+5]*r*lb.y);
      o[6]=(short)f2bs(xs[i*8+6]*r*lb.z); o[7]=(short)f2bs(xs[i*8+7]*r*lb.w);
      *(short8*)&ysh[g*528 + j16*32 + i*8] = o;
    }
  }
  __syncthreads();
  float s = 0.f;
  for (int kk = 0; kk < EE; kk += 8){
    short8 xv = *(const short8*)&ysh[g*528 + kk];
    short8 wv = *(const short8*)&wsh[j16*520 + kk];
    #pragma unroll
    for (int e = 0; e < 8; ++e)
      s += bs2f((unsigned short)xv[e]) * bs2f((unsigned short)wv[e]);
  }
  outp[(size_t)(row0 + g)*16 + j16] = s + bias[j16];
}

// ---------------- orchestration ----------------
extern "C" void kernel_launch(void* const* d_in, const int* in_sizes, int n_in,
                              void* d_out, int out_size, void* d_ws, size_t ws_size,
                              hipStream_t stream)
{
  const float* obs     = (const float*)d_in[0];
  const float* action  = (const float*)d_in[1];
  const float* enc_hs  = (const float*)d_in[2];
  const float* dec_hs1 = (const float*)d_in[3];
  const float* dec_hs2 = (const float*)d_in[4];
  const int*   stepc   = (const int*)d_in[5];
  const float* eoln = (const float*)d_in[6];
  const float* eow  = (const float*)d_in[7];
  const float* eln  = (const float*)d_in[8];
  const float* ewq  = (const float*)d_in[9];
  const float* ewk  = (const float*)d_in[10];
  const float* ewv  = (const float*)d_in[11];
  const float* ewo  = (const float*)d_in[12];
  const float* eln1 = (const float*)d_in[13];
  const float* eln2 = (const float*)d_in[14];
  const float* efg  = (const float*)d_in[15];
  const float* efp  = (const float*)d_in[16];
  const float* ehw1 = (const float*)d_in[17];
  const float* ehb1 = (const float*)d_in[18];
  const float* ehln = (const float*)d_in[19];
  const float* ehw2 = (const float*)d_in[20];
  const float* ehb2 = (const float*)d_in[21];
  const float* daw  = (const float*)d_in[22];
  const float* dln  = (const float*)d_in[23];
  const float* dwq1 = (const float*)d_in[24];
  const float* dwk1 = (const float*)d_in[25];
  const float* dwv1 = (const float*)d_in[26];
  const float* dwo1 = (const float*)d_in[27];
  const float* dwq2 = (const float*)d_in[28];
  const float* dwk2 = (const float*)d_in[29];
  const float* dwv2 = (const float*)d_in[30];
  const float* dwo2 = (const float*)d_in[31];
  const float* dln1 = (const float*)d_in[32];
  const float* dln2 = (const float*)d_in[33];
  const float* dln3 = (const float*)d_in[34];
  const float* dfg  = (const float*)d_in[35];
  const float* dfp  = (const float*)d_in[36];
  const float* dhw1 = (const float*)d_in[37];
  const float* dhb1 = (const float*)d_in[38];
  const float* dhln = (const float*)d_in[39];
  const float* dhw2 = (const float*)d_in[40];
  const float* dhb2 = (const float*)d_in[41];

  const size_t BUF = (size_t)MM*EE;
  // region A: wcum_lo + wcum_hi (bf16) ; gf_b (bf16 gemmF out) aliases wcum_lo (disjoint lifetimes)
  float* wsf  = (float*)d_ws;
  float* f32a = wsf;
  float* f32b = f32a + BUF;
  float* tmx  = f32b + BUF;
  unsigned short* wcum_lo = (unsigned short*)f32a;      // [B][H][8][4096] bf16
  unsigned short* wcum_hi = wcum_lo + BUF;              // [B][H][8][4096] bf16 (enc)
  unsigned short* gf_b    = wcum_lo;                    // alias: gemmF bf16 out
  unsigned short* sw_b    = (unsigned short*)f32b;      // silu(g)*p bf16
  // bf16 region
  unsigned short* ub = (unsigned short*)(tmx + 64);
  unsigned short* xrep_b    = ub;  ub += BUF;
  unsigned short* xrep_pe_b = ub;  ub += BUF;
  unsigned short* x_b       = ub;  ub += BUF;
  unsigned short* x_pe_b    = ub;  ub += BUF;
  unsigned short* t1_b      = ub;  ub += BUF;
  unsigned short* t1_pe_b   = ub;  ub += BUF;   // decoder r+pe
  unsigned short* peb       = ub;  ub += BUF;
  unsigned short* q_b       = ub;  ub += BUF;   // raw q
  unsigned short* k_b       = ub;  ub += BUF;   // raw k * 1/sqrt(D)
  unsigned short* vT_b      = ub;  ub += BUF;   // [B][H][64][512]
  unsigned short* obs_n     = ub;  ub += (size_t)MM*OBSD;
  unsigned short* act_b     = obs_n;            // aliased (obs_n dead by decoder embed)
  // weights
  const size_t W55 = (size_t)EE*EE;
  unsigned short* wts = ub;  ub += 50*W55;
  unsigned short* wt_eow = ub; ub += (size_t)EE*OBSD;
  unsigned short* wt_daw = ub; ub += (size_t)EE*64;
  size_t need = (char*)ub - (char*)d_ws;
  if (ws_size < need) return;

  // fused-weight layout (z index into wts):
  // 0..8  : enc [q,k,v] x3 layers     9..11 : ewo
  // 12..14: efg   15..17: efp   18: ehw1
  // 19..27: dec1 [q,k,v] x3           28..30: dwo1
  // 31..36: dec2 [k,v] x3             37..39: dwq2
  // 40..42: dwo2  43..45: dfg  46..48: dfp   49: dhw1
  unsigned short* wt_eqkv  = wts + 0*W55;   // +3*i per layer
  unsigned short* wt_ewo   = wts + 9*W55;
  unsigned short* wt_efg   = wts + 12*W55;
  unsigned short* wt_efp   = wts + 15*W55;
  unsigned short* wt_ehw1  = wts + 18*W55;
  unsigned short* wt_dqkv1 = wts + 19*W55;  // +3*i
  unsigned short* wt_dwo1  = wts + 28*W55;
  unsigned short* wt_dkv2  = wts + 31*W55;  // +2*i  ([k;v] contiguous per layer)
  unsigned short* wt_dwq2  = wts + 37*W55;
  unsigned short* wt_dwo2  = wts + 40*W55;
  unsigned short* wt_dfg   = wts + 43*W55;
  unsigned short* wt_dfp   = wts + 46*W55;
  unsigned short* wt_dhw1  = wts + 49*W55;

  float* out        = (float*)d_out;
  float* value_out  = out;
  float* logits_out = out + 8192;
  float* enc_out    = logits_out + (size_t)MM*16;
  float* d1_out     = enc_out + (size_t)BB*LL*HH*DH*DH;
  float* d2_out     = d1_out  + (size_t)BB*LL*HH*DH*DH;

  const size_t HS_L = (size_t)HH*DH*DH;

  {
    TP50 tp;
    int z = 0;
    auto add = [&](const float* p){ tp.s[z] = p; tp.d[z] = wts + (size_t)z*W55; ++z; };
    for (int i=0;i<3;++i){ add(ewq+i*W55); add(ewk+i*W55); add(ewv+i*W55); }
    for (int i=0;i<3;++i) add(ewo+i*W55);
    for (int i=0;i<3;++i) add(efg+i*W55);
    for (int i=0;i<3;++i) add(efp+i*W55);
    add(ehw1);
    for (int i=0;i<3;++i){ add(dwq1+i*W55); add(dwk1+i*W55); add(dwv1+i*W55); }
    for (int i=0;i<3;++i) add(dwo1+i*W55);
    for (int i=0;i<3;++i){ add(dwk2+i*W55); add(dwv2+i*W55); }
    for (int i=0;i<3;++i) add(dwq2+i*W55);
    for (int i=0;i<3;++i) add(dwo2+i*W55);
    for (int i=0;i<3;++i) add(dfg+i*W55);
    for (int i=0;i<3;++i) add(dfp+i*W55);
    add(dhw1);
    wtpose_batch_kernel<<<dim3(16,16,50), dim3(32,8), 0, stream>>>(tp);
  }
  wtpose_kernel<<<dim3(4,16), dim3(32,8), 0, stream>>>(eow, wt_eow, OBSD, OBSD);
  wtpose_kernel<<<dim3(2,16), dim3(32,8), 0, stream>>>(daw, wt_daw, ACTD, 64);

  pe_kernel<<<(MM*EE)/256, 256, 0, stream>>>(stepc, peb);
  tsmax_kernel<<<BB, 256, 0, stream>>>(stepc, tmx);

  auto gemmF = [&](const unsigned short* A, const unsigned short* Wt, const float* bias,
                   unsigned short* Cb, int Kpad, float scale, int act){
    gemm128_kernel<0><<<dim3(EE/128, MM/128), 256, 0, stream>>>(A, Wt, bias, Cb,
        Kpad, scale, act, 0, nullptr, nullptr, 1<<30, 0, nullptr, nullptr, nullptr);
  };
  auto gemmQKV = [&](const unsigned short* A, const unsigned short* Wt){
    gemm128_kernel<1><<<dim3(12, MM/128), 256, 0, stream>>>(A, Wt, nullptr, nullptr,
        EE, 1.f, ACT_NONE, 0, nullptr, nullptr, 1<<30, 0, q_b, k_b, vT_b);
  };
  // merged decoder layer-2 projections: blocks [0,4) q from A1@Wq2; [4,12) k,v from A2@[Wk2;Wv2]
  auto gemmQ2KV = [&](const unsigned short* A1, const unsigned short* Wq2,
                      const unsigned short* A2, const unsigned short* Wkv2){
    gemm128_kernel<1><<<dim3(12, MM/128), 256, 0, stream>>>(A1, Wq2, nullptr, nullptr,
        EE, 1.f, ACT_NONE, 0, A2, Wkv2, 512, 1, q_b, k_b, vT_b);
  };
  auto gemmSW = [&](const unsigned short* A, const unsigned short* Wg, const unsigned short* Wp){
    gemm_sw_kernel<<<dim3(EE/64, MM/128), 256, 0, stream>>>(A, Wg, Wp, sw_b);
  };
  auto norm = [&](const unsigned short* ab, const unsigned short* resb, const float* w,
                  unsigned short* o1, unsigned short* o2, int mode){
    norm_b_kernel<<<MM/4, 256, 0, stream>>>(ab, resb, w, o1, o2, peb, mode);
  };
  auto retention = [&](const float* h0, float* hnew, unsigned short* o, int enc){
    if (enc){
      wchunkscan_kernel<1><<<dim3(4, HH, BB), 256, 0, stream>>>(k_b, vT_b,
          h0, tmx, stepc, wcum_lo, wcum_hi, hnew);
      retention2_kernel<1><<<dim3(8, HH, BB), 256, 0, stream>>>(
          q_b, k_b, vT_b, wcum_lo, wcum_hi, stepc, o);
    } else {
      wchunkscan_kernel<0><<<dim3(2, HH, BB), 256, 0, stream>>>(k_b, vT_b,
          h0, tmx, stepc, wcum_lo, nullptr, hnew);
      retention2_kernel<0><<<dim3(8, HH, BB), 256, 0, stream>>>(
          q_b, k_b, vT_b, wcum_lo, nullptr, stepc, o);
    }
  };

  // ---- encoder embed ----
  norm_obs_kernel<<<MM/4, 256, 0, stream>>>(obs, eoln, obs_n);
  gemmF(obs_n, wt_eow, nullptr, gf_b, OBSD, 1.f, ACT_GELU);   // gf_b = obs_rep (bf16)

  // ---- encoder layers ----
  for (int i = 0; i < LL; ++i){
    if (i == 0) norm(gf_b, nullptr, eln, x_b, x_pe_b, NORM_PLAIN);
    else        norm(xrep_b, nullptr, eln, x_b, x_pe_b, NORM_PLAIN);
    gemmQKV(x_pe_b, wt_eqkv + (size_t)3*i*W55);
    retention(enc_hs + i*HS_L, enc_out + i*HS_L, t1_b, 1);
    gemmF(t1_b, wt_ewo + i*W55, nullptr, gf_b, EE, 1.f, ACT_NONE);
    norm(x_b, gf_b, eln1 + i*EE, t1_b, nullptr, NORM_ADD);
    gemmSW(t1_b, wt_efg + i*W55, wt_efp + i*W55);
    norm(t1_b, sw_b, eln2 + i*EE, xrep_b, xrep_pe_b, NORM_ADD);
  }

  // ---- value head (fused norm) ----
  gemmF(xrep_b, wt_ehw1, ehb1, gf_b, EE, 1.f, ACT_GELU);
  value_head_kernel<<<MM/4, 256, 0, stream>>>(gf_b, ehln, ehw2, ehb2, value_out);

  // ---- decoder embed ----
  act_embed_kernel<<<(MM*64)/256, 256, 0, stream>>>(action, act_b);
  gemmF(act_b, wt_daw, nullptr, gf_b, 64, 1.f, ACT_GELU);
  norm(gf_b, nullptr, dln, x_b, x_pe_b, NORM_PLAIN);

  // ---- decoder layers ----
  for (int i = 0; i < LL; ++i){
    gemmQKV(x_pe_b, wt_dqkv1 + (size_t)3*i*W55);
    retention(dec_hs1 + i*HS_L, d1_out + i*HS_L, t1_b, 0);
    gemmF(t1_b, wt_dwo1 + i*W55, nullptr, gf_b, EE, 1.f, ACT_NONE);
    norm(x_b, gf_b, dln1 + i*EE, t1_b, t1_pe_b, NORM_ADD);   // r
    gemmQ2KV(xrep_pe_b, wt_dwq2 + i*W55, t1_pe_b, wt_dkv2 + (size_t)2*i*W55);
    retention(dec_hs2 + i*HS_L, d2_out + i*HS_L, t1_b, 0);
    gemmF(t1_b, wt_dwo2 + i*W55, nullptr, gf_b, EE, 1.f, ACT_NONE);
    norm(xrep_b, gf_b, dln2 + i*EE, x_b, nullptr, NORM_ADD); // y
    gemmSW(x_b, wt_dfg + i*W55, wt_dfp + i*W55);
    norm(x_b, sw_b, dln3 + i*EE, x_b, x_pe_b, NORM_ADD);
  }

  // ---- logits head (fused norm) ----
  gemmF(x_b, wt_dhw1, dhb1, gf_b, EE, 1.f, ACT_GELU);
  logits_head_kernel<<<MM/16, 256, 0, stream>>>(gf_b, dhln, dhw2, dhb2, logits_out);
}